// Round 1
// 465.251 us; speedup vs baseline: 1.1065x; 1.1065x over previous
//
#include <hip/hip_runtime.h>
#include <hip/hip_fp16.h>
#include <stdint.h>

#define TROWS 51712   // 512*101
#define NCITY 101
#define BATCH 512
#define EDIM  128
#define NBH   4096    // BATCH*8 heads

using half_t = _Float16;
typedef __attribute__((ext_vector_type(8))) _Float16 h8;
typedef __attribute__((ext_vector_type(4))) _Float16 h4;
typedef __attribute__((ext_vector_type(4))) float   f32x4;

typedef __attribute__((address_space(1))) const unsigned int gu32;
typedef __attribute__((address_space(3))) unsigned int lu32;
static __device__ __forceinline__ void async16(const void* g, const void* l) {
    __builtin_amdgcn_global_load_lds((gu32*)g, (lu32*)(uint32_t)(uintptr_t)l, 16, 0, 0);
}

// ---------------- one-shot weight prep: all transposes + bias pack ----------------
// wf1/wf2 are stored as the per-chunk LDS images ff_fused stages flat via
// global_load_lds, with the quarter-XOR swizzle (q' = q ^ ((n>>1)&3)) baked in
// so that swizzled ds_read_b128 in ff_fused is bank-conflict-free.
__global__ __launch_bounds__(256)
void prep_kernel(const float* __restrict__ Wq, const float* __restrict__ Wk,
                 const float* __restrict__ Wv, const float* __restrict__ Wo,
                 const float* __restrict__ Wf1, const float* __restrict__ Wf2,
                 const float* __restrict__ bq, const float* __restrict__ bk,
                 const float* __restrict__ bv,
                 half_t* __restrict__ wqkv, half_t* __restrict__ wo,
                 half_t* __restrict__ wf1, half_t* __restrict__ wf2,
                 float* __restrict__ bqkv)
{
    const int which = blockIdx.y;
    const int gid = blockIdx.x * 256 + threadIdx.x;
    if (which <= 2) {
        if (gid >= 3 * 128 * 128) return;
        const float* src = (which == 0) ? Wq : (which == 1) ? Wk : Wv;
        int l = gid >> 14, r = gid & 16383, k = r >> 7, n = r & 127;
        wqkv[(size_t)l * 49152 + which * 16384 + n * 128 + k] = (half_t)src[gid];
    } else if (which == 3) {
        if (gid >= 3 * 128 * 128) return;
        int l = gid >> 14, r = gid & 16383, k = r >> 7, n = r & 127;
        wo[(size_t)l * 16384 + n * 128 + k] = (half_t)Wo[gid];
    } else if (which == 4) {
        // wf1 image: [l][j(8)][kc(4)][n(64)][h'(32)]
        // value(n,h') = Wf1[l][k = kc*32 + ((h'>>3)^((n>>1)&3))*8 + (h'&7)][j*64+n]
        if (gid >= 3 * 65536) return;
        int l = gid >> 16, u = gid & 65535;
        int j = u >> 13, kc = (u >> 11) & 3, n = (u >> 5) & 63, hp = u & 31;
        int k = kc * 32 + ((((hp >> 3) ^ (n >> 1)) & 3) << 3) + (hp & 7);
        wf1[(size_t)l * 65536 + u] = (half_t)Wf1[(size_t)(l * 128 + k) * 512 + j * 64 + n];
    } else if (which == 5) {
        // wf2 image: [l][j(8)][kc2(2)][n(128)][h'(32)]
        // value(n,h') = Wf2[l][kh = j*64 + kc2*32 + ((h'>>3)^((n>>1)&3))*8 + (h'&7)][n]
        if (gid >= 3 * 65536) return;
        int l = gid >> 16, u = gid & 65535;
        int j = u >> 13, kc = (u >> 12) & 1, n = (u >> 5) & 127, hp = u & 31;
        int kh = j * 64 + kc * 32 + ((((hp >> 3) ^ (n >> 1)) & 3) << 3) + (hp & 7);
        wf2[(size_t)l * 65536 + u] = (half_t)Wf2[(size_t)(l * 512 + kh) * 128 + n];
    } else {
        if (gid >= 3 * 384) return;
        int l = gid / 384, c = gid - l * 384;
        float v = (c < 128) ? bq[l * 128 + c]
                : (c < 256) ? bk[l * 128 + c - 128]
                            : bv[l * 128 + c - 256];
        bqkv[gid] = v;
    }
}

// ---------------- embedding (fp16 activation mirror only) ----------------
__global__ __launch_bounds__(256)
void embed_kernel(const float* __restrict__ s, const int* __restrict__ d,
                  const float* __restrict__ e_w, const float* __restrict__ e_b,
                  const float* __restrict__ ep_w, const float* __restrict__ ep_b,
                  half_t* __restrict__ xh)
{
    int gid = blockIdx.x * 256 + threadIdx.x;      // over TROWS*128
    int row = gid >> 7;
    int c   = gid & 127;
    int b = row / NCITY;
    int n = row - b * NCITY;
    const float* sp = s + ((size_t)b * NCITY + n) * 2;
    float v;
    if (n == 0) {
        v = sp[0] * ep_w[c] + sp[1] * ep_w[128 + c] + ep_b[c];
    } else {
        float dv = (float)d[b * NCITY + n];
        v = sp[0] * e_w[c] + sp[1] * e_w[128 + c] + dv * e_w[256 + c] + e_b[c];
    }
    xh[gid] = (half_t)v;
}

// ---------------- fp16 GEMM, 1-barrier double-buffered pipeline ----------------
// MODE 0: QKV — scatter fp16 to Q/K/V, all [bh][tok][16]
// MODE 1: out fp16 y = acc + bias + res(fp16), fused BN stats (O-proj)
template<int MODE, int KSTEPS>
__global__ __launch_bounds__(256)
void gemm_tile(const half_t* __restrict__ A, const half_t* __restrict__ B,
               const float* __restrict__ bias, const half_t* __restrict__ res,
               void* __restrict__ out, void* __restrict__ outK, void* __restrict__ outV,
               float* __restrict__ stats, int Nout)
{
    constexpr int K = KSTEPS * 32;
    __shared__ alignas(16) half_t sA[2][128 * 32];
    __shared__ alignas(16) half_t sB[2][128 * 32];

    const int tid  = threadIdx.x;
    const int wave = tid >> 6, lane = tid & 63;
    const int n0 = blockIdx.x * 128;
    const int m0 = blockIdx.y * 128;

    const int sr = wave * 16 + (lane >> 2);
    const int sc = (lane & 3) * 8;
    const half_t* gA = A + (size_t)(m0 + sr) * K + sc;
    const half_t* gB = B + (size_t)(n0 + sr) * K + sc;
    const int ldst = wave * 512;

    const int quad = lane >> 4, l16 = lane & 15;
    const int wm = (wave >> 1) * 64, wn = (wave & 1) * 64;

    f32x4 acc[4][4] = {};

    async16(gA,                  &sA[0][ldst]);
    async16(gA + (size_t)64 * K, &sA[0][2048 + ldst]);
    async16(gB,                  &sB[0][ldst]);
    async16(gB + (size_t)64 * K, &sB[0][2048 + ldst]);

    for (int ks = 0; ks < KSTEPS; ++ks) {
        __syncthreads();
        if (ks + 1 < KSTEPS) {
            const int k0 = (ks + 1) * 32;
            const int nb = (ks + 1) & 1;
            async16(gA + k0,                  &sA[nb][ldst]);
            async16(gA + (size_t)64 * K + k0, &sA[nb][2048 + ldst]);
            async16(gB + k0,                  &sB[nb][ldst]);
            async16(gB + (size_t)64 * K + k0, &sB[nb][2048 + ldst]);
        }
        const int cb = ks & 1;
        h8 af[4], bf[4];
        #pragma unroll
        for (int mi = 0; mi < 4; ++mi)
            af[mi] = *(const h8*)(&sA[cb][(wm + mi * 16 + l16) * 32 + quad * 8]);
        #pragma unroll
        for (int ni = 0; ni < 4; ++ni)
            bf[ni] = *(const h8*)(&sB[cb][(wn + ni * 16 + l16) * 32 + quad * 8]);
        #pragma unroll
        for (int mi = 0; mi < 4; ++mi)
        #pragma unroll
        for (int ni = 0; ni < 4; ++ni)
            acc[mi][ni] = __builtin_amdgcn_mfma_f32_16x16x32_f16(af[mi], bf[ni], acc[mi][ni], 0, 0, 0);
    }

    #pragma unroll
    for (int ni = 0; ni < 4; ++ni) {
        int col = n0 + wn + ni * 16 + l16;
        float bvv = bias[col];
        float s = 0.0f, ss = 0.0f;
        #pragma unroll
        for (int mi = 0; mi < 4; ++mi) {
            #pragma unroll
            for (int r = 0; r < 4; ++r) {
                int row = m0 + wm + mi * 16 + quad * 4 + r;
                float v = acc[mi][ni][r] + bvv;
                if (MODE == 0) {
                    int b   = row / NCITY;
                    int tok = row - b * NCITY;
                    int which = col >> 7;
                    int h     = (col >> 4) & 7;
                    int bh    = b * 8 + h;
                    half_t hv = (half_t)v;
                    half_t* dst = (which == 0) ? (half_t*)out
                                : (which == 1) ? (half_t*)outK : (half_t*)outV;
                    dst[((size_t)bh * NCITY + tok) * 16 + l16] = hv;
                } else {
                    size_t off = (size_t)row * Nout + col;
                    float o = v + (float)res[off];
                    ((half_t*)out)[off] = (half_t)o;
                    s += o; ss += o * o;
                }
            }
        }
        if (MODE == 1) {
            s  += __shfl_xor(s, 16);  s  += __shfl_xor(s, 32);
            ss += __shfl_xor(ss, 16); ss += __shfl_xor(ss, 32);
            if (quad == 0) {
                atomicAdd(&stats[col], s);
                atomicAdd(&stats[128 + col], ss);
            }
        }
    }
}

// ---------------- fused BN1 + FF1(ReLU) + FF2 ----------------
// 512 threads / 8 waves, 80 KB LDS -> 2 blocks/CU = 16 waves/CU.
// BN1 scale table precomputed once (overlaid in sW1 before first stage).
// All LDS tiles quarter-XOR swizzled: h' = h ^ (((row>>1)&3)<<3)  (16B granules)
// -> conflict-free ds_read_b128. Weight chunks arrive pre-swizzled from prep.
__global__ __launch_bounds__(512, 4)
void ff_fused(half_t* __restrict__ y16, const float* __restrict__ st1,
              const float* __restrict__ g1, const float* __restrict__ be1,
              const half_t* __restrict__ w1, const half_t* __restrict__ w2,
              const float* __restrict__ bf1, const float* __restrict__ bf2,
              float* __restrict__ stats)
{
    __shared__ alignas(16) half_t sX[4][128 * 32];   // 32 KB  x' tile [kc][row*32+h']
    __shared__ alignas(16) half_t sW1[4][64 * 32];   // 16 KB  wf1 chunk image
    __shared__ alignas(16) half_t sW2[2][128 * 32];  // 16 KB  wf2 chunk image
    __shared__ alignas(16) half_t sH[2][128 * 32];   // 16 KB  relu chunk

    const int tid  = threadIdx.x;
    const int wave = tid >> 6, lane = tid & 63;
    const int quad = lane >> 4, l16 = lane & 15;
    const int m0 = blockIdx.x * 128;
    const int wr = wave >> 1;          // 0..3: 32-row group
    const int wc = wave & 1;           // col group

    const float invN = 1.0f / (float)TROWS;

    // BN1 scale/shift table (1 KB, overlaid in sW1; consumed before first stage)
    float* sBN = (float*)&sW1[0][0];
    if (tid < 128) {
        float mean = st1[tid] * invN;
        float var  = st1[128 + tid] * invN - mean * mean;
        float scl  = g1[tid] * rsqrtf(var + 1e-5f);
        sBN[tid]       = scl;
        sBN[128 + tid] = be1[tid] - mean * scl;
    }
    __syncthreads();

    // stage x' = BN1(y16) -> sX (swizzled); one (row, quarter) per thread, 4 kc each
    {
        const int row = tid >> 2;            // 0..127
        const int q   = tid & 3;
        const int qs  = ((q ^ (row >> 1)) & 3) << 3;
        const half_t* src = y16 + (size_t)(m0 + row) * 128 + q * 8;
        #pragma unroll
        for (int kc = 0; kc < 4; ++kc) {
            h8 v = *(const h8*)(src + kc * 32);
            h8 xv;
            #pragma unroll
            for (int r = 0; r < 8; ++r) {
                int c = kc * 32 + q * 8 + r;
                xv[r] = (half_t)((float)v[r] * sBN[c] + sBN[128 + c]);
            }
            *(h8*)(&sX[kc][row * 32 + qs]) = xv;
        }
    }

    const int so = wave * 512 + lane * 8;    // halves: flat stage offset per round

    f32x4 acc2[2][4] = {};

    for (int j = 0; j < 8; ++j) {
        __syncthreads();   // j=0: sBN consumed + sX visible; j>0: FF1/FF2(j-1) done with sW/sH
        {
            const half_t* w1c = w1 + (size_t)j * 8192;
            const half_t* w2c = w2 + (size_t)j * 8192;
            async16(w1c + so,        &sW1[0][wave * 512]);
            async16(w1c + so + 4096, &sW1[2][wave * 512]);
            async16(w2c + so,        &sW2[0][wave * 512]);
            async16(w2c + so + 4096, &sW2[1][wave * 512]);
        }
        __syncthreads();   // staging drained (vmcnt(0) at barrier)

        // FF1: wave tile 32x32 of 128x64 chunk
        f32x4 acc1[2][2] = {};
        #pragma unroll
        for (int kc = 0; kc < 4; ++kc) {
            h8 af[2], bf[2];
            #pragma unroll
            for (int mi = 0; mi < 2; ++mi) {
                int r = wr * 32 + mi * 16 + l16;
                af[mi] = *(const h8*)(&sX[kc][r * 32 + (((quad ^ (r >> 1)) & 3) << 3)]);
            }
            #pragma unroll
            for (int ni = 0; ni < 2; ++ni) {
                int n = wc * 32 + ni * 16 + l16;
                bf[ni] = *(const h8*)(&sW1[kc][n * 32 + (((quad ^ (n >> 1)) & 3) << 3)]);
            }
            #pragma unroll
            for (int mi = 0; mi < 2; ++mi)
            #pragma unroll
            for (int ni = 0; ni < 2; ++ni)
                acc1[mi][ni] = __builtin_amdgcn_mfma_f32_16x16x32_f16(af[mi], bf[ni], acc1[mi][ni], 0, 0, 0);
        }
        // bias + ReLU -> sH (swizzled scalar writes)
        #pragma unroll
        for (int ni = 0; ni < 2; ++ni) {
            int c = wc * 32 + ni * 16 + l16;       // 0..63
            float bvv = bf1[j * 64 + c];
            int kc2 = c >> 5, c5 = c & 31;
            #pragma unroll
            for (int mi = 0; mi < 2; ++mi)
            #pragma unroll
            for (int r = 0; r < 4; ++r) {
                int row = wr * 32 + mi * 16 + quad * 4 + r;
                float v = acc1[mi][ni][r] + bvv;
                v = v > 0.0f ? v : 0.0f;
                int hsw = (c5 & 7) | ((((c5 >> 3) ^ (row >> 1)) & 3) << 3);
                sH[kc2][row * 32 + hsw] = (half_t)v;
            }
        }
        __syncthreads();   // sH visible

        // FF2 partial: wave tile 32x64, K-slice 64
        #pragma unroll
        for (int kc = 0; kc < 2; ++kc) {
            h8 af[2], bf[4];
            #pragma unroll
            for (int mi = 0; mi < 2; ++mi) {
                int r = wr * 32 + mi * 16 + l16;
                af[mi] = *(const h8*)(&sH[kc][r * 32 + (((quad ^ (r >> 1)) & 3) << 3)]);
            }
            #pragma unroll
            for (int ni = 0; ni < 4; ++ni) {
                int n = wc * 64 + ni * 16 + l16;
                bf[ni] = *(const h8*)(&sW2[kc][n * 32 + (((quad ^ (n >> 1)) & 3) << 3)]);
            }
            #pragma unroll
            for (int mi = 0; mi < 2; ++mi)
            #pragma unroll
            for (int ni = 0; ni < 4; ++ni)
                acc2[mi][ni] = __builtin_amdgcn_mfma_f32_16x16x32_f16(af[mi], bf[ni], acc2[mi][ni], 0, 0, 0);
        }
    }

    // epilogue: y2 = acc2 + bf2 + x' (x' recomputed from y16), BN2 stats
    __syncthreads();                       // sH reads done -> reuse as reduction scratch
    float* red = (float*)&sH[0][0];        // [2][512] floats (s, ss)

    #pragma unroll
    for (int ni = 0; ni < 4; ++ni) {
        int col = wc * 64 + ni * 16 + l16;
        float bvv = bf2[col];
        float mean = st1[col] * invN;
        float var  = st1[128 + col] * invN - mean * mean;
        float scl  = g1[col] * rsqrtf(var + 1e-5f);
        float shf  = be1[col] - mean * scl;
        float s = 0.0f, ss = 0.0f;
        #pragma unroll
        for (int mi = 0; mi < 2; ++mi) {
            #pragma unroll
            for (int r = 0; r < 4; ++r) {
                int row = m0 + wr * 32 + mi * 16 + quad * 4 + r;
                size_t off = (size_t)row * 128 + col;
                float xv = (float)y16[off] * scl + shf;
                float o = acc2[mi][ni][r] + bvv + xv;
                y16[off] = (half_t)o;
                s += o; ss += o * o;
            }
        }
        s  += __shfl_xor(s, 16);  s  += __shfl_xor(s, 32);
        ss += __shfl_xor(ss, 16); ss += __shfl_xor(ss, 32);
        if (quad == 0) {
            red[wave * 64 + ni * 16 + l16]       = s;
            red[512 + wave * 64 + ni * 16 + l16] = ss;
        }
    }
    __syncthreads();
    if (tid < 256) {
        int a   = tid >> 7;          // 0 = s, 1 = ss
        int col = tid & 127;
        int wcc = col >> 6, nii = (col >> 4) & 3, lx = col & 15;
        float t = 0.0f;
        #pragma unroll
        for (int w = 0; w < 4; ++w)
            t += red[a * 512 + (w * 2 + wcc) * 64 + nii * 16 + lx];
        atomicAdd(&stats[a * 128 + col], t);
    }
}

// ---------------- LDS-free fp16 MFMA attention: one wave per (bh, q-tile) ----------------
__global__ __launch_bounds__(256)
void attn_kernel(const half_t* __restrict__ Qh, const half_t* __restrict__ Kh,
                 const half_t* __restrict__ V, half_t* __restrict__ oh)
{
    const int wid = blockIdx.x * 4 + (threadIdx.x >> 6);
    const int bh = wid / 7;
    const int it = wid - bh * 7;
    if (bh >= NBH) return;
    const int b = bh >> 3, h = bh & 7;

    const int lane = threadIdx.x & 63, quad = lane >> 4, l16 = lane & 15;
    const int s0 = (((quad & 1) * 2)    ) * 16 + l16;
    const int s1 = (((quad & 1) * 2) + 1) * 16 + l16;
    const bool hi2 = (quad >> 1) != 0;

    const half_t* qbase = Qh + (size_t)bh * NCITY * 16;
    const half_t* kbase = Kh + (size_t)bh * NCITY * 16;
    const half_t* vbase = V  + (size_t)bh * NCITY * 16;

    h8 qf = {};
    if (quad < 2)
        qf = *reinterpret_cast<const h8*>(qbase + (it * 16 + l16) * 16 + quad * 8);

    f32x4 S[7];
    #pragma unroll
    for (int jt = 0; jt < 7; ++jt) {
        h8 kf = {};
        if (quad < 2)
            kf = *reinterpret_cast<const h8*>(kbase + (jt * 16 + l16) * 16 + quad * 8);
        f32x4 a = {};
        a = __builtin_amdgcn_mfma_f32_16x16x32_f16(kf, qf, a, 0, 0, 0);
        S[jt] = a;
    }
    float m = -1e30f;
    #pragma unroll
    for (int jt = 0; jt < 7; ++jt)
        #pragma unroll
        for (int r = 0; r < 4; ++r) {
            int jg = jt * 16 + quad * 4 + r;
            float sv = (jg < NCITY) ? S[jt][r] * 0.25f : -1e30f;
            S[jt][r] = sv;
            m = fmaxf(m, sv);
        }
    m = fmaxf(m, __shfl_xor(m, 16));
    m = fmaxf(m, __shfl_xor(m, 32));
    float sum = 0.0f;
    #pragma unroll
    for (int jt = 0; jt < 7; ++jt)
        #pragma unroll
        for (int r = 0; r < 4; ++r) {
            float e = __expf(S[jt][r] - m);
            S[jt][r] = e;
            sum += e;
        }
    sum += __shfl_xor(sum, 16);
    sum += __shfl_xor(sum, 32);
    float inv = 1.0f / sum;
    #pragma unroll
    for (int jt = 0; jt < 7; ++jt)
        #pragma unroll
        for (int r = 0; r < 4; ++r) S[jt][r] *= inv;

    f32x4 O = {};
    #pragma unroll
    for (int p = 0; p < 4; ++p) {
        h8 vf;
        #pragma unroll
        for (int jj = 0; jj < 8; ++jj)
            vf[jj] = vbase[(size_t)(p * 32 + quad * 8 + jj) * 16 + l16];
        float pj[8];
        #pragma unroll
        for (int r = 0; r < 4; ++r) {
            float a0 = __shfl(S[2 * p][r],     s0);
            float b0 = __shfl(S[2 * p + 1][r], s0);
            float a1 = __shfl(S[2 * p][r],     s1);
            float b1 = __shfl(S[2 * p + 1][r], s1);
            pj[r]     = hi2 ? b0 : a0;
            pj[4 + r] = hi2 ? b1 : a1;
        }
        h8 ph;
        #pragma unroll
        for (int jj = 0; jj < 8; ++jj)
            ph[jj] = (half_t)pj[jj];
        O = __builtin_amdgcn_mfma_f32_16x16x32_f16(ph, vf, O, 0, 0, 0);
    }
    #pragma unroll
    for (int r = 0; r < 4; ++r) {
        int q = it * 16 + quad * 4 + r;
        if (q < NCITY)
            oh[((size_t)b * NCITY + q) * 128 + h * 16 + l16] = (half_t)O[r];
    }
}

// ---------------- BatchNorm apply (finalize folded in) ----------------
__global__ __launch_bounds__(256)
void bn_apply(const h8* __restrict__ y, const float* __restrict__ stats,
              const float* __restrict__ g, const float* __restrict__ be,
              half_t* __restrict__ xh, float* __restrict__ dst32)
{
    __shared__ float sh[256];
    const int tid = threadIdx.x;
    if (tid < 128) {
        const float invN = 1.0f / (float)TROWS;
        float mean = stats[tid] * invN;
        float var  = stats[128 + tid] * invN - mean * mean;
        float inv  = rsqrtf(var + 1e-5f);
        float scl  = g[tid] * inv;
        sh[tid]       = scl;
        sh[128 + tid] = be[tid] - mean * scl;
    }
    __syncthreads();

    int gid = blockIdx.x * 256 + tid;   // over TROWS*16 (8 ch each)
    int c = (gid & 15) * 8;
    h8 v = y[gid];
    h8 hv;
    float o[8];
    #pragma unroll
    for (int r = 0; r < 8; ++r) {
        o[r] = (float)v[r] * sh[c + r] + sh[128 + c + r];
        hv[r] = (half_t)o[r];
    }
    *reinterpret_cast<h8*>(xh + (size_t)gid * 8) = hv;
    if (dst32) {
        f32x4 lo = { o[0], o[1], o[2], o[3] };
        f32x4 hi = { o[4], o[5], o[6], o[7] };
        ((f32x4*)dst32)[gid * 2]     = lo;
        ((f32x4*)dst32)[gid * 2 + 1] = hi;
    }
}

// ---------------- launch ----------------
extern "C" void kernel_launch(void* const* d_in, const int* in_sizes, int n_in,
                              void* d_out, int out_size, void* d_ws, size_t ws_size,
                              hipStream_t stream)
{
    const float* s    = (const float*)d_in[0];
    const int*   dd   = (const int*)d_in[1];
    const float* e_w  = (const float*)d_in[2];
    const float* e_b  = (const float*)d_in[3];
    const float* ep_w = (const float*)d_in[4];
    const float* ep_b = (const float*)d_in[5];
    const float* Wq   = (const float*)d_in[6];
    const float* bq   = (const float*)d_in[7];
    const float* Wk   = (const float*)d_in[8];
    const float* bk   = (const float*)d_in[9];
    const float* Wv   = (const float*)d_in[10];
    const float* bv   = (const float*)d_in[11];
    const float* Wo   = (const float*)d_in[12];
    const float* bo   = (const float*)d_in[13];
    const float* Wf1  = (const float*)d_in[14];
    const float* bf1  = (const float*)d_in[15];
    const float* Wf2  = (const float*)d_in[16];
    const float* bf2  = (const float*)d_in[17];
    const float* g1   = (const float*)d_in[18];
    const float* be1  = (const float*)d_in[19];
    const float* g2   = (const float*)d_in[20];
    const float* be2  = (const float*)d_in[21];

    char* ws = (char*)d_ws;
    size_t off = 0;
    auto alloc = [&](size_t bytes) -> void* {
        void* p = ws + off;
        off += (bytes + 255) & ~(size_t)255;
        return p;
    };
    half_t* y16   = (half_t*)alloc((size_t)TROWS * 128 * 2);
    half_t* xh    = (half_t*)alloc((size_t)TROWS * 128 * 2);
    half_t* Qh    = (half_t*)alloc((size_t)NBH * NCITY * 16 * 2);
    half_t* Kh    = (half_t*)alloc((size_t)NBH * NCITY * 16 * 2);
    half_t* Vb    = (half_t*)alloc((size_t)NBH * NCITY * 16 * 2);
    half_t* oh    = (half_t*)alloc((size_t)TROWS * 128 * 2);
    half_t* wqkv  = (half_t*)alloc((size_t)3 * 384 * 128 * 2);
    half_t* wo    = (half_t*)alloc((size_t)3 * 128 * 128 * 2);
    half_t* wf1   = (half_t*)alloc((size_t)3 * 512 * 128 * 2);
    half_t* wf2   = (half_t*)alloc((size_t)3 * 128 * 512 * 2);
    float*  bqkv  = (float*) alloc((size_t)3 * 384 * 4);
    float*  stats = (float*) alloc(6 * 256 * 4);

    dim3 blk(256);

    hipMemsetAsync(stats, 0, 6 * 256 * 4, stream);

    prep_kernel<<<dim3(768, 7), blk, 0, stream>>>(Wq, Wk, Wv, Wo, Wf1, Wf2, bq, bk, bv,
                                                  wqkv, wo, wf1, wf2, bqkv);

    embed_kernel<<<dim3(TROWS * 128 / 256), blk, 0, stream>>>(s, dd, e_w, e_b, ep_w, ep_b, xh);

    for (int l = 0; l < 3; ++l) {
        float* st1 = stats + (size_t)(l * 2) * 256;
        float* st2 = stats + (size_t)(l * 2 + 1) * 256;
        // QKV -> Q/K/V all [bh][tok][16]
        gemm_tile<0, 4><<<dim3(3, 404), blk, 0, stream>>>(xh, wqkv + (size_t)l * 49152,
                                                          bqkv + l * 384, nullptr,
                                                          Qh, Kh, Vb, nullptr, 384);
        // attention (LDS-free fp16 MFMA)
        attn_kernel<<<dim3(7168), blk, 0, stream>>>(Qh, Kh, Vb, oh);
        // O-proj + bias + residual(xh) + fused BN1 stats -> y16
        gemm_tile<1, 4><<<dim3(1, 404), blk, 0, stream>>>(oh, wo + (size_t)l * 16384,
                                                          bo + l * 128, xh,
                                                          y16, nullptr, nullptr, st1, 128);
        // fused BN1-apply + FF1 + FF2 + residual + BN2 stats (in-place y16)
        ff_fused<<<dim3(404), dim3(512), 0, stream>>>(y16, st1, g1 + l * 128, be1 + l * 128,
                                                      wf1 + (size_t)l * 65536, wf2 + (size_t)l * 65536,
                                                      bf1 + l * 512, bf2 + l * 128, st2);
        // BN2 apply -> xh (+ fp32 out on last layer)
        bn_apply<<<dim3(TROWS * 16 / 256), blk, 0, stream>>>((const h8*)y16, st2,
                                                             g2 + l * 128, be2 + l * 128,
                                                             xh, (l == 2) ? (float*)d_out : nullptr);
    }
}

// Round 2
// 457.141 us; speedup vs baseline: 1.1261x; 1.0177x over previous
//
#include <hip/hip_runtime.h>
#include <hip/hip_fp16.h>
#include <stdint.h>

#define TROWS 51712   // 512*101
#define NCITY 101
#define BATCH 512
#define EDIM  128
#define NBH   4096    // BATCH*8 heads

using half_t = _Float16;
typedef __attribute__((ext_vector_type(8))) _Float16 h8;
typedef __attribute__((ext_vector_type(4))) _Float16 h4;
typedef __attribute__((ext_vector_type(4))) float   f32x4;

typedef __attribute__((address_space(1))) const unsigned int gu32;
typedef __attribute__((address_space(3))) unsigned int lu32;
static __device__ __forceinline__ void async16(const void* g, const void* l) {
    __builtin_amdgcn_global_load_lds((gu32*)g, (lu32*)(uint32_t)(uintptr_t)l, 16, 0, 0);
}

// ---------------- one-shot weight prep: all transposes + bias pack ----------------
// wf1/wf2 are stored as the per-chunk LDS images ff_fused stages flat via
// global_load_lds, with the quarter-XOR swizzle (q' = q ^ ((n>>1)&3)) baked in
// so that swizzled ds_read_b128 in ff_fused is bank-conflict-free.
__global__ __launch_bounds__(256)
void prep_kernel(const float* __restrict__ Wq, const float* __restrict__ Wk,
                 const float* __restrict__ Wv, const float* __restrict__ Wo,
                 const float* __restrict__ Wf1, const float* __restrict__ Wf2,
                 const float* __restrict__ bq, const float* __restrict__ bk,
                 const float* __restrict__ bv,
                 half_t* __restrict__ wqkv, half_t* __restrict__ wo,
                 half_t* __restrict__ wf1, half_t* __restrict__ wf2,
                 float* __restrict__ bqkv)
{
    const int which = blockIdx.y;
    const int gid = blockIdx.x * 256 + threadIdx.x;
    if (which <= 2) {
        if (gid >= 3 * 128 * 128) return;
        const float* src = (which == 0) ? Wq : (which == 1) ? Wk : Wv;
        int l = gid >> 14, r = gid & 16383, k = r >> 7, n = r & 127;
        wqkv[(size_t)l * 49152 + which * 16384 + n * 128 + k] = (half_t)src[gid];
    } else if (which == 3) {
        if (gid >= 3 * 128 * 128) return;
        int l = gid >> 14, r = gid & 16383, k = r >> 7, n = r & 127;
        wo[(size_t)l * 16384 + n * 128 + k] = (half_t)Wo[gid];
    } else if (which == 4) {
        // wf1 image: [l][j(8)][kc(4)][n(64)][h'(32)]
        // value(n,h') = Wf1[l][k = kc*32 + ((h'>>3)^((n>>1)&3))*8 + (h'&7)][j*64+n]
        if (gid >= 3 * 65536) return;
        int l = gid >> 16, u = gid & 65535;
        int j = u >> 13, kc = (u >> 11) & 3, n = (u >> 5) & 63, hp = u & 31;
        int k = kc * 32 + ((((hp >> 3) ^ (n >> 1)) & 3) << 3) + (hp & 7);
        wf1[(size_t)l * 65536 + u] = (half_t)Wf1[(size_t)(l * 128 + k) * 512 + j * 64 + n];
    } else if (which == 5) {
        // wf2 image: [l][j(8)][kc2(2)][n(128)][h'(32)]
        // value(n,h') = Wf2[l][kh = j*64 + kc2*32 + ((h'>>3)^((n>>1)&3))*8 + (h'&7)][n]
        if (gid >= 3 * 65536) return;
        int l = gid >> 16, u = gid & 65535;
        int j = u >> 13, kc = (u >> 12) & 1, n = (u >> 5) & 127, hp = u & 31;
        int kh = j * 64 + kc * 32 + ((((hp >> 3) ^ (n >> 1)) & 3) << 3) + (hp & 7);
        wf2[(size_t)l * 65536 + u] = (half_t)Wf2[(size_t)(l * 512 + kh) * 128 + n];
    } else {
        if (gid >= 3 * 384) return;
        int l = gid / 384, c = gid - l * 384;
        float v = (c < 128) ? bq[l * 128 + c]
                : (c < 256) ? bk[l * 128 + c - 128]
                            : bv[l * 128 + c - 256];
        bqkv[gid] = v;
    }
}

// ---------------- embedding (fp16 activation mirror only) ----------------
__global__ __launch_bounds__(256)
void embed_kernel(const float* __restrict__ s, const int* __restrict__ d,
                  const float* __restrict__ e_w, const float* __restrict__ e_b,
                  const float* __restrict__ ep_w, const float* __restrict__ ep_b,
                  half_t* __restrict__ xh)
{
    int gid = blockIdx.x * 256 + threadIdx.x;      // over TROWS*128
    int row = gid >> 7;
    int c   = gid & 127;
    int b = row / NCITY;
    int n = row - b * NCITY;
    const float* sp = s + ((size_t)b * NCITY + n) * 2;
    float v;
    if (n == 0) {
        v = sp[0] * ep_w[c] + sp[1] * ep_w[128 + c] + ep_b[c];
    } else {
        float dv = (float)d[b * NCITY + n];
        v = sp[0] * e_w[c] + sp[1] * e_w[128 + c] + dv * e_w[256 + c] + e_b[c];
    }
    xh[gid] = (half_t)v;
}

// ---------------- fp16 GEMM, 1-barrier double-buffered pipeline ----------------
// MODE 0: QKV — LDS-transpose epilogue, h8 stores to Q/K/V [bh][tok][16]
// MODE 1: out fp16 y = acc + bias + res(fp16), fused BN stats (O-proj)
template<int MODE, int KSTEPS>
__global__ __launch_bounds__(256)
void gemm_tile(const half_t* __restrict__ A, const half_t* __restrict__ B,
               const float* __restrict__ bias, const half_t* __restrict__ res,
               void* __restrict__ out, void* __restrict__ outK, void* __restrict__ outV,
               float* __restrict__ stats, int Nout)
{
    constexpr int K = KSTEPS * 32;
    // stage: sA = smem[0..8191] (2 bufs x 4096), sB = smem[8192..16383]
    // MODE 0 epilogue reuses smem as a 128x136 transpose tile (34 KB)
    constexpr int SMEMH = (MODE == 0) ? (128 * 136) : 16384;
    __shared__ alignas(16) half_t smem[SMEMH];
    half_t* sA = smem;
    half_t* sB = smem + 8192;

    const int tid  = threadIdx.x;
    const int wave = tid >> 6, lane = tid & 63;
    const int n0 = blockIdx.x * 128;
    const int m0 = blockIdx.y * 128;

    const int sr = wave * 16 + (lane >> 2);
    const int sc = (lane & 3) * 8;
    const half_t* gA = A + (size_t)(m0 + sr) * K + sc;
    const half_t* gB = B + (size_t)(n0 + sr) * K + sc;
    const int ldst = wave * 512;

    const int quad = lane >> 4, l16 = lane & 15;
    const int wm = (wave >> 1) * 64, wn = (wave & 1) * 64;

    f32x4 acc[4][4] = {};

    async16(gA,                  &sA[ldst]);
    async16(gA + (size_t)64 * K, &sA[2048 + ldst]);
    async16(gB,                  &sB[ldst]);
    async16(gB + (size_t)64 * K, &sB[2048 + ldst]);

    for (int ks = 0; ks < KSTEPS; ++ks) {
        __syncthreads();
        if (ks + 1 < KSTEPS) {
            const int k0 = (ks + 1) * 32;
            const int nb = (ks + 1) & 1;
            async16(gA + k0,                  &sA[nb * 4096 + ldst]);
            async16(gA + (size_t)64 * K + k0, &sA[nb * 4096 + 2048 + ldst]);
            async16(gB + k0,                  &sB[nb * 4096 + ldst]);
            async16(gB + (size_t)64 * K + k0, &sB[nb * 4096 + 2048 + ldst]);
        }
        const int cb = ks & 1;
        h8 af[4], bf[4];
        #pragma unroll
        for (int mi = 0; mi < 4; ++mi)
            af[mi] = *(const h8*)(&sA[cb * 4096 + (wm + mi * 16 + l16) * 32 + quad * 8]);
        #pragma unroll
        for (int ni = 0; ni < 4; ++ni)
            bf[ni] = *(const h8*)(&sB[cb * 4096 + (wn + ni * 16 + l16) * 32 + quad * 8]);
        #pragma unroll
        for (int mi = 0; mi < 4; ++mi)
        #pragma unroll
        for (int ni = 0; ni < 4; ++ni)
            acc[mi][ni] = __builtin_amdgcn_mfma_f32_16x16x32_f16(af[mi], bf[ni], acc[mi][ni], 0, 0, 0);
    }

    if (MODE == 0) {
        // LDS-transpose epilogue: stride 136 halves (16B-aligned rows) with
        // granule swizzle g' = g ^ ((row&8)>>2) -> conflict-free ds writes/reads.
        __syncthreads();   // all staging reads done; reuse smem
        half_t* sT = smem;
        #pragma unroll
        for (int ni = 0; ni < 4; ++ni) {
            int col = wn + ni * 16 + l16;
            float bvv = bias[n0 + col];
            #pragma unroll
            for (int mi = 0; mi < 4; ++mi) {
                #pragma unroll
                for (int r = 0; r < 4; ++r) {
                    int row = wm + mi * 16 + quad * 4 + r;
                    int g = (col >> 3) ^ ((row & 8) >> 2);
                    sT[row * 136 + g * 8 + (col & 7)] = (half_t)(acc[mi][ni][r] + bvv);
                }
            }
        }
        __syncthreads();
        half_t* dst = (blockIdx.x == 0) ? (half_t*)out
                    : (blockIdx.x == 1) ? (half_t*)outK : (half_t*)outV;
        #pragma unroll
        for (int i = 0; i < 8; ++i) {
            int u = tid + 256 * i;          // 2048 (row, chunk) units
            int row = u >> 4, chunk = u & 15;
            int g = chunk ^ ((row & 8) >> 2);
            h8 v = *(const h8*)(&sT[row * 136 + g * 8]);
            int rg = m0 + row;
            int bb = rg / NCITY, tok = rg - bb * NCITY;
            *(h8*)(dst + ((size_t)(bb * 8 + (chunk >> 1)) * NCITY + tok) * 16 + (chunk & 1) * 8) = v;
        }
    } else {
        #pragma unroll
        for (int ni = 0; ni < 4; ++ni) {
            int col = n0 + wn + ni * 16 + l16;
            float bvv = bias[col];
            float s = 0.0f, ss = 0.0f;
            #pragma unroll
            for (int mi = 0; mi < 4; ++mi) {
                #pragma unroll
                for (int r = 0; r < 4; ++r) {
                    int row = m0 + wm + mi * 16 + quad * 4 + r;
                    size_t off = (size_t)row * Nout + col;
                    float o = acc[mi][ni][r] + bvv + (float)res[off];
                    ((half_t*)out)[off] = (half_t)o;
                    s += o; ss += o * o;
                }
            }
            s  += __shfl_xor(s, 16);  s  += __shfl_xor(s, 32);
            ss += __shfl_xor(ss, 16); ss += __shfl_xor(ss, 32);
            if (quad == 0) {
                atomicAdd(&stats[col], s);
                atomicAdd(&stats[128 + col], ss);
            }
        }
    }
}

// ---------------- fused BN1 + FF1(ReLU) + FF2 ----------------
// 512 threads / 8 waves, 80 KB LDS -> 2 blocks/CU = 16 waves/CU.
// BN1 scale table precomputed once (overlaid in sW1 before first stage).
// All LDS tiles quarter-XOR swizzled: h' = h ^ (((row>>1)&3)<<3)  (16B granules)
// -> conflict-free ds_read_b128. Weight chunks arrive pre-swizzled from prep.
__global__ __launch_bounds__(512, 4)
void ff_fused(half_t* __restrict__ y16, const float* __restrict__ st1,
              const float* __restrict__ g1, const float* __restrict__ be1,
              const half_t* __restrict__ w1, const half_t* __restrict__ w2,
              const float* __restrict__ bf1, const float* __restrict__ bf2,
              float* __restrict__ stats)
{
    __shared__ alignas(16) half_t sX[4][128 * 32];   // 32 KB  x' tile [kc][row*32+h']
    __shared__ alignas(16) half_t sW1[4][64 * 32];   // 16 KB  wf1 chunk image
    __shared__ alignas(16) half_t sW2[2][128 * 32];  // 16 KB  wf2 chunk image
    __shared__ alignas(16) half_t sH[2][128 * 32];   // 16 KB  relu chunk

    const int tid  = threadIdx.x;
    const int wave = tid >> 6, lane = tid & 63;
    const int quad = lane >> 4, l16 = lane & 15;
    const int m0 = blockIdx.x * 128;
    const int wr = wave >> 1;          // 0..3: 32-row group
    const int wc = wave & 1;           // col group

    const float invN = 1.0f / (float)TROWS;

    // BN1 scale/shift table (1 KB, overlaid in sW1; consumed before first stage)
    float* sBN = (float*)&sW1[0][0];
    if (tid < 128) {
        float mean = st1[tid] * invN;
        float var  = st1[128 + tid] * invN - mean * mean;
        float scl  = g1[tid] * rsqrtf(var + 1e-5f);
        sBN[tid]       = scl;
        sBN[128 + tid] = be1[tid] - mean * scl;
    }
    __syncthreads();

    // stage x' = BN1(y16) -> sX (swizzled); one (row, quarter) per thread, 4 kc each
    {
        const int row = tid >> 2;            // 0..127
        const int q   = tid & 3;
        const int qs  = ((q ^ (row >> 1)) & 3) << 3;
        const half_t* src = y16 + (size_t)(m0 + row) * 128 + q * 8;
        #pragma unroll
        for (int kc = 0; kc < 4; ++kc) {
            h8 v = *(const h8*)(src + kc * 32);
            h8 xv;
            #pragma unroll
            for (int r = 0; r < 8; ++r) {
                int c = kc * 32 + q * 8 + r;
                xv[r] = (half_t)((float)v[r] * sBN[c] + sBN[128 + c]);
            }
            *(h8*)(&sX[kc][row * 32 + qs]) = xv;
        }
    }

    const int so = wave * 512 + lane * 8;    // halves: flat stage offset per round

    f32x4 acc2[2][4] = {};

    for (int j = 0; j < 8; ++j) {
        __syncthreads();   // j=0: sBN consumed + sX visible; j>0: FF1/FF2(j-1) done with sW/sH
        {
            const half_t* w1c = w1 + (size_t)j * 8192;
            const half_t* w2c = w2 + (size_t)j * 8192;
            async16(w1c + so,        &sW1[0][wave * 512]);
            async16(w1c + so + 4096, &sW1[2][wave * 512]);
            async16(w2c + so,        &sW2[0][wave * 512]);
            async16(w2c + so + 4096, &sW2[1][wave * 512]);
        }
        __syncthreads();   // staging drained (vmcnt(0) at barrier)

        // FF1: wave tile 32x32 of 128x64 chunk
        f32x4 acc1[2][2] = {};
        #pragma unroll
        for (int kc = 0; kc < 4; ++kc) {
            h8 af[2], bf[2];
            #pragma unroll
            for (int mi = 0; mi < 2; ++mi) {
                int r = wr * 32 + mi * 16 + l16;
                af[mi] = *(const h8*)(&sX[kc][r * 32 + (((quad ^ (r >> 1)) & 3) << 3)]);
            }
            #pragma unroll
            for (int ni = 0; ni < 2; ++ni) {
                int n = wc * 32 + ni * 16 + l16;
                bf[ni] = *(const h8*)(&sW1[kc][n * 32 + (((quad ^ (n >> 1)) & 3) << 3)]);
            }
            #pragma unroll
            for (int mi = 0; mi < 2; ++mi)
            #pragma unroll
            for (int ni = 0; ni < 2; ++ni)
                acc1[mi][ni] = __builtin_amdgcn_mfma_f32_16x16x32_f16(af[mi], bf[ni], acc1[mi][ni], 0, 0, 0);
        }
        // bias + ReLU -> sH (swizzled scalar writes)
        #pragma unroll
        for (int ni = 0; ni < 2; ++ni) {
            int c = wc * 32 + ni * 16 + l16;       // 0..63
            float bvv = bf1[j * 64 + c];
            int kc2 = c >> 5, c5 = c & 31;
            #pragma unroll
            for (int mi = 0; mi < 2; ++mi)
            #pragma unroll
            for (int r = 0; r < 4; ++r) {
                int row = wr * 32 + mi * 16 + quad * 4 + r;
                float v = acc1[mi][ni][r] + bvv;
                v = v > 0.0f ? v : 0.0f;
                int hsw = (c5 & 7) | ((((c5 >> 3) ^ (row >> 1)) & 3) << 3);
                sH[kc2][row * 32 + hsw] = (half_t)v;
            }
        }
        __syncthreads();   // sH visible

        // FF2 partial: wave tile 32x64, K-slice 64
        #pragma unroll
        for (int kc = 0; kc < 2; ++kc) {
            h8 af[2], bf[4];
            #pragma unroll
            for (int mi = 0; mi < 2; ++mi) {
                int r = wr * 32 + mi * 16 + l16;
                af[mi] = *(const h8*)(&sH[kc][r * 32 + (((quad ^ (r >> 1)) & 3) << 3)]);
            }
            #pragma unroll
            for (int ni = 0; ni < 4; ++ni) {
                int n = wc * 64 + ni * 16 + l16;
                bf[ni] = *(const h8*)(&sW2[kc][n * 32 + (((quad ^ (n >> 1)) & 3) << 3)]);
            }
            #pragma unroll
            for (int mi = 0; mi < 2; ++mi)
            #pragma unroll
            for (int ni = 0; ni < 4; ++ni)
                acc2[mi][ni] = __builtin_amdgcn_mfma_f32_16x16x32_f16(af[mi], bf[ni], acc2[mi][ni], 0, 0, 0);
        }
    }

    // epilogue: y2 = acc2 + bf2 + x' (x' recomputed from y16), BN2 stats
    __syncthreads();                       // sH reads done -> reuse as reduction scratch
    float* red = (float*)&sH[0][0];        // [2][512] floats (s, ss)

    #pragma unroll
    for (int ni = 0; ni < 4; ++ni) {
        int col = wc * 64 + ni * 16 + l16;
        float bvv = bf2[col];
        float mean = st1[col] * invN;
        float var  = st1[128 + col] * invN - mean * mean;
        float scl  = g1[col] * rsqrtf(var + 1e-5f);
        float shf  = be1[col] - mean * scl;
        float s = 0.0f, ss = 0.0f;
        #pragma unroll
        for (int mi = 0; mi < 2; ++mi) {
            #pragma unroll
            for (int r = 0; r < 4; ++r) {
                int row = m0 + wr * 32 + mi * 16 + quad * 4 + r;
                size_t off = (size_t)row * 128 + col;
                float xv = (float)y16[off] * scl + shf;
                float o = acc2[mi][ni][r] + bvv + xv;
                y16[off] = (half_t)o;
                s += o; ss += o * o;
            }
        }
        s  += __shfl_xor(s, 16);  s  += __shfl_xor(s, 32);
        ss += __shfl_xor(ss, 16); ss += __shfl_xor(ss, 32);
        if (quad == 0) {
            red[wave * 64 + ni * 16 + l16]       = s;
            red[512 + wave * 64 + ni * 16 + l16] = ss;
        }
    }
    __syncthreads();
    if (tid < 256) {
        int a   = tid >> 7;          // 0 = s, 1 = ss
        int col = tid & 127;
        int wcc = col >> 6, nii = (col >> 4) & 3, lx = col & 15;
        float t = 0.0f;
        #pragma unroll
        for (int w = 0; w < 4; ++w)
            t += red[a * 512 + (w * 2 + wcc) * 64 + nii * 16 + lx];
        atomicAdd(&stats[a * 128 + col], t);
    }
}

// ---------------- LDS-free fp16 MFMA attention: one wave per bh ----------------
// K tiles (7xh8) and V fragments (4xh8) hoisted to registers, reused across the
// 7 q-tiles; next q-tile prefetched under current tile's compute.
__global__ __launch_bounds__(256, 4)
void attn_kernel(const half_t* __restrict__ Qh, const half_t* __restrict__ Kh,
                 const half_t* __restrict__ V, half_t* __restrict__ oh)
{
    const int bh = blockIdx.x * 4 + (threadIdx.x >> 6);
    if (bh >= NBH) return;
    const int b = bh >> 3, h = bh & 7;

    const int lane = threadIdx.x & 63, quad = lane >> 4, l16 = lane & 15;
    const int s0 = (((quad & 1) * 2)    ) * 16 + l16;
    const int s1 = (((quad & 1) * 2) + 1) * 16 + l16;
    const bool hi2 = (quad >> 1) != 0;

    const half_t* qbase = Qh + (size_t)bh * NCITY * 16;
    const half_t* kbase = Kh + (size_t)bh * NCITY * 16;
    const half_t* vbase = V  + (size_t)bh * NCITY * 16;

    // hoist K tiles (reused across all q-tiles)
    h8 kf[7];
    #pragma unroll
    for (int jt = 0; jt < 7; ++jt) {
        kf[jt] = (h8){};
        if (quad < 2)
            kf[jt] = *reinterpret_cast<const h8*>(kbase + (jt * 16 + l16) * 16 + quad * 8);
    }
    // hoist V fragments
    h8 vt[4];
    #pragma unroll
    for (int p = 0; p < 4; ++p)
        #pragma unroll
        for (int jj = 0; jj < 8; ++jj)
            vt[p][jj] = vbase[(size_t)(p * 32 + quad * 8 + jj) * 16 + l16];

    h8 qf = {};
    if (quad < 2)
        qf = *reinterpret_cast<const h8*>(qbase + l16 * 16 + quad * 8);

    for (int it = 0; it < 7; ++it) {
        h8 qn = {};
        if (it < 6 && quad < 2)
            qn = *reinterpret_cast<const h8*>(qbase + ((it + 1) * 16 + l16) * 16 + quad * 8);

        f32x4 S[7];
        #pragma unroll
        for (int jt = 0; jt < 7; ++jt) {
            f32x4 a = {};
            a = __builtin_amdgcn_mfma_f32_16x16x32_f16(kf[jt], qf, a, 0, 0, 0);
            S[jt] = a;
        }
        float m = -1e30f;
        #pragma unroll
        for (int jt = 0; jt < 7; ++jt)
            #pragma unroll
            for (int r = 0; r < 4; ++r) {
                int jg = jt * 16 + quad * 4 + r;
                float sv = (jg < NCITY) ? S[jt][r] * 0.25f : -1e30f;
                S[jt][r] = sv;
                m = fmaxf(m, sv);
            }
        m = fmaxf(m, __shfl_xor(m, 16));
        m = fmaxf(m, __shfl_xor(m, 32));
        float sum = 0.0f;
        #pragma unroll
        for (int jt = 0; jt < 7; ++jt)
            #pragma unroll
            for (int r = 0; r < 4; ++r) {
                float e = __expf(S[jt][r] - m);
                S[jt][r] = e;
                sum += e;
            }
        sum += __shfl_xor(sum, 16);
        sum += __shfl_xor(sum, 32);
        float inv = 1.0f / sum;
        #pragma unroll
        for (int jt = 0; jt < 7; ++jt)
            #pragma unroll
            for (int r = 0; r < 4; ++r) S[jt][r] *= inv;

        f32x4 O = {};
        #pragma unroll
        for (int p = 0; p < 4; ++p) {
            float pj[8];
            #pragma unroll
            for (int r = 0; r < 4; ++r) {
                float a0 = __shfl(S[2 * p][r],     s0);
                float b0 = __shfl(S[2 * p + 1][r], s0);
                float a1 = __shfl(S[2 * p][r],     s1);
                float b1 = __shfl(S[2 * p + 1][r], s1);
                pj[r]     = hi2 ? b0 : a0;
                pj[4 + r] = hi2 ? b1 : a1;
            }
            h8 ph;
            #pragma unroll
            for (int jj = 0; jj < 8; ++jj)
                ph[jj] = (half_t)pj[jj];
            O = __builtin_amdgcn_mfma_f32_16x16x32_f16(ph, vt[p], O, 0, 0, 0);
        }
        #pragma unroll
        for (int r = 0; r < 4; ++r) {
            int q = it * 16 + quad * 4 + r;
            if (q < NCITY)
                oh[((size_t)b * NCITY + q) * 128 + h * 16 + l16] = (half_t)O[r];
        }
        qf = qn;
    }
}

// ---------------- BatchNorm apply (finalize folded in) ----------------
__global__ __launch_bounds__(256)
void bn_apply(const h8* __restrict__ y, const float* __restrict__ stats,
              const float* __restrict__ g, const float* __restrict__ be,
              half_t* __restrict__ xh, float* __restrict__ dst32)
{
    __shared__ float sh[256];
    const int tid = threadIdx.x;
    if (tid < 128) {
        const float invN = 1.0f / (float)TROWS;
        float mean = stats[tid] * invN;
        float var  = stats[128 + tid] * invN - mean * mean;
        float inv  = rsqrtf(var + 1e-5f);
        float scl  = g[tid] * inv;
        sh[tid]       = scl;
        sh[128 + tid] = be[tid] - mean * scl;
    }
    __syncthreads();

    int gid = blockIdx.x * 256 + tid;   // over TROWS*16 (8 ch each)
    int c = (gid & 15) * 8;
    h8 v = y[gid];
    h8 hv;
    float o[8];
    #pragma unroll
    for (int r = 0; r < 8; ++r) {
        o[r] = (float)v[r] * sh[c + r] + sh[128 + c + r];
        hv[r] = (half_t)o[r];
    }
    *reinterpret_cast<h8*>(xh + (size_t)gid * 8) = hv;
    if (dst32) {
        f32x4 lo = { o[0], o[1], o[2], o[3] };
        f32x4 hi = { o[4], o[5], o[6], o[7] };
        ((f32x4*)dst32)[gid * 2]     = lo;
        ((f32x4*)dst32)[gid * 2 + 1] = hi;
    }
}

// ---------------- launch ----------------
extern "C" void kernel_launch(void* const* d_in, const int* in_sizes, int n_in,
                              void* d_out, int out_size, void* d_ws, size_t ws_size,
                              hipStream_t stream)
{
    const float* s    = (const float*)d_in[0];
    const int*   dd   = (const int*)d_in[1];
    const float* e_w  = (const float*)d_in[2];
    const float* e_b  = (const float*)d_in[3];
    const float* ep_w = (const float*)d_in[4];
    const float* ep_b = (const float*)d_in[5];
    const float* Wq   = (const float*)d_in[6];
    const float* bq   = (const float*)d_in[7];
    const float* Wk   = (const float*)d_in[8];
    const float* bk   = (const float*)d_in[9];
    const float* Wv   = (const float*)d_in[10];
    const float* bv   = (const float*)d_in[11];
    const float* Wo   = (const float*)d_in[12];
    const float* bo   = (const float*)d_in[13];
    const float* Wf1  = (const float*)d_in[14];
    const float* bf1  = (const float*)d_in[15];
    const float* Wf2  = (const float*)d_in[16];
    const float* bf2  = (const float*)d_in[17];
    const float* g1   = (const float*)d_in[18];
    const float* be1  = (const float*)d_in[19];
    const float* g2   = (const float*)d_in[20];
    const float* be2  = (const float*)d_in[21];

    char* ws = (char*)d_ws;
    size_t off = 0;
    auto alloc = [&](size_t bytes) -> void* {
        void* p = ws + off;
        off += (bytes + 255) & ~(size_t)255;
        return p;
    };
    half_t* y16   = (half_t*)alloc((size_t)TROWS * 128 * 2);
    half_t* xh    = (half_t*)alloc((size_t)TROWS * 128 * 2);
    half_t* Qh    = (half_t*)alloc((size_t)NBH * NCITY * 16 * 2);
    half_t* Kh    = (half_t*)alloc((size_t)NBH * NCITY * 16 * 2);
    half_t* Vb    = (half_t*)alloc((size_t)NBH * NCITY * 16 * 2);
    half_t* oh    = (half_t*)alloc((size_t)TROWS * 128 * 2);
    half_t* wqkv  = (half_t*)alloc((size_t)3 * 384 * 128 * 2);
    half_t* wo    = (half_t*)alloc((size_t)3 * 128 * 128 * 2);
    half_t* wf1   = (half_t*)alloc((size_t)3 * 512 * 128 * 2);
    half_t* wf2   = (half_t*)alloc((size_t)3 * 128 * 512 * 2);
    float*  bqkv  = (float*) alloc((size_t)3 * 384 * 4);
    float*  stats = (float*) alloc(6 * 256 * 4);

    dim3 blk(256);

    hipMemsetAsync(stats, 0, 6 * 256 * 4, stream);

    prep_kernel<<<dim3(768, 7), blk, 0, stream>>>(Wq, Wk, Wv, Wo, Wf1, Wf2, bq, bk, bv,
                                                  wqkv, wo, wf1, wf2, bqkv);

    embed_kernel<<<dim3(TROWS * 128 / 256), blk, 0, stream>>>(s, dd, e_w, e_b, ep_w, ep_b, xh);

    for (int l = 0; l < 3; ++l) {
        float* st1 = stats + (size_t)(l * 2) * 256;
        float* st2 = stats + (size_t)(l * 2 + 1) * 256;
        // QKV -> Q/K/V all [bh][tok][16]
        gemm_tile<0, 4><<<dim3(3, 404), blk, 0, stream>>>(xh, wqkv + (size_t)l * 49152,
                                                          bqkv + l * 384, nullptr,
                                                          Qh, Kh, Vb, nullptr, 384);
        // attention (LDS-free fp16 MFMA, one wave per bh)
        attn_kernel<<<dim3(1024), blk, 0, stream>>>(Qh, Kh, Vb, oh);
        // O-proj + bias + residual(xh) + fused BN1 stats -> y16
        gemm_tile<1, 4><<<dim3(1, 404), blk, 0, stream>>>(oh, wo + (size_t)l * 16384,
                                                          bo + l * 128, xh,
                                                          y16, nullptr, nullptr, st1, 128);
        // fused BN1-apply + FF1 + FF2 + residual + BN2 stats (in-place y16)
        ff_fused<<<dim3(404), dim3(512), 0, stream>>>(y16, st1, g1 + l * 128, be1 + l * 128,
                                                      wf1 + (size_t)l * 65536, wf2 + (size_t)l * 65536,
                                                      bf1 + l * 512, bf2 + l * 128, st2);
        // BN2 apply -> xh (+ fp32 out on last layer)
        bn_apply<<<dim3(TROWS * 16 / 256), blk, 0, stream>>>((const h8*)y16, st2,
                                                             g2 + l * 128, be2 + l * 128,
                                                             xh, (l == 2) ? (float*)d_out : nullptr);
    }
}

// Round 3
// 453.373 us; speedup vs baseline: 1.1355x; 1.0083x over previous
//
#include <hip/hip_runtime.h>
#include <hip/hip_fp16.h>
#include <stdint.h>

#define TROWS 51712   // 512*101
#define NCITY 101
#define BATCH 512
#define EDIM  128
#define NBH   4096    // BATCH*8 heads

using half_t = _Float16;
typedef __attribute__((ext_vector_type(8))) _Float16 h8;
typedef __attribute__((ext_vector_type(4))) _Float16 h4;
typedef __attribute__((ext_vector_type(4))) float   f32x4;

typedef __attribute__((address_space(1))) const unsigned int gu32;
typedef __attribute__((address_space(3))) unsigned int lu32;
static __device__ __forceinline__ void async16(const void* g, const void* l) {
    __builtin_amdgcn_global_load_lds((gu32*)g, (lu32*)(uint32_t)(uintptr_t)l, 16, 0, 0);
}

// Quarter-XOR image swizzle: element (row, c) of a [row][128] fp16 tensor is
// stored at column  c' = (c & ~31) | ((((c>>3) ^ (row>>1)) & 3) << 3) | (c & 7).
// Staged linearly into LDS [row][32] chunks, a ds_read_b128 at granule
// (quad ^ ((row>>1)&3)) returns the plain element -> conflict-free (ff-proven).
static __device__ __forceinline__ int swz_col(int c, int row) {
    return (c & ~31) | ((((c >> 3) ^ (row >> 1)) & 3) << 3) | (c & 7);
}

// ---------------- one-shot weight prep: all transposes + bias pack ----------------
__global__ __launch_bounds__(256)
void prep_kernel(const float* __restrict__ Wq, const float* __restrict__ Wk,
                 const float* __restrict__ Wv, const float* __restrict__ Wo,
                 const float* __restrict__ Wf1, const float* __restrict__ Wf2,
                 const float* __restrict__ bq, const float* __restrict__ bk,
                 const float* __restrict__ bv,
                 half_t* __restrict__ wqkv, half_t* __restrict__ wo,
                 half_t* __restrict__ wf1, half_t* __restrict__ wf2,
                 float* __restrict__ bqkv)
{
    const int which = blockIdx.y;
    const int gid = blockIdx.x * 256 + threadIdx.x;
    if (which <= 2) {
        if (gid >= 3 * 128 * 128) return;
        const float* src = (which == 0) ? Wq : (which == 1) ? Wk : Wv;
        int l = gid >> 14, r = gid & 16383, k = r >> 7, n = r & 127;
        wqkv[(size_t)l * 49152 + which * 16384 + n * 128 + swz_col(k, n)] = (half_t)src[gid];
    } else if (which == 3) {
        if (gid >= 3 * 128 * 128) return;
        int l = gid >> 14, r = gid & 16383, k = r >> 7, n = r & 127;
        wo[(size_t)l * 16384 + n * 128 + swz_col(k, n)] = (half_t)Wo[gid];
    } else if (which == 4) {
        // wf1 image: [l][j(8)][kc(4)][n(64)][h'(32)]
        if (gid >= 3 * 65536) return;
        int l = gid >> 16, u = gid & 65535;
        int j = u >> 13, kc = (u >> 11) & 3, n = (u >> 5) & 63, hp = u & 31;
        int k = kc * 32 + ((((hp >> 3) ^ (n >> 1)) & 3) << 3) + (hp & 7);
        wf1[(size_t)l * 65536 + u] = (half_t)Wf1[(size_t)(l * 128 + k) * 512 + j * 64 + n];
    } else if (which == 5) {
        // wf2 image: [l][j(8)][kc2(2)][n(128)][h'(32)]
        if (gid >= 3 * 65536) return;
        int l = gid >> 16, u = gid & 65535;
        int j = u >> 13, kc = (u >> 12) & 1, n = (u >> 5) & 127, hp = u & 31;
        int kh = j * 64 + kc * 32 + ((((hp >> 3) ^ (n >> 1)) & 3) << 3) + (hp & 7);
        wf2[(size_t)l * 65536 + u] = (half_t)Wf2[(size_t)(l * 512 + kh) * 128 + n];
    } else {
        if (gid >= 3 * 384) return;
        int l = gid / 384, c = gid - l * 384;
        float v = (c < 128) ? bq[l * 128 + c]
                : (c < 256) ? bk[l * 128 + c - 128]
                            : bv[l * 128 + c - 256];
        bqkv[gid] = v;
    }
}

// ---------------- embedding (writes swizzled xh image) ----------------
__global__ __launch_bounds__(256)
void embed_kernel(const float* __restrict__ s, const int* __restrict__ d,
                  const float* __restrict__ e_w, const float* __restrict__ e_b,
                  const float* __restrict__ ep_w, const float* __restrict__ ep_b,
                  half_t* __restrict__ xh)
{
    int gid = blockIdx.x * 256 + threadIdx.x;      // over TROWS*128
    int row = gid >> 7;
    int c   = gid & 127;
    int b = row / NCITY;
    int n = row - b * NCITY;
    const float* sp = s + ((size_t)b * NCITY + n) * 2;
    float v;
    if (n == 0) {
        v = sp[0] * ep_w[c] + sp[1] * ep_w[128 + c] + ep_b[c];
    } else {
        float dv = (float)d[b * NCITY + n];
        v = sp[0] * e_w[c] + sp[1] * e_w[128 + c] + dv * e_w[256 + c] + e_b[c];
    }
    xh[(size_t)row * 128 + swz_col(c, row)] = (half_t)v;
}

// ---------------- fp16 GEMM, 1-barrier double-buffered pipeline ----------------
// A and B are swizzled images; fragment reads apply the matching XOR -> conflict-free.
// MODE 0: QKV — LDS-transpose epilogue, h8 stores to Q/K/V [bh][tok][16] (plain)
// MODE 1: out fp16 y(plain) = acc + bias + res(image), fused BN stats (O-proj)
template<int MODE, int KSTEPS>
__global__ __launch_bounds__(256)
void gemm_tile(const half_t* __restrict__ A, const half_t* __restrict__ B,
               const float* __restrict__ bias, const half_t* __restrict__ res,
               void* __restrict__ out, void* __restrict__ outK, void* __restrict__ outV,
               float* __restrict__ stats, int Nout)
{
    constexpr int K = KSTEPS * 32;
    constexpr int SMEMH = (MODE == 0) ? (128 * 136) : 16384;
    __shared__ alignas(16) half_t smem[SMEMH];
    half_t* sA = smem;
    half_t* sB = smem + 8192;

    const int tid  = threadIdx.x;
    const int wave = tid >> 6, lane = tid & 63;
    const int n0 = blockIdx.x * 128;
    const int m0 = blockIdx.y * 128;

    const int sr = wave * 16 + (lane >> 2);
    const int sc = (lane & 3) * 8;
    const half_t* gA = A + (size_t)(m0 + sr) * K + sc;
    const half_t* gB = B + (size_t)(n0 + sr) * K + sc;
    const int ldst = wave * 512;

    const int quad = lane >> 4, l16 = lane & 15;
    const int wm = (wave >> 1) * 64, wn = (wave & 1) * 64;

    f32x4 acc[4][4] = {};

    async16(gA,                  &sA[ldst]);
    async16(gA + (size_t)64 * K, &sA[2048 + ldst]);
    async16(gB,                  &sB[ldst]);
    async16(gB + (size_t)64 * K, &sB[2048 + ldst]);

    for (int ks = 0; ks < KSTEPS; ++ks) {
        __syncthreads();
        if (ks + 1 < KSTEPS) {
            const int k0 = (ks + 1) * 32;
            const int nb = (ks + 1) & 1;
            async16(gA + k0,                  &sA[nb * 4096 + ldst]);
            async16(gA + (size_t)64 * K + k0, &sA[nb * 4096 + 2048 + ldst]);
            async16(gB + k0,                  &sB[nb * 4096 + ldst]);
            async16(gB + (size_t)64 * K + k0, &sB[nb * 4096 + 2048 + ldst]);
        }
        const int cb = ks & 1;
        h8 af[4], bf[4];
        #pragma unroll
        for (int mi = 0; mi < 4; ++mi) {
            int r = wm + mi * 16 + l16;
            af[mi] = *(const h8*)(&sA[cb * 4096 + r * 32 + (((quad ^ (r >> 1)) & 3) << 3)]);
        }
        #pragma unroll
        for (int ni = 0; ni < 4; ++ni) {
            int n = wn + ni * 16 + l16;
            bf[ni] = *(const h8*)(&sB[cb * 4096 + n * 32 + (((quad ^ (n >> 1)) & 3) << 3)]);
        }
        #pragma unroll
        for (int mi = 0; mi < 4; ++mi)
        #pragma unroll
        for (int ni = 0; ni < 4; ++ni)
            acc[mi][ni] = __builtin_amdgcn_mfma_f32_16x16x32_f16(af[mi], bf[ni], acc[mi][ni], 0, 0, 0);
    }

    if (MODE == 0) {
        // LDS-transpose epilogue: stride 136 halves, granule swizzle -> conflict-free.
        __syncthreads();
        half_t* sT = smem;
        #pragma unroll
        for (int ni = 0; ni < 4; ++ni) {
            int col = wn + ni * 16 + l16;
            float bvv = bias[n0 + col];
            #pragma unroll
            for (int mi = 0; mi < 4; ++mi) {
                #pragma unroll
                for (int r = 0; r < 4; ++r) {
                    int row = wm + mi * 16 + quad * 4 + r;
                    int g = (col >> 3) ^ ((row & 8) >> 2);
                    sT[row * 136 + g * 8 + (col & 7)] = (half_t)(acc[mi][ni][r] + bvv);
                }
            }
        }
        __syncthreads();
        half_t* dst = (blockIdx.x == 0) ? (half_t*)out
                    : (blockIdx.x == 1) ? (half_t*)outK : (half_t*)outV;
        #pragma unroll
        for (int i = 0; i < 8; ++i) {
            int u = tid + 256 * i;          // 2048 (row, chunk) units
            int row = u >> 4, chunk = u & 15;
            int g = chunk ^ ((row & 8) >> 2);
            h8 v = *(const h8*)(&sT[row * 136 + g * 8]);
            int rg = m0 + row;
            int bb = rg / NCITY, tok = rg - bb * NCITY;
            *(h8*)(dst + ((size_t)(bb * 8 + (chunk >> 1)) * NCITY + tok) * 16 + (chunk & 1) * 8) = v;
        }
    } else {
        #pragma unroll
        for (int ni = 0; ni < 4; ++ni) {
            int col = n0 + wn + ni * 16 + l16;
            float bvv = bias[col];
            float s = 0.0f, ss = 0.0f;
            #pragma unroll
            for (int mi = 0; mi < 4; ++mi) {
                #pragma unroll
                for (int r = 0; r < 4; ++r) {
                    int row = m0 + wm + mi * 16 + quad * 4 + r;
                    size_t off = (size_t)row * Nout + col;
                    float o = acc[mi][ni][r] + bvv + (float)res[(size_t)row * Nout + swz_col(col, row)];
                    ((half_t*)out)[off] = (half_t)o;
                    s += o; ss += o * o;
                }
            }
            s  += __shfl_xor(s, 16);  s  += __shfl_xor(s, 32);
            ss += __shfl_xor(ss, 16); ss += __shfl_xor(ss, 32);
            if (quad == 0) {
                atomicAdd(&stats[col], s);
                atomicAdd(&stats[128 + col], ss);
            }
        }
    }
}

// ---------------- fused BN1 + FF1(ReLU) + FF2 ----------------
// 512 threads / 8 waves, 80 KB LDS -> 2 blocks/CU.
// Weights reg-staged (T14): next round's 4x dwordx4 loads issued under compute,
// ds_write after raw barrier + lgkmcnt(0)-only wait -> global loads never drained.
__global__ __launch_bounds__(512, 4)
void ff_fused(half_t* __restrict__ y16, const float* __restrict__ st1,
              const float* __restrict__ g1, const float* __restrict__ be1,
              const half_t* __restrict__ w1, const half_t* __restrict__ w2,
              const float* __restrict__ bf1, const float* __restrict__ bf2,
              float* __restrict__ stats)
{
    __shared__ alignas(16) half_t sX[4][128 * 32];   // 32 KB  x' tile
    __shared__ alignas(16) half_t sW1f[8192];        // 16 KB  wf1 chunk image (flat)
    __shared__ alignas(16) half_t sW2f[8192];        // 16 KB  wf2 chunk image (flat)
    __shared__ alignas(16) half_t sH[2][128 * 32];   // 16 KB  relu chunk

    const int tid  = threadIdx.x;
    const int wave = tid >> 6, lane = tid & 63;
    const int quad = lane >> 4, l16 = lane & 15;
    const int m0 = blockIdx.x * 128;
    const int wr = wave >> 1;          // 0..3: 32-row group
    const int wc = wave & 1;           // col group

    const float invN = 1.0f / (float)TROWS;
    const int so = wave * 512 + lane * 8;    // identity global<->LDS offset

    // prologue: round-0 weight regs
    h8 rw1a = *(const h8*)(w1 + so);
    h8 rw1b = *(const h8*)(w1 + so + 4096);
    h8 rw2a = *(const h8*)(w2 + so);
    h8 rw2b = *(const h8*)(w2 + so + 4096);

    // BN1 scale/shift table (1 KB, overlaid in sW1f; dead after sX stage)
    float* sBN = (float*)&sW1f[0];
    if (tid < 128) {
        float mean = st1[tid] * invN;
        float var  = st1[128 + tid] * invN - mean * mean;
        float scl  = g1[tid] * rsqrtf(var + 1e-5f);
        sBN[tid]       = scl;
        sBN[128 + tid] = be1[tid] - mean * scl;
    }
    __syncthreads();

    // stage x' = BN1(y16) -> sX (swizzled)
    {
        const int row = tid >> 2;            // 0..127
        const int q   = tid & 3;
        const int qs  = ((q ^ (row >> 1)) & 3) << 3;
        const half_t* src = y16 + (size_t)(m0 + row) * 128 + q * 8;
        #pragma unroll
        for (int kc = 0; kc < 4; ++kc) {
            h8 v = *(const h8*)(src + kc * 32);
            h8 xv;
            #pragma unroll
            for (int r = 0; r < 8; ++r) {
                int c = kc * 32 + q * 8 + r;
                xv[r] = (half_t)((float)v[r] * sBN[c] + sBN[128 + c]);
            }
            *(h8*)(&sX[kc][row * 32 + qs]) = xv;
        }
    }

    f32x4 acc2[2][4] = {};

    for (int j = 0; j < 8; ++j) {
        // b1: FF2(j-1) done reading sW/sH; sX/sBN writes visible (j=0)
        asm volatile("s_waitcnt lgkmcnt(0)" ::: "memory");
        __builtin_amdgcn_s_barrier();
        __builtin_amdgcn_sched_barrier(0);
        // write W(j) from regs (compiler inserts the per-thread vmcnt waits)
        *(h8*)(&sW1f[so])        = rw1a;
        *(h8*)(&sW1f[so + 4096]) = rw1b;
        *(h8*)(&sW2f[so])        = rw2a;
        *(h8*)(&sW2f[so + 4096]) = rw2b;
        asm volatile("s_waitcnt lgkmcnt(0)" ::: "memory");
        __builtin_amdgcn_s_barrier();
        __builtin_amdgcn_sched_barrier(0);
        if (j < 7) {   // issue next round's loads; they fly under FF1+FF2
            const half_t* w1n = w1 + (size_t)(j + 1) * 8192;
            const half_t* w2n = w2 + (size_t)(j + 1) * 8192;
            rw1a = *(const h8*)(w1n + so);
            rw1b = *(const h8*)(w1n + so + 4096);
            rw2a = *(const h8*)(w2n + so);
            rw2b = *(const h8*)(w2n + so + 4096);
        }

        // FF1: wave tile 32x32 of 128x64 chunk
        f32x4 acc1[2][2] = {};
        #pragma unroll
        for (int kc = 0; kc < 4; ++kc) {
            h8 af[2], bf[2];
            #pragma unroll
            for (int mi = 0; mi < 2; ++mi) {
                int r = wr * 32 + mi * 16 + l16;
                af[mi] = *(const h8*)(&sX[kc][r * 32 + (((quad ^ (r >> 1)) & 3) << 3)]);
            }
            #pragma unroll
            for (int ni = 0; ni < 2; ++ni) {
                int n = wc * 32 + ni * 16 + l16;
                bf[ni] = *(const h8*)(&sW1f[kc * 2048 + n * 32 + (((quad ^ (n >> 1)) & 3) << 3)]);
            }
            #pragma unroll
            for (int mi = 0; mi < 2; ++mi)
            #pragma unroll
            for (int ni = 0; ni < 2; ++ni)
                acc1[mi][ni] = __builtin_amdgcn_mfma_f32_16x16x32_f16(af[mi], bf[ni], acc1[mi][ni], 0, 0, 0);
        }
        // bias + ReLU -> sH (swizzled scalar writes)
        #pragma unroll
        for (int ni = 0; ni < 2; ++ni) {
            int c = wc * 32 + ni * 16 + l16;       // 0..63
            float bvv = bf1[j * 64 + c];
            int kc2 = c >> 5, c5 = c & 31;
            #pragma unroll
            for (int mi = 0; mi < 2; ++mi)
            #pragma unroll
            for (int r = 0; r < 4; ++r) {
                int row = wr * 32 + mi * 16 + quad * 4 + r;
                float v = acc1[mi][ni][r] + bvv;
                v = v > 0.0f ? v : 0.0f;
                int hsw = (c5 & 7) | ((((c5 >> 3) ^ (row >> 1)) & 3) << 3);
                sH[kc2][row * 32 + hsw] = (half_t)v;
            }
        }
        asm volatile("s_waitcnt lgkmcnt(0)" ::: "memory");
        __builtin_amdgcn_s_barrier();
        __builtin_amdgcn_sched_barrier(0);

        // FF2 partial: wave tile 32x64, K-slice 64
        #pragma unroll
        for (int kc = 0; kc < 2; ++kc) {
            h8 af[2], bf[4];
            #pragma unroll
            for (int mi = 0; mi < 2; ++mi) {
                int r = wr * 32 + mi * 16 + l16;
                af[mi] = *(const h8*)(&sH[kc][r * 32 + (((quad ^ (r >> 1)) & 3) << 3)]);
            }
            #pragma unroll
            for (int ni = 0; ni < 4; ++ni) {
                int n = wc * 64 + ni * 16 + l16;
                bf[ni] = *(const h8*)(&sW2f[kc * 4096 + n * 32 + (((quad ^ (n >> 1)) & 3) << 3)]);
            }
            #pragma unroll
            for (int mi = 0; mi < 2; ++mi)
            #pragma unroll
            for (int ni = 0; ni < 4; ++ni)
                acc2[mi][ni] = __builtin_amdgcn_mfma_f32_16x16x32_f16(af[mi], bf[ni], acc2[mi][ni], 0, 0, 0);
        }
    }

    // epilogue: y2 = acc2 + bf2 + x' (x' recomputed from y16), BN2 stats
    __syncthreads();                       // sH reads done -> reuse as reduction scratch
    float* red = (float*)&sH[0][0];        // [2][512] floats (s, ss)

    #pragma unroll
    for (int ni = 0; ni < 4; ++ni) {
        int col = wc * 64 + ni * 16 + l16;
        float bvv = bf2[col];
        float mean = st1[col] * invN;
        float var  = st1[128 + col] * invN - mean * mean;
        float scl  = g1[col] * rsqrtf(var + 1e-5f);
        float shf  = be1[col] - mean * scl;
        float s = 0.0f, ss = 0.0f;
        #pragma unroll
        for (int mi = 0; mi < 2; ++mi) {
            #pragma unroll
            for (int r = 0; r < 4; ++r) {
                int row = m0 + wr * 32 + mi * 16 + quad * 4 + r;
                size_t off = (size_t)row * 128 + col;
                float xv = (float)y16[off] * scl + shf;
                float o = acc2[mi][ni][r] + bvv + xv;
                y16[off] = (half_t)o;
                s += o; ss += o * o;
            }
        }
        s  += __shfl_xor(s, 16);  s  += __shfl_xor(s, 32);
        ss += __shfl_xor(ss, 16); ss += __shfl_xor(ss, 32);
        if (quad == 0) {
            red[wave * 64 + ni * 16 + l16]       = s;
            red[512 + wave * 64 + ni * 16 + l16] = ss;
        }
    }
    __syncthreads();
    if (tid < 256) {
        int a   = tid >> 7;          // 0 = s, 1 = ss
        int col = tid & 127;
        int wcc = col >> 6, nii = (col >> 4) & 3, lx = col & 15;
        float t = 0.0f;
        #pragma unroll
        for (int w = 0; w < 4; ++w)
            t += red[a * 512 + (w * 2 + wcc) * 64 + nii * 16 + lx];
        atomicAdd(&stats[a * 128 + col], t);
    }
}

// ---------------- LDS-free fp16 MFMA attention: one wave per bh ----------------
// oh written as swizzled image (consumed as gemm1's A).
__global__ __launch_bounds__(256, 4)
void attn_kernel(const half_t* __restrict__ Qh, const half_t* __restrict__ Kh,
                 const half_t* __restrict__ V, half_t* __restrict__ oh)
{
    const int bh = blockIdx.x * 4 + (threadIdx.x >> 6);
    if (bh >= NBH) return;
    const int b = bh >> 3, h = bh & 7;

    const int lane = threadIdx.x & 63, quad = lane >> 4, l16 = lane & 15;
    const int s0 = (((quad & 1) * 2)    ) * 16 + l16;
    const int s1 = (((quad & 1) * 2) + 1) * 16 + l16;
    const bool hi2 = (quad >> 1) != 0;

    const half_t* qbase = Qh + (size_t)bh * NCITY * 16;
    const half_t* kbase = Kh + (size_t)bh * NCITY * 16;
    const half_t* vbase = V  + (size_t)bh * NCITY * 16;

    h8 kf[7];
    #pragma unroll
    for (int jt = 0; jt < 7; ++jt) {
        kf[jt] = (h8){};
        if (quad < 2)
            kf[jt] = *reinterpret_cast<const h8*>(kbase + (jt * 16 + l16) * 16 + quad * 8);
    }
    h8 vt[4];
    #pragma unroll
    for (int p = 0; p < 4; ++p)
        #pragma unroll
        for (int jj = 0; jj < 8; ++jj)
            vt[p][jj] = vbase[(size_t)(p * 32 + quad * 8 + jj) * 16 + l16];

    h8 qf = {};
    if (quad < 2)
        qf = *reinterpret_cast<const h8*>(qbase + l16 * 16 + quad * 8);

    for (int it = 0; it < 7; ++it) {
        h8 qn = {};
        if (it < 6 && quad < 2)
            qn = *reinterpret_cast<const h8*>(qbase + ((it + 1) * 16 + l16) * 16 + quad * 8);

        f32x4 S[7];
        #pragma unroll
        for (int jt = 0; jt < 7; ++jt) {
            f32x4 a = {};
            a = __builtin_amdgcn_mfma_f32_16x16x32_f16(kf[jt], qf, a, 0, 0, 0);
            S[jt] = a;
        }
        float m = -1e30f;
        #pragma unroll
        for (int jt = 0; jt < 7; ++jt)
            #pragma unroll
            for (int r = 0; r < 4; ++r) {
                int jg = jt * 16 + quad * 4 + r;
                float sv = (jg < NCITY) ? S[jt][r] * 0.25f : -1e30f;
                S[jt][r] = sv;
                m = fmaxf(m, sv);
            }
        m = fmaxf(m, __shfl_xor(m, 16));
        m = fmaxf(m, __shfl_xor(m, 32));
        float sum = 0.0f;
        #pragma unroll
        for (int jt = 0; jt < 7; ++jt)
            #pragma unroll
            for (int r = 0; r < 4; ++r) {
                float e = __expf(S[jt][r] - m);
                S[jt][r] = e;
                sum += e;
            }
        sum += __shfl_xor(sum, 16);
        sum += __shfl_xor(sum, 32);
        float inv = 1.0f / sum;
        #pragma unroll
        for (int jt = 0; jt < 7; ++jt)
            #pragma unroll
            for (int r = 0; r < 4; ++r) S[jt][r] *= inv;

        f32x4 O = {};
        #pragma unroll
        for (int p = 0; p < 4; ++p) {
            float pj[8];
            #pragma unroll
            for (int r = 0; r < 4; ++r) {
                float a0 = __shfl(S[2 * p][r],     s0);
                float b0 = __shfl(S[2 * p + 1][r], s0);
                float a1 = __shfl(S[2 * p][r],     s1);
                float b1 = __shfl(S[2 * p + 1][r], s1);
                pj[r]     = hi2 ? b0 : a0;
                pj[4 + r] = hi2 ? b1 : a1;
            }
            h8 ph;
            #pragma unroll
            for (int jj = 0; jj < 8; ++jj)
                ph[jj] = (half_t)pj[jj];
            O = __builtin_amdgcn_mfma_f32_16x16x32_f16(ph, vt[p], O, 0, 0, 0);
        }
        #pragma unroll
        for (int r = 0; r < 4; ++r) {
            int q = it * 16 + quad * 4 + r;
            if (q < NCITY) {
                int row = b * NCITY + q;
                int col = h * 16 + l16;
                oh[(size_t)row * 128 + swz_col(col, row)] = (half_t)O[r];
            }
        }
        qf = qn;
    }
}

// ---------------- BatchNorm apply (writes swizzled xh image) ----------------
__global__ __launch_bounds__(256)
void bn_apply(const h8* __restrict__ y, const float* __restrict__ stats,
              const float* __restrict__ g, const float* __restrict__ be,
              half_t* __restrict__ xh, float* __restrict__ dst32)
{
    __shared__ float sh[256];
    const int tid = threadIdx.x;
    if (tid < 128) {
        const float invN = 1.0f / (float)TROWS;
        float mean = stats[tid] * invN;
        float var  = stats[128 + tid] * invN - mean * mean;
        float inv  = rsqrtf(var + 1e-5f);
        float scl  = g[tid] * inv;
        sh[tid]       = scl;
        sh[128 + tid] = be[tid] - mean * scl;
    }
    __syncthreads();

    int gid = blockIdx.x * 256 + tid;   // over TROWS*16 (8 ch each)
    int row = gid >> 4;
    int gr  = gid & 15;
    int c = gr * 8;
    h8 v = y[gid];
    h8 hv;
    float o[8];
    #pragma unroll
    for (int r = 0; r < 8; ++r) {
        o[r] = (float)v[r] * sh[c + r] + sh[128 + c + r];
        hv[r] = (half_t)o[r];
    }
    int grp = (gr & ~3) | ((gr ^ (row >> 1)) & 3);   // image granule
    *reinterpret_cast<h8*>(xh + (size_t)row * 128 + grp * 8) = hv;
    if (dst32) {
        f32x4 lo = { o[0], o[1], o[2], o[3] };
        f32x4 hi = { o[4], o[5], o[6], o[7] };
        ((f32x4*)dst32)[gid * 2]     = lo;
        ((f32x4*)dst32)[gid * 2 + 1] = hi;
    }
}

// ---------------- launch ----------------
extern "C" void kernel_launch(void* const* d_in, const int* in_sizes, int n_in,
                              void* d_out, int out_size, void* d_ws, size_t ws_size,
                              hipStream_t stream)
{
    const float* s    = (const float*)d_in[0];
    const int*   dd   = (const int*)d_in[1];
    const float* e_w  = (const float*)d_in[2];
    const float* e_b  = (const float*)d_in[3];
    const float* ep_w = (const float*)d_in[4];
    const float* ep_b = (const float*)d_in[5];
    const float* Wq   = (const float*)d_in[6];
    const float* bq   = (const float*)d_in[7];
    const float* Wk   = (const float*)d_in[8];
    const float* bk   = (const float*)d_in[9];
    const float* Wv   = (const float*)d_in[10];
    const float* bv   = (const float*)d_in[11];
    const float* Wo   = (const float*)d_in[12];
    const float* bo   = (const float*)d_in[13];
    const float* Wf1  = (const float*)d_in[14];
    const float* bf1  = (const float*)d_in[15];
    const float* Wf2  = (const float*)d_in[16];
    const float* bf2  = (const float*)d_in[17];
    const float* g1   = (const float*)d_in[18];
    const float* be1  = (const float*)d_in[19];
    const float* g2   = (const float*)d_in[20];
    const float* be2  = (const float*)d_in[21];

    char* ws = (char*)d_ws;
    size_t off = 0;
    auto alloc = [&](size_t bytes) -> void* {
        void* p = ws + off;
        off += (bytes + 255) & ~(size_t)255;
        return p;
    };
    half_t* y16   = (half_t*)alloc((size_t)TROWS * 128 * 2);
    half_t* xh    = (half_t*)alloc((size_t)TROWS * 128 * 2);
    half_t* Qh    = (half_t*)alloc((size_t)NBH * NCITY * 16 * 2);
    half_t* Kh    = (half_t*)alloc((size_t)NBH * NCITY * 16 * 2);
    half_t* Vb    = (half_t*)alloc((size_t)NBH * NCITY * 16 * 2);
    half_t* oh    = (half_t*)alloc((size_t)TROWS * 128 * 2);
    half_t* wqkv  = (half_t*)alloc((size_t)3 * 384 * 128 * 2);
    half_t* wo    = (half_t*)alloc((size_t)3 * 128 * 128 * 2);
    half_t* wf1   = (half_t*)alloc((size_t)3 * 512 * 128 * 2);
    half_t* wf2   = (half_t*)alloc((size_t)3 * 128 * 512 * 2);
    float*  bqkv  = (float*) alloc((size_t)3 * 384 * 4);
    float*  stats = (float*) alloc(6 * 256 * 4);

    dim3 blk(256);

    hipMemsetAsync(stats, 0, 6 * 256 * 4, stream);

    prep_kernel<<<dim3(768, 7), blk, 0, stream>>>(Wq, Wk, Wv, Wo, Wf1, Wf2, bq, bk, bv,
                                                  wqkv, wo, wf1, wf2, bqkv);

    embed_kernel<<<dim3(TROWS * 128 / 256), blk, 0, stream>>>(s, dd, e_w, e_b, ep_w, ep_b, xh);

    for (int l = 0; l < 3; ++l) {
        float* st1 = stats + (size_t)(l * 2) * 256;
        float* st2 = stats + (size_t)(l * 2 + 1) * 256;
        // QKV -> Q/K/V all [bh][tok][16]
        gemm_tile<0, 4><<<dim3(3, 404), blk, 0, stream>>>(xh, wqkv + (size_t)l * 49152,
                                                          bqkv + l * 384, nullptr,
                                                          Qh, Kh, Vb, nullptr, 384);
        // attention (LDS-free fp16 MFMA, one wave per bh)
        attn_kernel<<<dim3(1024), blk, 0, stream>>>(Qh, Kh, Vb, oh);
        // O-proj + bias + residual(xh image) + fused BN1 stats -> y16 (plain)
        gemm_tile<1, 4><<<dim3(1, 404), blk, 0, stream>>>(oh, wo + (size_t)l * 16384,
                                                          bo + l * 128, xh,
                                                          y16, nullptr, nullptr, st1, 128);
        // fused BN1-apply + FF1 + FF2 + residual + BN2 stats (in-place y16)
        ff_fused<<<dim3(404), dim3(512), 0, stream>>>(y16, st1, g1 + l * 128, be1 + l * 128,
                                                      wf1 + (size_t)l * 65536, wf2 + (size_t)l * 65536,
                                                      bf1 + l * 512, bf2 + l * 128, st2);
        // BN2 apply -> xh image (+ fp32 out on last layer)
        bn_apply<<<dim3(TROWS * 16 / 256), blk, 0, stream>>>((const h8*)y16, st2,
                                                             g2 + l * 128, be2 + l * 128,
                                                             xh, (l == 2) ? (float*)d_out : nullptr);
    }
}

// Round 5
// 395.677 us; speedup vs baseline: 1.3011x; 1.1458x over previous
//
#include <hip/hip_runtime.h>
#include <hip/hip_fp16.h>
#include <stdint.h>

#define TROWS 51712   // 512*101
#define NCITY 101
#define BATCH 512
#define EDIM  128
#define NBH   4096    // BATCH*8 heads

using half_t = _Float16;
typedef __attribute__((ext_vector_type(8))) _Float16 h8;
typedef __attribute__((ext_vector_type(4))) _Float16 h4;
typedef __attribute__((ext_vector_type(4))) float   f32x4;

typedef __attribute__((address_space(1))) const unsigned int gu32;
typedef __attribute__((address_space(3))) unsigned int lu32;
static __device__ __forceinline__ void async16(const void* g, const void* l) {
    __builtin_amdgcn_global_load_lds((gu32*)g, (lu32*)(uint32_t)(uintptr_t)l, 16, 0, 0);
}

// Quarter-XOR image swizzle: element (row, c) of a [row][128] fp16 tensor is
// stored at column  c' = (c & ~31) | ((((c>>3) ^ (row>>1)) & 3) << 3) | (c & 7).
// Staged linearly into LDS [row][32] chunks, a ds_read_b128 at granule
// (quad ^ ((row>>1)&3)) returns the plain element -> conflict-free (ff-proven).
static __device__ __forceinline__ int swz_col(int c, int row) {
    return (c & ~31) | ((((c >> 3) ^ (row >> 1)) & 3) << 3) | (c & 7);
}

// ---------------- one-shot weight prep: all transposes + bias pack ----------------
__global__ __launch_bounds__(256)
void prep_kernel(const float* __restrict__ Wq, const float* __restrict__ Wk,
                 const float* __restrict__ Wv, const float* __restrict__ Wo,
                 const float* __restrict__ Wf1, const float* __restrict__ Wf2,
                 const float* __restrict__ bq, const float* __restrict__ bk,
                 const float* __restrict__ bv,
                 half_t* __restrict__ wqkv, half_t* __restrict__ wo,
                 half_t* __restrict__ wf1, half_t* __restrict__ wf2,
                 float* __restrict__ bqkv)
{
    const int which = blockIdx.y;
    const int gid = blockIdx.x * 256 + threadIdx.x;
    if (which <= 2) {
        if (gid >= 3 * 128 * 128) return;
        const float* src = (which == 0) ? Wq : (which == 1) ? Wk : Wv;
        int l = gid >> 14, r = gid & 16383, k = r >> 7, n = r & 127;
        wqkv[(size_t)l * 49152 + which * 16384 + n * 128 + swz_col(k, n)] = (half_t)src[gid];
    } else if (which == 3) {
        if (gid >= 3 * 128 * 128) return;
        int l = gid >> 14, r = gid & 16383, k = r >> 7, n = r & 127;
        wo[(size_t)l * 16384 + n * 128 + swz_col(k, n)] = (half_t)Wo[gid];
    } else if (which == 4) {
        // wf1 image: [l][j(8)][kc(4)][n(64)][h'(32)]
        if (gid >= 3 * 65536) return;
        int l = gid >> 16, u = gid & 65535;
        int j = u >> 13, kc = (u >> 11) & 3, n = (u >> 5) & 63, hp = u & 31;
        int k = kc * 32 + ((((hp >> 3) ^ (n >> 1)) & 3) << 3) + (hp & 7);
        wf1[(size_t)l * 65536 + u] = (half_t)Wf1[(size_t)(l * 128 + k) * 512 + j * 64 + n];
    } else if (which == 5) {
        // wf2 image: [l][j(8)][kc2(2)][n(128)][h'(32)]
        if (gid >= 3 * 65536) return;
        int l = gid >> 16, u = gid & 65535;
        int j = u >> 13, kc = (u >> 12) & 1, n = (u >> 5) & 127, hp = u & 31;
        int kh = j * 64 + kc * 32 + ((((hp >> 3) ^ (n >> 1)) & 3) << 3) + (hp & 7);
        wf2[(size_t)l * 65536 + u] = (half_t)Wf2[(size_t)(l * 512 + kh) * 128 + n];
    } else {
        if (gid >= 3 * 384) return;
        int l = gid / 384, c = gid - l * 384;
        float v = (c < 128) ? bq[l * 128 + c]
                : (c < 256) ? bk[l * 128 + c - 128]
                            : bv[l * 128 + c - 256];
        bqkv[gid] = v;
    }
}

// ---------------- embedding (writes swizzled xh image) ----------------
__global__ __launch_bounds__(256)
void embed_kernel(const float* __restrict__ s, const int* __restrict__ d,
                  const float* __restrict__ e_w, const float* __restrict__ e_b,
                  const float* __restrict__ ep_w, const float* __restrict__ ep_b,
                  half_t* __restrict__ xh)
{
    int gid = blockIdx.x * 256 + threadIdx.x;      // over TROWS*128
    int row = gid >> 7;
    int c   = gid & 127;
    int b = row / NCITY;
    int n = row - b * NCITY;
    const float* sp = s + ((size_t)b * NCITY + n) * 2;
    float v;
    if (n == 0) {
        v = sp[0] * ep_w[c] + sp[1] * ep_w[128 + c] + ep_b[c];
    } else {
        float dv = (float)d[b * NCITY + n];
        v = sp[0] * e_w[c] + sp[1] * e_w[128 + c] + dv * e_w[256 + c] + e_b[c];
    }
    xh[(size_t)row * 128 + swz_col(c, row)] = (half_t)v;
}

// ---------------- QKV GEMM, 1-barrier double-buffered pipeline ----------------
// A and B are swizzled images; fragment reads apply the matching XOR -> conflict-free.
// Epilogue: LDS-transpose, h8 stores to Q/K/V [bh][tok][16] (plain layout).
__global__ __launch_bounds__(256)
void qkv_gemm(const half_t* __restrict__ A, const half_t* __restrict__ B,
              const float* __restrict__ bias,
              half_t* __restrict__ outQ, half_t* __restrict__ outK,
              half_t* __restrict__ outV)
{
    constexpr int K = 128;
    __shared__ alignas(16) half_t smem[128 * 136];   // staging 32KB / transpose 34KB
    half_t* sA = smem;
    half_t* sB = smem + 8192;

    const int tid  = threadIdx.x;
    const int wave = tid >> 6, lane = tid & 63;
    const int n0 = blockIdx.x * 128;
    const int m0 = blockIdx.y * 128;

    const int sr = wave * 16 + (lane >> 2);
    const int sc = (lane & 3) * 8;
    const half_t* gA = A + (size_t)(m0 + sr) * K + sc;
    const half_t* gB = B + (size_t)(n0 + sr) * K + sc;
    const int ldst = wave * 512;

    const int quad = lane >> 4, l16 = lane & 15;
    const int wm = (wave >> 1) * 64, wn = (wave & 1) * 64;

    f32x4 acc[4][4] = {};

    async16(gA,                  &sA[ldst]);
    async16(gA + (size_t)64 * K, &sA[2048 + ldst]);
    async16(gB,                  &sB[ldst]);
    async16(gB + (size_t)64 * K, &sB[2048 + ldst]);

    for (int ks = 0; ks < 4; ++ks) {
        __syncthreads();
        if (ks + 1 < 4) {
            const int k0 = (ks + 1) * 32;
            const int nb = (ks + 1) & 1;
            async16(gA + k0,                  &sA[nb * 4096 + ldst]);
            async16(gA + (size_t)64 * K + k0, &sA[nb * 4096 + 2048 + ldst]);
            async16(gB + k0,                  &sB[nb * 4096 + ldst]);
            async16(gB + (size_t)64 * K + k0, &sB[nb * 4096 + 2048 + ldst]);
        }
        const int cb = ks & 1;
        h8 af[4], bf[4];
        #pragma unroll
        for (int mi = 0; mi < 4; ++mi) {
            int r = wm + mi * 16 + l16;
            af[mi] = *(const h8*)(&sA[cb * 4096 + r * 32 + (((quad ^ (r >> 1)) & 3) << 3)]);
        }
        #pragma unroll
        for (int ni = 0; ni < 4; ++ni) {
            int n = wn + ni * 16 + l16;
            bf[ni] = *(const h8*)(&sB[cb * 4096 + n * 32 + (((quad ^ (n >> 1)) & 3) << 3)]);
        }
        #pragma unroll
        for (int mi = 0; mi < 4; ++mi)
        #pragma unroll
        for (int ni = 0; ni < 4; ++ni)
            acc[mi][ni] = __builtin_amdgcn_mfma_f32_16x16x32_f16(af[mi], bf[ni], acc[mi][ni], 0, 0, 0);
    }

    // LDS-transpose epilogue: stride 136 halves, granule swizzle -> conflict-free.
    __syncthreads();
    half_t* sT = smem;
    #pragma unroll
    for (int ni = 0; ni < 4; ++ni) {
        int col = wn + ni * 16 + l16;
        float bvv = bias[n0 + col];
        #pragma unroll
        for (int mi = 0; mi < 4; ++mi) {
            #pragma unroll
            for (int r = 0; r < 4; ++r) {
                int row = wm + mi * 16 + quad * 4 + r;
                int g = (col >> 3) ^ ((row & 8) >> 2);
                sT[row * 136 + g * 8 + (col & 7)] = (half_t)(acc[mi][ni][r] + bvv);
            }
        }
    }
    __syncthreads();
    half_t* dst = (blockIdx.x == 0) ? outQ : (blockIdx.x == 1) ? outK : outV;
    #pragma unroll
    for (int i = 0; i < 8; ++i) {
        int u = tid + 256 * i;          // 2048 (row, chunk) units
        int row = u >> 4, chunk = u & 15;
        int g = chunk ^ ((row & 8) >> 2);
        h8 v = *(const h8*)(&sT[row * 136 + g * 8]);
        int rg = m0 + row;
        int bb = rg / NCITY, tok = rg - bb * NCITY;
        *(h8*)(dst + ((size_t)(bb * 8 + (chunk >> 1)) * NCITY + tok) * 16 + (chunk & 1) * 8) = v;
    }
}

// ---------------- fused attention + O-proj + residual + BN1 stats ----------------
// One block per batch element, 8 waves = 1 wave per head. Attention output O
// goes to LDS (112x136 swizzled transpose tile); O-proj (M=112,N=128,K=128)
// reads A from LDS, B-fragments per-wave from the wo image (L2-hot), adds
// bias + residual(xh image), writes y16 (plain) and accumulates BN1 stats.
__global__ __launch_bounds__(512, 2)
void attn_oproj(const half_t* __restrict__ Qh, const half_t* __restrict__ Kh,
                const half_t* __restrict__ V,  const half_t* __restrict__ wo,
                const float* __restrict__ bo,  const half_t* __restrict__ xh,
                half_t* __restrict__ y16, float* __restrict__ stats)
{
    __shared__ alignas(16) half_t sO[112 * 136];   // 30.5 KB

    const int b    = blockIdx.x;
    const int wave = threadIdx.x >> 6;            // = head h
    const int bh   = b * 8 + wave;
    const int lane = threadIdx.x & 63, quad = lane >> 4, l16 = lane & 15;
    const int s0 = (((quad & 1) * 2)    ) * 16 + l16;
    const int s1 = (((quad & 1) * 2) + 1) * 16 + l16;
    const bool hi2 = (quad >> 1) != 0;

    const half_t* qbase = Qh + (size_t)bh * NCITY * 16;
    const half_t* kbase = Kh + (size_t)bh * NCITY * 16;
    const half_t* vbase = V  + (size_t)bh * NCITY * 16;

    // hoist K tiles and V fragments (reused across all q-tiles)
    h8 kf[7];
    #pragma unroll
    for (int jt = 0; jt < 7; ++jt) {
        kf[jt] = (h8){};
        if (quad < 2)
            kf[jt] = *reinterpret_cast<const h8*>(kbase + (jt * 16 + l16) * 16 + quad * 8);
    }
    h8 vt[4];
    #pragma unroll
    for (int p = 0; p < 4; ++p)
        #pragma unroll
        for (int jj = 0; jj < 8; ++jj)
            vt[p][jj] = vbase[(size_t)(p * 32 + quad * 8 + jj) * 16 + l16];

    h8 qf = {};
    if (quad < 2)
        qf = *reinterpret_cast<const h8*>(qbase + l16 * 16 + quad * 8);

    const int ocol = wave * 16 + l16;             // this wave's output column

    for (int it = 0; it < 7; ++it) {
        h8 qn = {};
        if (it < 6 && quad < 2)
            qn = *reinterpret_cast<const h8*>(qbase + ((it + 1) * 16 + l16) * 16 + quad * 8);

        f32x4 S[7];
        #pragma unroll
        for (int jt = 0; jt < 7; ++jt) {
            f32x4 a = {};
            a = __builtin_amdgcn_mfma_f32_16x16x32_f16(kf[jt], qf, a, 0, 0, 0);
            S[jt] = a;
        }
        float m = -1e30f;
        #pragma unroll
        for (int jt = 0; jt < 7; ++jt)
            #pragma unroll
            for (int r = 0; r < 4; ++r) {
                int jg = jt * 16 + quad * 4 + r;
                float sv = (jg < NCITY) ? S[jt][r] * 0.25f : -1e30f;
                S[jt][r] = sv;
                m = fmaxf(m, sv);
            }
        m = fmaxf(m, __shfl_xor(m, 16));
        m = fmaxf(m, __shfl_xor(m, 32));
        float sum = 0.0f;
        #pragma unroll
        for (int jt = 0; jt < 7; ++jt)
            #pragma unroll
            for (int r = 0; r < 4; ++r) {
                float e = __expf(S[jt][r] - m);
                S[jt][r] = e;
                sum += e;
            }
        sum += __shfl_xor(sum, 16);
        sum += __shfl_xor(sum, 32);
        float inv = 1.0f / sum;
        #pragma unroll
        for (int jt = 0; jt < 7; ++jt)
            #pragma unroll
            for (int r = 0; r < 4; ++r) S[jt][r] *= inv;

        f32x4 O = {};
        #pragma unroll
        for (int p = 0; p < 4; ++p) {
            float pj[8];
            #pragma unroll
            for (int r = 0; r < 4; ++r) {
                float a0 = __shfl(S[2 * p][r],     s0);
                float b0 = __shfl(S[2 * p + 1][r], s0);
                float a1 = __shfl(S[2 * p][r],     s1);
                float b1 = __shfl(S[2 * p + 1][r], s1);
                pj[r]     = hi2 ? b0 : a0;
                pj[4 + r] = hi2 ? b1 : a1;
            }
            h8 ph;
            #pragma unroll
            for (int jj = 0; jj < 8; ++jj)
                ph[jj] = (half_t)pj[jj];
            O = __builtin_amdgcn_mfma_f32_16x16x32_f16(ph, vt[p], O, 0, 0, 0);
        }
        // O -> LDS transpose tile (unguarded: tail rows are harmless garbage)
        #pragma unroll
        for (int r = 0; r < 4; ++r) {
            int q = it * 16 + quad * 4 + r;
            int g = (ocol >> 3) ^ ((q & 8) >> 2);
            sO[q * 136 + g * 8 + (ocol & 7)] = (half_t)O[r];
        }
        qf = qn;
    }
    __syncthreads();

    // O-proj: wave w owns n-tile w (cols w*16..+15), all 7 m-tiles.
    // B fragments straight from the wo image (plain values via XOR indexing).
    h8 bfr[4];
    {
        const half_t* wrow = wo + (size_t)ocol * 128;
        const int nsw = (ocol >> 1) & 3;
        #pragma unroll
        for (int kc = 0; kc < 4; ++kc)
            bfr[kc] = *(const h8*)(wrow + kc * 32 + (((quad ^ nsw) & 3) << 3));
    }
    f32x4 acc[7];
    #pragma unroll
    for (int mi = 0; mi < 7; ++mi) {
        acc[mi] = (f32x4){};
        int row = mi * 16 + l16;
        int swr = (row & 8) >> 2;
        #pragma unroll
        for (int kc = 0; kc < 4; ++kc) {
            h8 af = *(const h8*)(&sO[row * 136 + (((kc * 4 + quad) ^ swr) << 3)]);
            acc[mi] = __builtin_amdgcn_mfma_f32_16x16x32_f16(af, bfr[kc], acc[mi], 0, 0, 0);
        }
    }
    // epilogue: bias + residual + BN1 stats
    float bvv = bo[ocol];
    float s = 0.0f, ss = 0.0f;
    #pragma unroll
    for (int mi = 0; mi < 7; ++mi) {
        #pragma unroll
        for (int r = 0; r < 4; ++r) {
            int q = mi * 16 + quad * 4 + r;
            if (q < NCITY) {
                size_t grow = (size_t)b * NCITY + q;
                float o = acc[mi][r] + bvv + (float)xh[grow * 128 + swz_col(ocol, (int)grow)];
                y16[grow * 128 + ocol] = (half_t)o;
                s += o; ss += o * o;
            }
        }
    }
    s  += __shfl_xor(s, 16);  s  += __shfl_xor(s, 32);
    ss += __shfl_xor(ss, 16); ss += __shfl_xor(ss, 32);
    if (quad == 0) {
        atomicAdd(&stats[ocol], s);
        atomicAdd(&stats[128 + ocol], ss);
    }
}

// ---------------- fused BN1 + FF1(ReLU) + FF2 ----------------
// 512 threads / 8 waves, 80 KB LDS -> 2 blocks/CU.
// Weights reg-staged: next round's loads issued under compute.
// Epilogue residual x' read back from sX (LDS) -- no y16 re-read.
__global__ __launch_bounds__(512, 4)
void ff_fused(half_t* __restrict__ y16, const float* __restrict__ st1,
              const float* __restrict__ g1, const float* __restrict__ be1,
              const half_t* __restrict__ w1, const half_t* __restrict__ w2,
              const float* __restrict__ bf1, const float* __restrict__ bf2,
              float* __restrict__ stats)
{
    __shared__ alignas(16) half_t sX[4][128 * 32];   // 32 KB  x' tile
    __shared__ alignas(16) half_t sW1f[8192];        // 16 KB  wf1 chunk image (flat)
    __shared__ alignas(16) half_t sW2f[8192];        // 16 KB  wf2 chunk image (flat)
    __shared__ alignas(16) half_t sH[2][128 * 32];   // 16 KB  relu chunk

    const int tid  = threadIdx.x;
    const int wave = tid >> 6, lane = tid & 63;
    const int quad = lane >> 4, l16 = lane & 15;
    const int m0 = blockIdx.x * 128;
    const int wr = wave >> 1;          // 0..3: 32-row group
    const int wc = wave & 1;           // col group

    const float invN = 1.0f / (float)TROWS;
    const int so = wave * 512 + lane * 8;    // identity global<->LDS offset

    // prologue: round-0 weight regs
    h8 rw1a = *(const h8*)(w1 + so);
    h8 rw1b = *(const h8*)(w1 + so + 4096);
    h8 rw2a = *(const h8*)(w2 + so);
    h8 rw2b = *(const h8*)(w2 + so + 4096);

    // BN1 scale/shift table (1 KB, overlaid in sW1f; dead after sX stage)
    float* sBN = (float*)&sW1f[0];
    if (tid < 128) {
        float mean = st1[tid] * invN;
        float var  = st1[128 + tid] * invN - mean * mean;
        float scl  = g1[tid] * rsqrtf(var + 1e-5f);
        sBN[tid]       = scl;
        sBN[128 + tid] = be1[tid] - mean * scl;
    }
    __syncthreads();

    // stage x' = BN1(y16) -> sX (swizzled)
    {
        const int row = tid >> 2;            // 0..127
        const int q   = tid & 3;
        const int qs  = ((q ^ (row >> 1)) & 3) << 3;
        const half_t* src = y16 + (size_t)(m0 + row) * 128 + q * 8;
        #pragma unroll
        for (int kc = 0; kc < 4; ++kc) {
            h8 v = *(const h8*)(src + kc * 32);
            h8 xv;
            #pragma unroll
            for (int r = 0; r < 8; ++r) {
                int c = kc * 32 + q * 8 + r;
                xv[r] = (half_t)((float)v[r] * sBN[c] + sBN[128 + c]);
            }
            *(h8*)(&sX[kc][row * 32 + qs]) = xv;
        }
    }

    f32x4 acc2[2][4] = {};

    for (int j = 0; j < 8; ++j) {
        // b1: FF2(j-1) done reading sW/sH; sX/sBN writes visible (j=0)
        asm volatile("s_waitcnt lgkmcnt(0)" ::: "memory");
        __builtin_amdgcn_s_barrier();
        __builtin_amdgcn_sched_barrier(0);
        // write W(j) from regs (compiler inserts the per-thread vmcnt waits)
        *(h8*)(&sW1f[so])        = rw1a;
        *(h8*)(&sW1f[so + 4096]) = rw1b;
        *(h8*)(&sW2f[so])        = rw2a;
        *(h8*)(&sW2f[so + 4096]) = rw2b;
        asm volatile("s_waitcnt lgkmcnt(0)" ::: "memory");
        __builtin_amdgcn_s_barrier();
        __builtin_amdgcn_sched_barrier(0);
        if (j < 7) {   // issue next round's loads; they fly under FF1+FF2
            const half_t* w1n = w1 + (size_t)(j + 1) * 8192;
            const half_t* w2n = w2 + (size_t)(j + 1) * 8192;
            rw1a = *(const h8*)(w1n + so);
            rw1b = *(const h8*)(w1n + so + 4096);
            rw2a = *(const h8*)(w2n + so);
            rw2b = *(const h8*)(w2n + so + 4096);
        }

        // FF1: wave tile 32x32 of 128x64 chunk
        f32x4 acc1[2][2] = {};
        #pragma unroll
        for (int kc = 0; kc < 4; ++kc) {
            h8 af[2], bf[2];
            #pragma unroll
            for (int mi = 0; mi < 2; ++mi) {
                int r = wr * 32 + mi * 16 + l16;
                af[mi] = *(const h8*)(&sX[kc][r * 32 + (((quad ^ (r >> 1)) & 3) << 3)]);
            }
            #pragma unroll
            for (int ni = 0; ni < 2; ++ni) {
                int n = wc * 32 + ni * 16 + l16;
                bf[ni] = *(const h8*)(&sW1f[kc * 2048 + n * 32 + (((quad ^ (n >> 1)) & 3) << 3)]);
            }
            #pragma unroll
            for (int mi = 0; mi < 2; ++mi)
            #pragma unroll
            for (int ni = 0; ni < 2; ++ni)
                acc1[mi][ni] = __builtin_amdgcn_mfma_f32_16x16x32_f16(af[mi], bf[ni], acc1[mi][ni], 0, 0, 0);
        }
        // bias + ReLU -> sH (swizzled scalar writes)
        #pragma unroll
        for (int ni = 0; ni < 2; ++ni) {
            int c = wc * 32 + ni * 16 + l16;       // 0..63
            float bvv = bf1[j * 64 + c];
            int kc2 = c >> 5, c5 = c & 31;
            #pragma unroll
            for (int mi = 0; mi < 2; ++mi)
            #pragma unroll
            for (int r = 0; r < 4; ++r) {
                int row = wr * 32 + mi * 16 + quad * 4 + r;
                float v = acc1[mi][ni][r] + bvv;
                v = v > 0.0f ? v : 0.0f;
                int hsw = (c5 & 7) | ((((c5 >> 3) ^ (row >> 1)) & 3) << 3);
                sH[kc2][row * 32 + hsw] = (half_t)v;
            }
        }
        asm volatile("s_waitcnt lgkmcnt(0)" ::: "memory");
        __builtin_amdgcn_s_barrier();
        __builtin_amdgcn_sched_barrier(0);

        // FF2 partial: wave tile 32x64, K-slice 64
        #pragma unroll
        for (int kc = 0; kc < 2; ++kc) {
            h8 af[2], bf[4];
            #pragma unroll
            for (int mi = 0; mi < 2; ++mi) {
                int r = wr * 32 + mi * 16 + l16;
                af[mi] = *(const h8*)(&sH[kc][r * 32 + (((quad ^ (r >> 1)) & 3) << 3)]);
            }
            #pragma unroll
            for (int ni = 0; ni < 4; ++ni) {
                int n = wc * 64 + ni * 16 + l16;
                bf[ni] = *(const h8*)(&sW2f[kc * 4096 + n * 32 + (((quad ^ (n >> 1)) & 3) << 3)]);
            }
            #pragma unroll
            for (int mi = 0; mi < 2; ++mi)
            #pragma unroll
            for (int ni = 0; ni < 4; ++ni)
                acc2[mi][ni] = __builtin_amdgcn_mfma_f32_16x16x32_f16(af[mi], bf[ni], acc2[mi][ni], 0, 0, 0);
        }
    }

    // epilogue: y2 = acc2 + bf2 + x' (x' read from sX), BN2 stats
    __syncthreads();                       // sH reads done -> reuse as reduction scratch
    float* red = (float*)&sH[0][0];        // [2][512] floats (s, ss)

    #pragma unroll
    for (int ni = 0; ni < 4; ++ni) {
        int col = wc * 64 + ni * 16 + l16;
        float bvv = bf2[col];
        int kc = col >> 5, c5 = col & 31;
        float s = 0.0f, ss = 0.0f;
        #pragma unroll
        for (int mi = 0; mi < 2; ++mi) {
            #pragma unroll
            for (int r = 0; r < 4; ++r) {
                int rowl = wr * 32 + mi * 16 + quad * 4 + r;
                int hsw = (c5 & 7) | ((((c5 >> 3) ^ (rowl >> 1)) & 3) << 3);
                float xv = (float)sX[kc][rowl * 32 + hsw];
                float o = acc2[mi][ni][r] + bvv + xv;
                y16[(size_t)(m0 + rowl) * 128 + col] = (half_t)o;
                s += o; ss += o * o;
            }
        }
        s  += __shfl_xor(s, 16);  s  += __shfl_xor(s, 32);
        ss += __shfl_xor(ss, 16); ss += __shfl_xor(ss, 32);
        if (quad == 0) {
            red[wave * 64 + ni * 16 + l16]       = s;
            red[512 + wave * 64 + ni * 16 + l16] = ss;
        }
    }
    __syncthreads();
    if (tid < 256) {
        int a   = tid >> 7;          // 0 = s, 1 = ss
        int col = tid & 127;
        int wcc = col >> 6, nii = (col >> 4) & 3, lx = col & 15;
        float t = 0.0f;
        #pragma unroll
        for (int w = 0; w < 4; ++w)
            t += red[a * 512 + (w * 2 + wcc) * 64 + nii * 16 + lx];
        atomicAdd(&stats[a * 128 + col], t);
    }
}

// ---------------- BatchNorm apply (writes swizzled xh image) ----------------
__global__ __launch_bounds__(256)
void bn_apply(const h8* __restrict__ y, const float* __restrict__ stats,
              const float* __restrict__ g, const float* __restrict__ be,
              half_t* __restrict__ xh, float* __restrict__ dst32)
{
    __shared__ float sh[256];
    const int tid = threadIdx.x;
    if (tid < 128) {
        const float invN = 1.0f / (float)TROWS;
        float mean = stats[tid] * invN;
        float var  = stats[128 + tid] * invN - mean * mean;
        float inv  = rsqrtf(var + 1e-5f);
        float scl  = g[tid] * inv;
        sh[tid]       = scl;
        sh[128 + tid] = be[tid] - mean * scl;
    }
    __syncthreads();

    int gid = blockIdx.x * 256 + tid;   // over TROWS*16 (8 ch each)
    int row = gid >> 4;
    int gr  = gid & 15;
    int c = gr * 8;
    h8 v = y[gid];
    h8 hv;
    float o[8];
    #pragma unroll
    for (int r = 0; r < 8; ++r) {
        o[r] = (float)v[r] * sh[c + r] + sh[128 + c + r];
        hv[r] = (half_t)o[r];
    }
    int grp = (gr & ~3) | ((gr ^ (row >> 1)) & 3);   // image granule
    *reinterpret_cast<h8*>(xh + (size_t)row * 128 + grp * 8) = hv;
    if (dst32) {
        f32x4 lo = { o[0], o[1], o[2], o[3] };
        f32x4 hi = { o[4], o[5], o[6], o[7] };
        ((f32x4*)dst32)[gid * 2]     = lo;
        ((f32x4*)dst32)[gid * 2 + 1] = hi;
    }
}

// ---------------- launch ----------------
extern "C" void kernel_launch(void* const* d_in, const int* in_sizes, int n_in,
                              void* d_out, int out_size, void* d_ws, size_t ws_size,
                              hipStream_t stream)
{
    const float* s    = (const float*)d_in[0];
    const int*   dd   = (const int*)d_in[1];
    const float* e_w  = (const float*)d_in[2];
    const float* e_b  = (const float*)d_in[3];
    const float* ep_w = (const float*)d_in[4];
    const float* ep_b = (const float*)d_in[5];
    const float* Wq   = (const float*)d_in[6];
    const float* bq   = (const float*)d_in[7];
    const float* Wk   = (const float*)d_in[8];
    const float* bk   = (const float*)d_in[9];
    const float* Wv   = (const float*)d_in[10];
    const float* bv   = (const float*)d_in[11];
    const float* Wo   = (const float*)d_in[12];
    const float* bo   = (const float*)d_in[13];
    const float* Wf1  = (const float*)d_in[14];
    const float* bf1  = (const float*)d_in[15];
    const float* Wf2  = (const float*)d_in[16];
    const float* bf2  = (const float*)d_in[17];
    const float* g1   = (const float*)d_in[18];
    const float* be1  = (const float*)d_in[19];
    const float* g2   = (const float*)d_in[20];
    const float* be2  = (const float*)d_in[21];

    char* ws = (char*)d_ws;
    size_t off = 0;
    auto alloc = [&](size_t bytes) -> void* {
        void* p = ws + off;
        off += (bytes + 255) & ~(size_t)255;
        return p;
    };
    half_t* y16   = (half_t*)alloc((size_t)TROWS * 128 * 2);
    half_t* xh    = (half_t*)alloc((size_t)TROWS * 128 * 2);
    half_t* Qh    = (half_t*)alloc((size_t)NBH * NCITY * 16 * 2);
    half_t* Kh    = (half_t*)alloc((size_t)NBH * NCITY * 16 * 2);
    half_t* Vb    = (half_t*)alloc((size_t)NBH * NCITY * 16 * 2);
    half_t* wqkv  = (half_t*)alloc((size_t)3 * 384 * 128 * 2);
    half_t* wo    = (half_t*)alloc((size_t)3 * 128 * 128 * 2);
    half_t* wf1   = (half_t*)alloc((size_t)3 * 512 * 128 * 2);
    half_t* wf2   = (half_t*)alloc((size_t)3 * 128 * 512 * 2);
    float*  bqkv  = (float*) alloc((size_t)3 * 384 * 4);
    float*  stats = (float*) alloc(6 * 256 * 4);

    dim3 blk(256);

    hipMemsetAsync(stats, 0, 6 * 256 * 4, stream);

    prep_kernel<<<dim3(768, 7), blk, 0, stream>>>(Wq, Wk, Wv, Wo, Wf1, Wf2, bq, bk, bv,
                                                  wqkv, wo, wf1, wf2, bqkv);

    embed_kernel<<<dim3(TROWS * 128 / 256), blk, 0, stream>>>(s, dd, e_w, e_b, ep_w, ep_b, xh);

    for (int l = 0; l < 3; ++l) {
        float* st1 = stats + (size_t)(l * 2) * 256;
        float* st2 = stats + (size_t)(l * 2 + 1) * 256;
        // QKV -> Q/K/V all [bh][tok][16]
        qkv_gemm<<<dim3(3, 404), blk, 0, stream>>>(xh, wqkv + (size_t)l * 49152,
                                                   bqkv + l * 384, Qh, Kh, Vb);
        // attention + O-proj + residual + BN1 stats -> y16
        attn_oproj<<<dim3(BATCH), dim3(512), 0, stream>>>(Qh, Kh, Vb,
                                                          wo + (size_t)l * 16384,
                                                          bo + l * 128, xh, y16, st1);
        // fused BN1-apply + FF1 + FF2 + residual + BN2 stats (in-place y16)
        ff_fused<<<dim3(404), dim3(512), 0, stream>>>(y16, st1, g1 + l * 128, be1 + l * 128,
                                                      wf1 + (size_t)l * 65536, wf2 + (size_t)l * 65536,
                                                      bf1 + l * 512, bf2 + l * 128, st2);
        // BN2 apply -> xh image (+ fp32 out on last layer)
        bn_apply<<<dim3(TROWS * 16 / 256), blk, 0, stream>>>((const h8*)y16, st2,
                                                             g2 + l * 128, be2 + l * 128,
                                                             xh, (l == 2) ? (float*)d_out : nullptr);
    }
}

// Round 7
// 391.751 us; speedup vs baseline: 1.3141x; 1.0100x over previous
//
#include <hip/hip_runtime.h>
#include <hip/hip_fp16.h>
#include <stdint.h>

#define TROWS 51712   // 512*101
#define NCITY 101
#define BATCH 512
#define EDIM  128
#define NBH   4096    // BATCH*8 heads

using half_t = _Float16;
typedef __attribute__((ext_vector_type(8))) _Float16 h8;
typedef __attribute__((ext_vector_type(4))) _Float16 h4;
typedef __attribute__((ext_vector_type(4))) float   f32x4;

typedef __attribute__((address_space(1))) const unsigned int gu32;
typedef __attribute__((address_space(3))) unsigned int lu32;
static __device__ __forceinline__ void async16(const void* g, const void* l) {
    __builtin_amdgcn_global_load_lds((gu32*)g, (lu32*)(uint32_t)(uintptr_t)l, 16, 0, 0);
}

// Quarter-XOR image swizzle: element (row, c) of a [row][128] fp16 tensor is
// stored at column  c' = (c & ~31) | ((((c>>3) ^ (row>>1)) & 3) << 3) | (c & 7).
static __device__ __forceinline__ int swz_col(int c, int row) {
    return (c & ~31) | ((((c >> 3) ^ (row >> 1)) & 3) << 3) | (c & 7);
}

// ---------------- one-shot weight prep: all transposes + bias pack ----------------
__global__ __launch_bounds__(256)
void prep_kernel(const float* __restrict__ Wq, const float* __restrict__ Wk,
                 const float* __restrict__ Wv, const float* __restrict__ Wo,
                 const float* __restrict__ Wf1, const float* __restrict__ Wf2,
                 const float* __restrict__ bq, const float* __restrict__ bk,
                 const float* __restrict__ bv,
                 half_t* __restrict__ wqkv, half_t* __restrict__ wo,
                 half_t* __restrict__ wf1, half_t* __restrict__ wf2,
                 float* __restrict__ bqkv)
{
    const int which = blockIdx.y;
    const int gid = blockIdx.x * 256 + threadIdx.x;
    if (which <= 2) {
        if (gid >= 3 * 128 * 128) return;
        const float* src = (which == 0) ? Wq : (which == 1) ? Wk : Wv;
        int l = gid >> 14, r = gid & 16383, k = r >> 7, n = r & 127;
        wqkv[(size_t)l * 49152 + which * 16384 + n * 128 + swz_col(k, n)] = (half_t)src[gid];
    } else if (which == 3) {
        if (gid >= 3 * 128 * 128) return;
        int l = gid >> 14, r = gid & 16383, k = r >> 7, n = r & 127;
        wo[(size_t)l * 16384 + n * 128 + swz_col(k, n)] = (half_t)Wo[gid];
    } else if (which == 4) {
        // wf1 image: [l][j(8)][kc(4)][n(64)][h'(32)]
        if (gid >= 3 * 65536) return;
        int l = gid >> 16, u = gid & 65535;
        int j = u >> 13, kc = (u >> 11) & 3, n = (u >> 5) & 63, hp = u & 31;
        int k = kc * 32 + ((((hp >> 3) ^ (n >> 1)) & 3) << 3) + (hp & 7);
        wf1[(size_t)l * 65536 + u] = (half_t)Wf1[(size_t)(l * 128 + k) * 512 + j * 64 + n];
    } else if (which == 5) {
        // wf2 image: [l][j(8)][kc2(2)][n(128)][h'(32)]
        if (gid >= 3 * 65536) return;
        int l = gid >> 16, u = gid & 65535;
        int j = u >> 13, kc = (u >> 12) & 1, n = (u >> 5) & 127, hp = u & 31;
        int kh = j * 64 + kc * 32 + ((((hp >> 3) ^ (n >> 1)) & 3) << 3) + (hp & 7);
        wf2[(size_t)l * 65536 + u] = (half_t)Wf2[(size_t)(l * 512 + kh) * 128 + n];
    } else {
        if (gid >= 3 * 384) return;
        int l = gid / 384, c = gid - l * 384;
        float v = (c < 128) ? bq[l * 128 + c]
                : (c < 256) ? bk[l * 128 + c - 128]
                            : bv[l * 128 + c - 256];
        bqkv[gid] = v;
    }
}

// ---------------- embedding (writes swizzled xh image) ----------------
__global__ __launch_bounds__(256)
void embed_kernel(const float* __restrict__ s, const int* __restrict__ d,
                  const float* __restrict__ e_w, const float* __restrict__ e_b,
                  const float* __restrict__ ep_w, const float* __restrict__ ep_b,
                  half_t* __restrict__ xh)
{
    int gid = blockIdx.x * 256 + threadIdx.x;      // over TROWS*128
    int row = gid >> 7;
    int c   = gid & 127;
    int b = row / NCITY;
    int n = row - b * NCITY;
    const float* sp = s + ((size_t)b * NCITY + n) * 2;
    float v;
    if (n == 0) {
        v = sp[0] * ep_w[c] + sp[1] * ep_w[128 + c] + ep_b[c];
    } else {
        float dv = (float)d[b * NCITY + n];
        v = sp[0] * e_w[c] + sp[1] * e_w[128 + c] + dv * e_w[256 + c] + e_b[c];
    }
    xh[(size_t)row * 128 + swz_col(c, row)] = (half_t)v;
}

// ---------------- fused QKV + attention + O-proj + residual + BN1 stats -------
// One block per batch element, 512 threads, 8 waves = 1 wave per head.
// Phase 1: stage x image tile -> sX with GLOBAL->LOCAL row re-swizzle
//          (granule g -> g ^ ((grow>>1 ^ row>>1)&3)); rows>=101 zeroed.
// Phase 2: each wave computes ITS head's Q/K/V (weights from L2-hot wqkv image)
//          into wave-private LDS [which][wave][112][16] -- no cross-wave sync.
// Phase 3: attention per wave (K/V/Q from LDS).
// Phase 4: O -> sO transpose tile (overlays sX), barrier, O-proj + residual +
//          BN1 stats (verbatim from the proven attn_oproj epilogue).
__global__ __launch_bounds__(512, 1)
void layer_attn(const half_t* __restrict__ xh, const half_t* __restrict__ wqkv,
                const float* __restrict__ bqkv, const half_t* __restrict__ wo,
                const float* __restrict__ bo, half_t* __restrict__ y16,
                float* __restrict__ stats)
{
    __shared__ alignas(16) half_t sO[112 * 136];          // 30.5 KB (overlays sX)
    __shared__ alignas(16) half_t sQKV[3][8][112 * 16];   // 84 KB
    half_t* sX = sO;                                      // [4][112*32] = 28 KB

    const int b   = blockIdx.x;
    const int tid = threadIdx.x;
    const int wave = tid >> 6, lane = tid & 63;
    const int quad = lane >> 4, l16 = lane & 15;

    // ---- phase 1: stage x tile (global-row image -> local-row image; tail zeroed)
    if (tid < 448) {
        int row = tid >> 2, kc = tid & 3;
        h8* dst = (h8*)&sX[kc * 3584 + row * 32];
        if (row < NCITY) {
            size_t grow = (size_t)b * NCITY + row;
            const h8* src = (const h8*)(xh + grow * 128 + kc * 32);
            int xf = (int)(((grow >> 1) ^ (row >> 1)) & 3);
            h8 v0 = src[0], v1 = src[1], v2 = src[2], v3 = src[3];
            dst[0 ^ xf] = v0;
            dst[1 ^ xf] = v1;
            dst[2 ^ xf] = v2;
            dst[3 ^ xf] = v3;
        } else {
            h8 z = {};
            dst[0] = z; dst[1] = z; dst[2] = z; dst[3] = z;
        }
    }
    __syncthreads();

    // ---- phase 2: per-wave QKV for head `wave`
    const int hn  = wave * 16 + l16;         // output column 0..127
    const int nsw = (hn >> 1) & 3;
    h8 bfr[3][4];
    float bv3[3];
    #pragma unroll
    for (int which = 0; which < 3; ++which) {
        const half_t* wrow = wqkv + which * 16384 + (size_t)hn * 128;
        #pragma unroll
        for (int kc = 0; kc < 4; ++kc)
            bfr[which][kc] = *(const h8*)(wrow + kc * 32 + (((quad ^ nsw) & 3) << 3));
        bv3[which] = bqkv[which * 128 + hn];
    }
    #pragma unroll
    for (int mi = 0; mi < 7; ++mi) {
        h8 af[4];
        #pragma unroll
        for (int kc = 0; kc < 4; ++kc) {
            int r = mi * 16 + l16;
            af[kc] = *(const h8*)(&sX[kc * 3584 + r * 32 + (((quad ^ (r >> 1)) & 3) << 3)]);
        }
        #pragma unroll
        for (int which = 0; which < 3; ++which) {
            f32x4 a = {};
            #pragma unroll
            for (int kc = 0; kc < 4; ++kc)
                a = __builtin_amdgcn_mfma_f32_16x16x32_f16(af[kc], bfr[which][kc], a, 0, 0, 0);
            half_t* dstL = &sQKV[which][wave][0];
            #pragma unroll
            for (int r = 0; r < 4; ++r) {
                int tok = mi * 16 + quad * 4 + r;
                int dsw = l16 ^ (((tok >> 2) & 1) << 3);
                dstL[tok * 16 + dsw] = (half_t)(a[r] + bv3[which]);
            }
        }
    }
    __syncthreads();   // all waves done reading sX -> sO overlay is safe

    // ---- phase 3: attention (per-wave private; K/V/Q from LDS)
    const half_t* qb = &sQKV[0][wave][0];
    const half_t* kb = &sQKV[1][wave][0];
    const half_t* vb = &sQKV[2][wave][0];
    const int kflip = (l16 >> 2) & 1;

    const int s0 = (((quad & 1) * 2)    ) * 16 + l16;
    const int s1 = (((quad & 1) * 2) + 1) * 16 + l16;
    const bool hi2 = (quad >> 1) != 0;

    h8 kf[7];
    #pragma unroll
    for (int jt = 0; jt < 7; ++jt) {
        kf[jt] = (h8){};
        if (quad < 2)
            kf[jt] = *(const h8*)(kb + (jt * 16 + l16) * 16 + ((quad ^ kflip) << 3));
    }
    h8 vt[4];
    #pragma unroll
    for (int p = 0; p < 4; ++p)
        #pragma unroll
        for (int jj = 0; jj < 8; ++jj) {
            int tok = p * 32 + quad * 8 + jj;
            vt[p][jj] = vb[tok * 16 + (l16 ^ (((jj >> 2) & 1) << 3))];
        }

    const int ocol = hn;                       // this wave's output column

    for (int it = 0; it < 7; ++it) {
        h8 qf = {};
        if (quad < 2)
            qf = *(const h8*)(qb + (it * 16 + l16) * 16 + ((quad ^ kflip) << 3));

        f32x4 S[7];
        #pragma unroll
        for (int jt = 0; jt < 7; ++jt) {
            f32x4 a = {};
            a = __builtin_amdgcn_mfma_f32_16x16x32_f16(kf[jt], qf, a, 0, 0, 0);
            S[jt] = a;
        }
        float m = -1e30f;
        #pragma unroll
        for (int jt = 0; jt < 7; ++jt)
            #pragma unroll
            for (int r = 0; r < 4; ++r) {
                int jg = jt * 16 + quad * 4 + r;
                float sv = (jg < NCITY) ? S[jt][r] * 0.25f : -1e30f;
                S[jt][r] = sv;
                m = fmaxf(m, sv);
            }
        m = fmaxf(m, __shfl_xor(m, 16));
        m = fmaxf(m, __shfl_xor(m, 32));
        float sum = 0.0f;
        #pragma unroll
        for (int jt = 0; jt < 7; ++jt)
            #pragma unroll
            for (int r = 0; r < 4; ++r) {
                float e = __expf(S[jt][r] - m);
                S[jt][r] = e;
                sum += e;
            }
        sum += __shfl_xor(sum, 16);
        sum += __shfl_xor(sum, 32);
        float inv = 1.0f / sum;
        #pragma unroll
        for (int jt = 0; jt < 7; ++jt)
            #pragma unroll
            for (int r = 0; r < 4; ++r) S[jt][r] *= inv;

        f32x4 O = {};
        #pragma unroll
        for (int p = 0; p < 4; ++p) {
            float pj[8];
            #pragma unroll
            for (int r = 0; r < 4; ++r) {
                float a0 = __shfl(S[2 * p][r],     s0);
                float b0 = __shfl(S[2 * p + 1][r], s0);
                float a1 = __shfl(S[2 * p][r],     s1);
                float b1 = __shfl(S[2 * p + 1][r], s1);
                pj[r]     = hi2 ? b0 : a0;
                pj[4 + r] = hi2 ? b1 : a1;
            }
            h8 ph;
            #pragma unroll
            for (int jj = 0; jj < 8; ++jj)
                ph[jj] = (half_t)pj[jj];
            O = __builtin_amdgcn_mfma_f32_16x16x32_f16(ph, vt[p], O, 0, 0, 0);
        }
        // O -> LDS transpose tile (tail rows harmless garbage)
        #pragma unroll
        for (int r = 0; r < 4; ++r) {
            int q = it * 16 + quad * 4 + r;
            int g = (ocol >> 3) ^ ((q & 8) >> 2);
            sO[q * 136 + g * 8 + (ocol & 7)] = (half_t)O[r];
        }
    }
    __syncthreads();

    // ---- phase 4: O-proj (wave w owns cols w*16..+15), residual, BN1 stats
    h8 bfr2[4];
    {
        const half_t* wrow = wo + (size_t)ocol * 128;
        const int nsw2 = (ocol >> 1) & 3;
        #pragma unroll
        for (int kc = 0; kc < 4; ++kc)
            bfr2[kc] = *(const h8*)(wrow + kc * 32 + (((quad ^ nsw2) & 3) << 3));
    }
    f32x4 acc[7];
    #pragma unroll
    for (int mi = 0; mi < 7; ++mi) {
        acc[mi] = (f32x4){};
        int row = mi * 16 + l16;
        int swr = (row & 8) >> 2;
        #pragma unroll
        for (int kc = 0; kc < 4; ++kc) {
            h8 af = *(const h8*)(&sO[row * 136 + (((kc * 4 + quad) ^ swr) << 3)]);
            acc[mi] = __builtin_amdgcn_mfma_f32_16x16x32_f16(af, bfr2[kc], acc[mi], 0, 0, 0);
        }
    }
    float bvv = bo[ocol];
    float s = 0.0f, ss = 0.0f;
    #pragma unroll
    for (int mi = 0; mi < 7; ++mi) {
        #pragma unroll
        for (int r = 0; r < 4; ++r) {
            int q = mi * 16 + quad * 4 + r;
            if (q < NCITY) {
                size_t grow = (size_t)b * NCITY + q;
                float o = acc[mi][r] + bvv + (float)xh[grow * 128 + swz_col(ocol, (int)grow)];
                y16[grow * 128 + ocol] = (half_t)o;
                s += o; ss += o * o;
            }
        }
    }
    s  += __shfl_xor(s, 16);  s  += __shfl_xor(s, 32);
    ss += __shfl_xor(ss, 16); ss += __shfl_xor(ss, 32);
    if (quad == 0) {
        atomicAdd(&stats[ocol], s);
        atomicAdd(&stats[128 + ocol], ss);
    }
}

// ---------------- fused BN1 + FF1(ReLU) + FF2 ----------------
// 512 threads / 8 waves, 80 KB LDS -> 2 blocks/CU.
// Weights reg-staged: next round's loads issued under compute.
// Epilogue residual x' read back from sX (LDS) -- no y16 re-read.
__global__ __launch_bounds__(512, 4)
void ff_fused(half_t* __restrict__ y16, const float* __restrict__ st1,
              const float* __restrict__ g1, const float* __restrict__ be1,
              const half_t* __restrict__ w1, const half_t* __restrict__ w2,
              const float* __restrict__ bf1, const float* __restrict__ bf2,
              float* __restrict__ stats)
{
    __shared__ alignas(16) half_t sX[4][128 * 32];   // 32 KB  x' tile
    __shared__ alignas(16) half_t sW1f[8192];        // 16 KB  wf1 chunk image (flat)
    __shared__ alignas(16) half_t sW2f[8192];        // 16 KB  wf2 chunk image (flat)
    __shared__ alignas(16) half_t sH[2][128 * 32];   // 16 KB  relu chunk

    const int tid  = threadIdx.x;
    const int wave = tid >> 6, lane = tid & 63;
    const int quad = lane >> 4, l16 = lane & 15;
    const int m0 = blockIdx.x * 128;
    const int wr = wave >> 1;          // 0..3: 32-row group
    const int wc = wave & 1;           // col group

    const float invN = 1.0f / (float)TROWS;
    const int so = wave * 512 + lane * 8;    // identity global<->LDS offset

    // prologue: round-0 weight regs
    h8 rw1a = *(const h8*)(w1 + so);
    h8 rw1b = *(const h8*)(w1 + so + 4096);
    h8 rw2a = *(const h8*)(w2 + so);
    h8 rw2b = *(const h8*)(w2 + so + 4096);

    // BN1 scale/shift table (1 KB, overlaid in sW1f; dead after sX stage)
    float* sBN = (float*)&sW1f[0];
    if (tid < 128) {
        float mean = st1[tid] * invN;
        float var  = st1[128 + tid] * invN - mean * mean;
        float scl  = g1[tid] * rsqrtf(var + 1e-5f);
        sBN[tid]       = scl;
        sBN[128 + tid] = be1[tid] - mean * scl;
    }
    __syncthreads();

    // stage x' = BN1(y16) -> sX (swizzled)
    {
        const int row = tid >> 2;            // 0..127
        const int q   = tid & 3;
        const int qs  = ((q ^ (row >> 1)) & 3) << 3;
        const half_t* src = y16 + (size_t)(m0 + row) * 128 + q * 8;
        #pragma unroll
        for (int kc = 0; kc < 4; ++kc) {
            h8 v = *(const h8*)(src + kc * 32);
            h8 xv;
            #pragma unroll
            for (int r = 0; r < 8; ++r) {
                int c = kc * 32 + q * 8 + r;
                xv[r] = (half_t)((float)v[r] * sBN[c] + sBN[128 + c]);
            }
            *(h8*)(&sX[kc][row * 32 + qs]) = xv;
        }
    }

    f32x4 acc2[2][4] = {};

    for (int j = 0; j < 8; ++j) {
        // b1: FF2(j-1) done reading sW/sH; sX/sBN writes visible (j=0)
        asm volatile("s_waitcnt lgkmcnt(0)" ::: "memory");
        __builtin_amdgcn_s_barrier();
        __builtin_amdgcn_sched_barrier(0);
        // write W(j) from regs (compiler inserts the per-thread vmcnt waits)
        *(h8*)(&sW1f[so])        = rw1a;
        *(h8*)(&sW1f[so + 4096]) = rw1b;
        *(h8*)(&sW2f[so])        = rw2a;
        *(h8*)(&sW2f[so + 4096]) = rw2b;
        asm volatile("s_waitcnt lgkmcnt(0)" ::: "memory");
        __builtin_amdgcn_s_barrier();
        __builtin_amdgcn_sched_barrier(0);
        if (j < 7) {   // issue next round's loads; they fly under FF1+FF2
            const half_t* w1n = w1 + (size_t)(j + 1) * 8192;
            const half_t* w2n = w2 + (size_t)(j + 1) * 8192;
            rw1a = *(const h8*)(w1n + so);
            rw1b = *(const h8*)(w1n + so + 4096);
            rw2a = *(const h8*)(w2n + so);
            rw2b = *(const h8*)(w2n + so + 4096);
        }

        // FF1: wave tile 32x32 of 128x64 chunk
        f32x4 acc1[2][2] = {};
        #pragma unroll
        for (int kc = 0; kc < 4; ++kc) {
            h8 af[2], bf[2];
            #pragma unroll
            for (int mi = 0; mi < 2; ++mi) {
                int r = wr * 32 + mi * 16 + l16;
                af[mi] = *(const h8*)(&sX[kc][r * 32 + (((quad ^ (r >> 1)) & 3) << 3)]);
            }
            #pragma unroll
            for (int ni = 0; ni < 2; ++ni) {
                int n = wc * 32 + ni * 16 + l16;
                bf[ni] = *(const h8*)(&sW1f[kc * 2048 + n * 32 + (((quad ^ (n >> 1)) & 3) << 3)]);
            }
            #pragma unroll
            for (int mi = 0; mi < 2; ++mi)
            #pragma unroll
            for (int ni = 0; ni < 2; ++ni)
                acc1[mi][ni] = __builtin_amdgcn_mfma_f32_16x16x32_f16(af[mi], bf[ni], acc1[mi][ni], 0, 0, 0);
        }
        // bias + ReLU -> sH (swizzled scalar writes)
        #pragma unroll
        for (int ni = 0; ni < 2; ++ni) {
            int c = wc * 32 + ni * 16 + l16;       // 0..63
            float bvv = bf1[j * 64 + c];
            int kc2 = c >> 5, c5 = c & 31;
            #pragma unroll
            for (int mi = 0; mi < 2; ++mi)
            #pragma unroll
            for (int r = 0; r < 4; ++r) {
                int row = wr * 32 + mi * 16 + quad * 4 + r;
                float v = acc1[mi][ni][r] + bvv;
                v = v > 0.0f ? v : 0.0f;
                int hsw = (c5 & 7) | ((((c5 >> 3) ^ (row >> 1)) & 3) << 3);
                sH[kc2][row * 32 + hsw] = (half_t)v;
            }
        }
        asm volatile("s_waitcnt lgkmcnt(0)" ::: "memory");
        __builtin_amdgcn_s_barrier();
        __builtin_amdgcn_sched_barrier(0);

        // FF2 partial: wave tile 32x64, K-slice 64
        #pragma unroll
        for (int kc = 0; kc < 2; ++kc) {
            h8 af[2], bf[4];
            #pragma unroll
            for (int mi = 0; mi < 2; ++mi) {
                int r = wr * 32 + mi * 16 + l16;
                af[mi] = *(const h8*)(&sH[kc][r * 32 + (((quad ^ (r >> 1)) & 3) << 3)]);
            }
            #pragma unroll
            for (int ni = 0; ni < 4; ++ni) {
                int n = wc * 64 + ni * 16 + l16;
                bf[ni] = *(const h8*)(&sW2f[kc * 4096 + n * 32 + (((quad ^ (n >> 1)) & 3) << 3)]);
            }
            #pragma unroll
            for (int mi = 0; mi < 2; ++mi)
            #pragma unroll
            for (int ni = 0; ni < 4; ++ni)
                acc2[mi][ni] = __builtin_amdgcn_mfma_f32_16x16x32_f16(af[mi], bf[ni], acc2[mi][ni], 0, 0, 0);
        }
    }

    // epilogue: y2 = acc2 + bf2 + x' (x' read from sX), BN2 stats
    __syncthreads();                       // sH reads done -> reuse as reduction scratch
    float* red = (float*)&sH[0][0];        // [2][512] floats (s, ss)

    #pragma unroll
    for (int ni = 0; ni < 4; ++ni) {
        int col = wc * 64 + ni * 16 + l16;
        float bvv = bf2[col];
        int kc = col >> 5, c5 = col & 31;
        float s = 0.0f, ss = 0.0f;
        #pragma unroll
        for (int mi = 0; mi < 2; ++mi) {
            #pragma unroll
            for (int r = 0; r < 4; ++r) {
                int rowl = wr * 32 + mi * 16 + quad * 4 + r;
                int hsw = (c5 & 7) | ((((c5 >> 3) ^ (rowl >> 1)) & 3) << 3);
                float xv = (float)sX[kc][rowl * 32 + hsw];
                float o = acc2[mi][ni][r] + bvv + xv;
                y16[(size_t)(m0 + rowl) * 128 + col] = (half_t)o;
                s += o; ss += o * o;
            }
        }
        s  += __shfl_xor(s, 16);  s  += __shfl_xor(s, 32);
        ss += __shfl_xor(ss, 16); ss += __shfl_xor(ss, 32);
        if (quad == 0) {
            red[wave * 64 + ni * 16 + l16]       = s;
            red[512 + wave * 64 + ni * 16 + l16] = ss;
        }
    }
    __syncthreads();
    if (tid < 256) {
        int a   = tid >> 7;          // 0 = s, 1 = ss
        int col = tid & 127;
        int wcc = col >> 6, nii = (col >> 4) & 3, lx = col & 15;
        float t = 0.0f;
        #pragma unroll
        for (int w = 0; w < 4; ++w)
            t += red[a * 512 + (w * 2 + wcc) * 64 + nii * 16 + lx];
        atomicAdd(&stats[a * 128 + col], t);
    }
}

// ---------------- BatchNorm apply (writes swizzled xh image) ----------------
__global__ __launch_bounds__(256)
void bn_apply(const h8* __restrict__ y, const float* __restrict__ stats,
              const float* __restrict__ g, const float* __restrict__ be,
              half_t* __restrict__ xh, float* __restrict__ dst32)
{
    __shared__ float sh[256];
    const int tid = threadIdx.x;
    if (tid < 128) {
        const float invN = 1.0f / (float)TROWS;
        float mean = stats[tid] * invN;
        float var  = stats[128 + tid] * invN - mean * mean;
        float inv  = rsqrtf(var + 1e-5f);
        float scl  = g[tid] * inv;
        sh[tid]       = scl;
        sh[128 + tid] = be[tid] - mean * scl;
    }
    __syncthreads();

    int gid = blockIdx.x * 256 + tid;   // over TROWS*16 (8 ch each)
    int row = gid >> 4;
    int gr  = gid & 15;
    int c = gr * 8;
    h8 v = y[gid];
    h8 hv;
    float o[8];
    #pragma unroll
    for (int r = 0; r < 8; ++r) {
        o[r] = (float)v[r] * sh[c + r] + sh[128 + c + r];
        hv[r] = (half_t)o[r];
    }
    int grp = (gr & ~3) | ((gr ^ (row >> 1)) & 3);   // image granule
    *reinterpret_cast<h8*>(xh + (size_t)row * 128 + grp * 8) = hv;
    if (dst32) {
        f32x4 lo = { o[0], o[1], o[2], o[3] };
        f32x4 hi = { o[4], o[5], o[6], o[7] };
        ((f32x4*)dst32)[gid * 2]     = lo;
        ((f32x4*)dst32)[gid * 2 + 1] = hi;
    }
}

// ---------------- launch ----------------
extern "C" void kernel_launch(void* const* d_in, const int* in_sizes, int n_in,
                              void* d_out, int out_size, void* d_ws, size_t ws_size,
                              hipStream_t stream)
{
    const float* s    = (const float*)d_in[0];
    const int*   dd   = (const int*)d_in[1];
    const float* e_w  = (const float*)d_in[2];
    const float* e_b  = (const float*)d_in[3];
    const float* ep_w = (const float*)d_in[4];
    const float* ep_b = (const float*)d_in[5];
    const float* Wq   = (const float*)d_in[6];
    const float* bq   = (const float*)d_in[7];
    const float* Wk   = (const float*)d_in[8];
    const float* bk   = (const float*)d_in[9];
    const float* Wv   = (const float*)d_in[10];
    const float* bv   = (const float*)d_in[11];
    const float* Wo   = (const float*)d_in[12];
    const float* bo   = (const float*)d_in[13];
    const float* Wf1  = (const float*)d_in[14];
    const float* bf1  = (const float*)d_in[15];
    const float* Wf2  = (const float*)d_in[16];
    const float* bf2  = (const float*)d_in[17];
    const float* g1   = (const float*)d_in[18];
    const float* be1  = (const float*)d_in[19];
    const float* g2   = (const float*)d_in[20];
    const float* be2  = (const float*)d_in[21];

    char* ws = (char*)d_ws;
    size_t off = 0;
    auto alloc = [&](size_t bytes) -> void* {
        void* p = ws + off;
        off += (bytes + 255) & ~(size_t)255;
        return p;
    };
    half_t* y16   = (half_t*)alloc((size_t)TROWS * 128 * 2);
    half_t* xh    = (half_t*)alloc((size_t)TROWS * 128 * 2);
    half_t* wqkv  = (half_t*)alloc((size_t)3 * 384 * 128 * 2);
    half_t* wo    = (half_t*)alloc((size_t)3 * 128 * 128 * 2);
    half_t* wf1   = (half_t*)alloc((size_t)3 * 512 * 128 * 2);
    half_t* wf2   = (half_t*)alloc((size_t)3 * 128 * 512 * 2);
    float*  bqkv  = (float*) alloc((size_t)3 * 384 * 4);
    float*  stats = (float*) alloc(6 * 256 * 4);

    dim3 blk(256);

    hipMemsetAsync(stats, 0, 6 * 256 * 4, stream);

    prep_kernel<<<dim3(768, 7), blk, 0, stream>>>(Wq, Wk, Wv, Wo, Wf1, Wf2, bq, bk, bv,
                                                  wqkv, wo, wf1, wf2, bqkv);

    embed_kernel<<<dim3(TROWS * 128 / 256), blk, 0, stream>>>(s, dd, e_w, e_b, ep_w, ep_b, xh);

    for (int l = 0; l < 3; ++l) {
        float* st1 = stats + (size_t)(l * 2) * 256;
        float* st2 = stats + (size_t)(l * 2 + 1) * 256;
        // QKV + attention + O-proj + residual + BN1 stats -> y16
        layer_attn<<<dim3(BATCH), dim3(512), 0, stream>>>(xh, wqkv + (size_t)l * 49152,
                                                          bqkv + l * 384,
                                                          wo + (size_t)l * 16384,
                                                          bo + l * 128, y16, st1);
        // fused BN1-apply + FF1 + FF2 + residual + BN2 stats (in-place y16)
        ff_fused<<<dim3(404), dim3(512), 0, stream>>>(y16, st1, g1 + l * 128, be1 + l * 128,
                                                      wf1 + (size_t)l * 65536, wf2 + (size_t)l * 65536,
                                                      bf1 + l * 512, bf2 + l * 128, st2);
        // BN2 apply -> xh image (+ fp32 out on last layer)
        bn_apply<<<dim3(TROWS * 16 / 256), blk, 0, stream>>>((const h8*)y16, st2,
                                                             g2 + l * 128, be2 + l * 128,
                                                             xh, (l == 2) ? (float*)d_out : nullptr);
    }
}

// Round 9
// 378.959 us; speedup vs baseline: 1.3585x; 1.0338x over previous
//
#include <hip/hip_runtime.h>
#include <hip/hip_fp16.h>
#include <stdint.h>

#define TROWS 51712   // 512*101
#define NCITY 101
#define BATCH 512
#define EDIM  128
#define NBH   4096    // BATCH*8 heads

using half_t = _Float16;
typedef __attribute__((ext_vector_type(8))) _Float16 h8;
typedef __attribute__((ext_vector_type(4))) _Float16 h4;
typedef __attribute__((ext_vector_type(4))) float   f32x4;

typedef __attribute__((address_space(1))) const unsigned int gu32;
typedef __attribute__((address_space(3))) unsigned int lu32;
static __device__ __forceinline__ void async16(const void* g, const void* l) {
    __builtin_amdgcn_global_load_lds((gu32*)g, (lu32*)(uint32_t)(uintptr_t)l, 16, 0, 0);
}

// Quarter-XOR image swizzle (weights only): element (row, c) stored at
// c' = (c & ~31) | ((((c>>3) ^ (row>>1)) & 3) << 3) | (c & 7).
static __device__ __forceinline__ int swz_col(int c, int row) {
    return (c & ~31) | ((((c >> 3) ^ (row >> 1)) & 3) << 3) | (c & 7);
}

// ---------------- one-shot weight prep: all transposes + bias pack ----------------
__global__ __launch_bounds__(256)
void prep_kernel(const float* __restrict__ Wq, const float* __restrict__ Wk,
                 const float* __restrict__ Wv, const float* __restrict__ Wo,
                 const float* __restrict__ Wf1, const float* __restrict__ Wf2,
                 const float* __restrict__ bq, const float* __restrict__ bk,
                 const float* __restrict__ bv,
                 half_t* __restrict__ wqkv, half_t* __restrict__ wo,
                 half_t* __restrict__ wf1, half_t* __restrict__ wf2,
                 float* __restrict__ bqkv)
{
    const int which = blockIdx.y;
    const int gid = blockIdx.x * 256 + threadIdx.x;
    if (which <= 2) {
        if (gid >= 3 * 128 * 128) return;
        const float* src = (which == 0) ? Wq : (which == 1) ? Wk : Wv;
        int l = gid >> 14, r = gid & 16383, k = r >> 7, n = r & 127;
        wqkv[(size_t)l * 49152 + which * 16384 + n * 128 + swz_col(k, n)] = (half_t)src[gid];
    } else if (which == 3) {
        if (gid >= 3 * 128 * 128) return;
        int l = gid >> 14, r = gid & 16383, k = r >> 7, n = r & 127;
        wo[(size_t)l * 16384 + n * 128 + swz_col(k, n)] = (half_t)Wo[gid];
    } else if (which == 4) {
        // wf1 image: [l][j(8)][kc(4)][n(64)][h'(32)]
        if (gid >= 3 * 65536) return;
        int l = gid >> 16, u = gid & 65535;
        int j = u >> 13, kc = (u >> 11) & 3, n = (u >> 5) & 63, hp = u & 31;
        int k = kc * 32 + ((((hp >> 3) ^ (n >> 1)) & 3) << 3) + (hp & 7);
        wf1[(size_t)l * 65536 + u] = (half_t)Wf1[(size_t)(l * 128 + k) * 512 + j * 64 + n];
    } else if (which == 5) {
        // wf2 image: [l][j(8)][kc2(2)][n(128)][h'(32)]
        if (gid >= 3 * 65536) return;
        int l = gid >> 16, u = gid & 65535;
        int j = u >> 13, kc = (u >> 12) & 1, n = (u >> 5) & 127, hp = u & 31;
        int kh = j * 64 + kc * 32 + ((((hp >> 3) ^ (n >> 1)) & 3) << 3) + (hp & 7);
        wf2[(size_t)l * 65536 + u] = (half_t)Wf2[(size_t)(l * 512 + kh) * 128 + n];
    } else {
        if (gid >= 3 * 384) return;
        int l = gid / 384, c = gid - l * 384;
        float v = (c < 128) ? bq[l * 128 + c]
                : (c < 256) ? bk[l * 128 + c - 128]
                            : bv[l * 128 + c - 256];
        bqkv[gid] = v;
    }
}

// ---------------- embedding (plain xh) ----------------
__global__ __launch_bounds__(256)
void embed_kernel(const float* __restrict__ s, const int* __restrict__ d,
                  const float* __restrict__ e_w, const float* __restrict__ e_b,
                  const float* __restrict__ ep_w, const float* __restrict__ ep_b,
                  half_t* __restrict__ xh)
{
    int gid = blockIdx.x * 256 + threadIdx.x;      // over TROWS*128
    int row = gid >> 7;
    int c   = gid & 127;
    int b = row / NCITY;
    int n = row - b * NCITY;
    const float* sp = s + ((size_t)b * NCITY + n) * 2;
    float v;
    if (n == 0) {
        v = sp[0] * ep_w[c] + sp[1] * ep_w[128 + c] + ep_b[c];
    } else {
        float dv = (float)d[b * NCITY + n];
        v = sp[0] * e_w[c] + sp[1] * e_w[128 + c] + dv * e_w[256 + c] + e_b[c];
    }
    xh[gid] = (half_t)v;
}

// ---------------- fused [BN2-prev] + QKV + attention + O-proj + residual + BN1 stats
// One block per batch element, 512 threads, 8 waves = 1 wave per head.
// xsrc = plain fp16 [row][128] (xh for layer 0, y16 in-place for layers 1-2).
// stats0 != null: apply BN2(prev layer) inline (table in phase 1, scalars in ph 4).
// Phase 1: stage x' -> sX (local quarter-swizzle, rows>=101 zeroed).
// Phase 2: each wave computes ITS head's Q/K/V into wave-private LDS.
// Phase 3: attention per wave.   Phase 4: O-proj + residual + BN1 stats.
__global__ __launch_bounds__(512, 1)
void layer_attn(const half_t* __restrict__ xsrc, const float* __restrict__ stats0,
                const float* __restrict__ g0, const float* __restrict__ be0,
                const half_t* __restrict__ wqkv, const float* __restrict__ bqkv,
                const half_t* __restrict__ wo, const float* __restrict__ bo,
                half_t* __restrict__ y16, float* __restrict__ stats)
{
    __shared__ alignas(16) half_t sO[112 * 136];          // 30.5 KB (overlays sX)
    __shared__ alignas(16) half_t sQKV[3][8][112 * 16];   // 84 KB
    half_t* sX = sO;                                      // [4][112*32] = 28 KB
    float* sBN2 = (float*)&sQKV[0][0][0];                 // 1 KB table (dead before ph2)

    const int b   = blockIdx.x;
    const int tid = threadIdx.x;
    const int wave = tid >> 6, lane = tid & 63;
    const int quad = lane >> 4, l16 = lane & 15;
    const float invN = 1.0f / (float)TROWS;

    // ---- phase 1: BN2 table (if prev layer), then stage x' tile
    if (stats0) {
        if (tid < 128) {
            float mean = stats0[tid] * invN;
            float var  = stats0[128 + tid] * invN - mean * mean;
            float scl  = g0[tid] * rsqrtf(var + 1e-5f);
            sBN2[tid]       = scl;
            sBN2[128 + tid] = be0[tid] - mean * scl;
        }
        __syncthreads();
    }
    if (tid < 448) {
        int row = tid >> 2, q = tid & 3;
        int qs = ((q ^ (row >> 1)) & 3) << 3;
        h8 out[4];
        if (row < NCITY) {
            const half_t* src = xsrc + ((size_t)b * NCITY + row) * 128 + q * 8;
            #pragma unroll
            for (int kc = 0; kc < 4; ++kc) {
                h8 v = *(const h8*)(src + kc * 32);
                if (stats0) {
                    #pragma unroll
                    for (int r = 0; r < 8; ++r) {
                        int c = kc * 32 + q * 8 + r;
                        v[r] = (half_t)((float)v[r] * sBN2[c] + sBN2[128 + c]);
                    }
                }
                out[kc] = v;
            }
        } else {
            h8 z = {};
            out[0] = z; out[1] = z; out[2] = z; out[3] = z;
        }
        #pragma unroll
        for (int kc = 0; kc < 4; ++kc)
            *(h8*)(&sX[kc * 3584 + row * 32 + qs]) = out[kc];
    }
    __syncthreads();

    // ---- phase 2: per-wave QKV for head `wave`
    const int hn  = wave * 16 + l16;         // output column 0..127
    const int nsw = (hn >> 1) & 3;
    h8 bfr[3][4];
    float bv3[3];
    #pragma unroll
    for (int which = 0; which < 3; ++which) {
        const half_t* wrow = wqkv + which * 16384 + (size_t)hn * 128;
        #pragma unroll
        for (int kc = 0; kc < 4; ++kc)
            bfr[which][kc] = *(const h8*)(wrow + kc * 32 + (((quad ^ nsw) & 3) << 3));
        bv3[which] = bqkv[which * 128 + hn];
    }
    #pragma unroll
    for (int mi = 0; mi < 7; ++mi) {
        h8 af[4];
        #pragma unroll
        for (int kc = 0; kc < 4; ++kc) {
            int r = mi * 16 + l16;
            af[kc] = *(const h8*)(&sX[kc * 3584 + r * 32 + (((quad ^ (r >> 1)) & 3) << 3)]);
        }
        #pragma unroll
        for (int which = 0; which < 3; ++which) {
            f32x4 a = {};
            #pragma unroll
            for (int kc = 0; kc < 4; ++kc)
                a = __builtin_amdgcn_mfma_f32_16x16x32_f16(af[kc], bfr[which][kc], a, 0, 0, 0);
            half_t* dstL = &sQKV[which][wave][0];
            #pragma unroll
            for (int r = 0; r < 4; ++r) {
                int tok = mi * 16 + quad * 4 + r;
                int dsw = l16 ^ (((tok >> 2) & 1) << 3);
                dstL[tok * 16 + dsw] = (half_t)(a[r] + bv3[which]);
            }
        }
    }
    __syncthreads();   // all waves done reading sX -> sO overlay is safe

    // ---- phase 3: attention (per-wave private; K/V/Q from LDS)
    const half_t* qb = &sQKV[0][wave][0];
    const half_t* kb = &sQKV[1][wave][0];
    const half_t* vb = &sQKV[2][wave][0];
    const int kflip = (l16 >> 2) & 1;

    const int s0 = (((quad & 1) * 2)    ) * 16 + l16;
    const int s1 = (((quad & 1) * 2) + 1) * 16 + l16;
    const bool hi2 = (quad >> 1) != 0;

    h8 kf[7];
    #pragma unroll
    for (int jt = 0; jt < 7; ++jt) {
        kf[jt] = (h8){};
        if (quad < 2)
            kf[jt] = *(const h8*)(kb + (jt * 16 + l16) * 16 + ((quad ^ kflip) << 3));
    }
    h8 vt[4];
    #pragma unroll
    for (int p = 0; p < 4; ++p)
        #pragma unroll
        for (int jj = 0; jj < 8; ++jj) {
            int tok = p * 32 + quad * 8 + jj;
            vt[p][jj] = vb[tok * 16 + (l16 ^ (((jj >> 2) & 1) << 3))];
        }

    const int ocol = hn;                       // this wave's output column

    for (int it = 0; it < 7; ++it) {
        h8 qf = {};
        if (quad < 2)
            qf = *(const h8*)(qb + (it * 16 + l16) * 16 + ((quad ^ kflip) << 3));

        f32x4 S[7];
        #pragma unroll
        for (int jt = 0; jt < 7; ++jt) {
            f32x4 a = {};
            a = __builtin_amdgcn_mfma_f32_16x16x32_f16(kf[jt], qf, a, 0, 0, 0);
            S[jt] = a;
        }
        float m = -1e30f;
        #pragma unroll
        for (int jt = 0; jt < 7; ++jt)
            #pragma unroll
            for (int r = 0; r < 4; ++r) {
                int jg = jt * 16 + quad * 4 + r;
                float sv = (jg < NCITY) ? S[jt][r] * 0.25f : -1e30f;
                S[jt][r] = sv;
                m = fmaxf(m, sv);
            }
        m = fmaxf(m, __shfl_xor(m, 16));
        m = fmaxf(m, __shfl_xor(m, 32));
        float sum = 0.0f;
        #pragma unroll
        for (int jt = 0; jt < 7; ++jt)
            #pragma unroll
            for (int r = 0; r < 4; ++r) {
                float e = __expf(S[jt][r] - m);
                S[jt][r] = e;
                sum += e;
            }
        sum += __shfl_xor(sum, 16);
        sum += __shfl_xor(sum, 32);
        float inv = 1.0f / sum;
        #pragma unroll
        for (int jt = 0; jt < 7; ++jt)
            #pragma unroll
            for (int r = 0; r < 4; ++r) S[jt][r] *= inv;

        f32x4 O = {};
        #pragma unroll
        for (int p = 0; p < 4; ++p) {
            float pj[8];
            #pragma unroll
            for (int r = 0; r < 4; ++r) {
                float a0 = __shfl(S[2 * p][r],     s0);
                float b0 = __shfl(S[2 * p + 1][r], s0);
                float a1 = __shfl(S[2 * p][r],     s1);
                float b1 = __shfl(S[2 * p + 1][r], s1);
                pj[r]     = hi2 ? b0 : a0;
                pj[4 + r] = hi2 ? b1 : a1;
            }
            h8 ph;
            #pragma unroll
            for (int jj = 0; jj < 8; ++jj)
                ph[jj] = (half_t)pj[jj];
            O = __builtin_amdgcn_mfma_f32_16x16x32_f16(ph, vt[p], O, 0, 0, 0);
        }
        // O -> LDS transpose tile (tail rows harmless garbage)
        #pragma unroll
        for (int r = 0; r < 4; ++r) {
            int q = it * 16 + quad * 4 + r;
            int g = (ocol >> 3) ^ ((q & 8) >> 2);
            sO[q * 136 + g * 8 + (ocol & 7)] = (half_t)O[r];
        }
    }
    __syncthreads();

    // ---- phase 4: O-proj (wave w owns cols w*16..+15), residual(+BN2), BN1 stats
    h8 bfr2[4];
    {
        const half_t* wrow = wo + (size_t)ocol * 128;
        const int nsw2 = (ocol >> 1) & 3;
        #pragma unroll
        for (int kc = 0; kc < 4; ++kc)
            bfr2[kc] = *(const h8*)(wrow + kc * 32 + (((quad ^ nsw2) & 3) << 3));
    }
    f32x4 acc[7];
    #pragma unroll
    for (int mi = 0; mi < 7; ++mi) {
        acc[mi] = (f32x4){};
        int row = mi * 16 + l16;
        int swr = (row & 8) >> 2;
        #pragma unroll
        for (int kc = 0; kc < 4; ++kc) {
            h8 af = *(const h8*)(&sO[row * 136 + (((kc * 4 + quad) ^ swr) << 3)]);
            acc[mi] = __builtin_amdgcn_mfma_f32_16x16x32_f16(af, bfr2[kc], acc[mi], 0, 0, 0);
        }
    }
    float sclo = 1.0f, shfo = 0.0f;
    if (stats0) {
        float mean = stats0[ocol] * invN;
        float var  = stats0[128 + ocol] * invN - mean * mean;
        sclo = g0[ocol] * rsqrtf(var + 1e-5f);
        shfo = be0[ocol] - mean * sclo;
    }
    float bvv = bo[ocol];
    float s = 0.0f, ss = 0.0f;
    #pragma unroll
    for (int mi = 0; mi < 7; ++mi) {
        #pragma unroll
        for (int r = 0; r < 4; ++r) {
            int q = mi * 16 + quad * 4 + r;
            if (q < NCITY) {
                size_t grow = (size_t)b * NCITY + q;
                float xv = (float)xsrc[grow * 128 + ocol] * sclo + shfo;
                float o = acc[mi][r] + bvv + xv;
                y16[grow * 128 + ocol] = (half_t)o;
                s += o; ss += o * o;
            }
        }
    }
    s  += __shfl_xor(s, 16);  s  += __shfl_xor(s, 32);
    ss += __shfl_xor(ss, 16); ss += __shfl_xor(ss, 32);
    if (quad == 0) {
        atomicAdd(&stats[ocol], s);
        atomicAdd(&stats[128 + ocol], ss);
    }
}

// ---------------- fused BN1 + FF1(ReLU) + FF2 ----------------
// 512 threads / 8 waves, 80 KB LDS -> 2 blocks/CU.
// Weights reg-staged: next round's loads issued under compute.
// Epilogue residual x' read back from sX (LDS) -- no y16 re-read.
__global__ __launch_bounds__(512, 4)
void ff_fused(half_t* __restrict__ y16, const float* __restrict__ st1,
              const float* __restrict__ g1, const float* __restrict__ be1,
              const half_t* __restrict__ w1, const half_t* __restrict__ w2,
              const float* __restrict__ bf1, const float* __restrict__ bf2,
              float* __restrict__ stats)
{
    __shared__ alignas(16) half_t sX[4][128 * 32];   // 32 KB  x' tile
    __shared__ alignas(16) half_t sW1f[8192];        // 16 KB  wf1 chunk image (flat)
    __shared__ alignas(16) half_t sW2f[8192];        // 16 KB  wf2 chunk image (flat)
    __shared__ alignas(16) half_t sH[2][128 * 32];   // 16 KB  relu chunk

    const int tid  = threadIdx.x;
    const int wave = tid >> 6, lane = tid & 63;
    const int quad = lane >> 4, l16 = lane & 15;
    const int m0 = blockIdx.x * 128;
    const int wr = wave >> 1;          // 0..3: 32-row group
    const int wc = wave & 1;           // col group

    const float invN = 1.0f / (float)TROWS;
    const int so = wave * 512 + lane * 8;    // identity global<->LDS offset

    // prologue: round-0 weight regs
    h8 rw1a = *(const h8*)(w1 + so);
    h8 rw1b = *(const h8*)(w1 + so + 4096);
    h8 rw2a = *(const h8*)(w2 + so);
    h8 rw2b = *(const h8*)(w2 + so + 4096);

    // BN1 scale/shift table (1 KB, overlaid in sW1f; dead after sX stage)
    float* sBN = (float*)&sW1f[0];
    if (tid < 128) {
        float mean = st1[tid] * invN;
        float var  = st1[128 + tid] * invN - mean * mean;
        float scl  = g1[tid] * rsqrtf(var + 1e-5f);
        sBN[tid]       = scl;
        sBN[128 + tid] = be1[tid] - mean * scl;
    }
    __syncthreads();

    // stage x' = BN1(y16) -> sX (swizzled)
    {
        const int row = tid >> 2;            // 0..127
        const int q   = tid & 3;
        const int qs  = ((q ^ (row >> 1)) & 3) << 3;
        const half_t* src = y16 + (size_t)(m0 + row) * 128 + q * 8;
        #pragma unroll
        for (int kc = 0; kc < 4; ++kc) {
            h8 v = *(const h8*)(src + kc * 32);
            h8 xv;
            #pragma unroll
            for (int r = 0; r < 8; ++r) {
                int c = kc * 32 + q * 8 + r;
                xv[r] = (half_t)((float)v[r] * sBN[c] + sBN[128 + c]);
            }
            *(h8*)(&sX[kc][row * 32 + qs]) = xv;
        }
    }

    f32x4 acc2[2][4] = {};

    for (int j = 0; j < 8; ++j) {
        // b1: FF2(j-1) done reading sW/sH; sX/sBN writes visible (j=0)
        asm volatile("s_waitcnt lgkmcnt(0)" ::: "memory");
        __builtin_amdgcn_s_barrier();
        __builtin_amdgcn_sched_barrier(0);
        // write W(j) from regs (compiler inserts the per-thread vmcnt waits)
        *(h8*)(&sW1f[so])        = rw1a;
        *(h8*)(&sW1f[so + 4096]) = rw1b;
        *(h8*)(&sW2f[so])        = rw2a;
        *(h8*)(&sW2f[so + 4096]) = rw2b;
        asm volatile("s_waitcnt lgkmcnt(0)" ::: "memory");
        __builtin_amdgcn_s_barrier();
        __builtin_amdgcn_sched_barrier(0);
        if (j < 7) {   // issue next round's loads; they fly under FF1+FF2
            const half_t* w1n = w1 + (size_t)(j + 1) * 8192;
            const half_t* w2n = w2 + (size_t)(j + 1) * 8192;
            rw1a = *(const h8*)(w1n + so);
            rw1b = *(const h8*)(w1n + so + 4096);
            rw2a = *(const h8*)(w2n + so);
            rw2b = *(const h8*)(w2n + so + 4096);
        }

        // FF1: wave tile 32x32 of 128x64 chunk
        f32x4 acc1[2][2] = {};
        #pragma unroll
        for (int kc = 0; kc < 4; ++kc) {
            h8 af[2], bf[2];
            #pragma unroll
            for (int mi = 0; mi < 2; ++mi) {
                int r = wr * 32 + mi * 16 + l16;
                af[mi] = *(const h8*)(&sX[kc][r * 32 + (((quad ^ (r >> 1)) & 3) << 3)]);
            }
            #pragma unroll
            for (int ni = 0; ni < 2; ++ni) {
                int n = wc * 32 + ni * 16 + l16;
                bf[ni] = *(const h8*)(&sW1f[kc * 2048 + n * 32 + (((quad ^ (n >> 1)) & 3) << 3)]);
            }
            #pragma unroll
            for (int mi = 0; mi < 2; ++mi)
            #pragma unroll
            for (int ni = 0; ni < 2; ++ni)
                acc1[mi][ni] = __builtin_amdgcn_mfma_f32_16x16x32_f16(af[mi], bf[ni], acc1[mi][ni], 0, 0, 0);
        }
        // bias + ReLU -> sH (swizzled scalar writes)
        #pragma unroll
        for (int ni = 0; ni < 2; ++ni) {
            int c = wc * 32 + ni * 16 + l16;       // 0..63
            float bvv = bf1[j * 64 + c];
            int kc2 = c >> 5, c5 = c & 31;
            #pragma unroll
            for (int mi = 0; mi < 2; ++mi)
            #pragma unroll
            for (int r = 0; r < 4; ++r) {
                int row = wr * 32 + mi * 16 + quad * 4 + r;
                float v = acc1[mi][ni][r] + bvv;
                v = v > 0.0f ? v : 0.0f;
                int hsw = (c5 & 7) | ((((c5 >> 3) ^ (row >> 1)) & 3) << 3);
                sH[kc2][row * 32 + hsw] = (half_t)v;
            }
        }
        asm volatile("s_waitcnt lgkmcnt(0)" ::: "memory");
        __builtin_amdgcn_s_barrier();
        __builtin_amdgcn_sched_barrier(0);

        // FF2 partial: wave tile 32x64, K-slice 64
        #pragma unroll
        for (int kc = 0; kc < 2; ++kc) {
            h8 af[2], bf[4];
            #pragma unroll
            for (int mi = 0; mi < 2; ++mi) {
                int r = wr * 32 + mi * 16 + l16;
                af[mi] = *(const h8*)(&sH[kc][r * 32 + (((quad ^ (r >> 1)) & 3) << 3)]);
            }
            #pragma unroll
            for (int ni = 0; ni < 4; ++ni) {
                int n = wc * 64 + ni * 16 + l16;
                bf[ni] = *(const h8*)(&sW2f[kc * 4096 + n * 32 + (((quad ^ (n >> 1)) & 3) << 3)]);
            }
            #pragma unroll
            for (int mi = 0; mi < 2; ++mi)
            #pragma unroll
            for (int ni = 0; ni < 4; ++ni)
                acc2[mi][ni] = __builtin_amdgcn_mfma_f32_16x16x32_f16(af[mi], bf[ni], acc2[mi][ni], 0, 0, 0);
        }
    }

    // epilogue: y2 = acc2 + bf2 + x' (x' read from sX), BN2 stats
    __syncthreads();                       // sH reads done -> reuse as reduction scratch
    float* red = (float*)&sH[0][0];        // [2][512] floats (s, ss)

    #pragma unroll
    for (int ni = 0; ni < 4; ++ni) {
        int col = wc * 64 + ni * 16 + l16;
        float bvv = bf2[col];
        int kc = col >> 5, c5 = col & 31;
        float s = 0.0f, ss = 0.0f;
        #pragma unroll
        for (int mi = 0; mi < 2; ++mi) {
            #pragma unroll
            for (int r = 0; r < 4; ++r) {
                int rowl = wr * 32 + mi * 16 + quad * 4 + r;
                int hsw = (c5 & 7) | ((((c5 >> 3) ^ (rowl >> 1)) & 3) << 3);
                float xv = (float)sX[kc][rowl * 32 + hsw];
                float o = acc2[mi][ni][r] + bvv + xv;
                y16[(size_t)(m0 + rowl) * 128 + col] = (half_t)o;
                s += o; ss += o * o;
            }
        }
        s  += __shfl_xor(s, 16);  s  += __shfl_xor(s, 32);
        ss += __shfl_xor(ss, 16); ss += __shfl_xor(ss, 32);
        if (quad == 0) {
            red[wave * 64 + ni * 16 + l16]       = s;
            red[512 + wave * 64 + ni * 16 + l16] = ss;
        }
    }
    __syncthreads();
    if (tid < 256) {
        int a   = tid >> 7;          // 0 = s, 1 = ss
        int col = tid & 127;
        int wcc = col >> 6, nii = (col >> 4) & 3, lx = col & 15;
        float t = 0.0f;
        #pragma unroll
        for (int w = 0; w < 4; ++w)
            t += red[a * 512 + (w * 2 + wcc) * 64 + nii * 16 + lx];
        atomicAdd(&stats[a * 128 + col], t);
    }
}

// ---------------- BatchNorm apply (final layer only: fp32 out) ----------------
__global__ __launch_bounds__(256)
void bn_apply(const h8* __restrict__ y, const float* __restrict__ stats,
              const float* __restrict__ g, const float* __restrict__ be,
              float* __restrict__ dst32)
{
    __shared__ float sh[256];
    const int tid = threadIdx.x;
    if (tid < 128) {
        const float invN = 1.0f / (float)TROWS;
        float mean = stats[tid] * invN;
        float var  = stats[128 + tid] * invN - mean * mean;
        float inv  = rsqrtf(var + 1e-5f);
        float scl  = g[tid] * inv;
        sh[tid]       = scl;
        sh[128 + tid] = be[tid] - mean * scl;
    }
    __syncthreads();

    int gid = blockIdx.x * 256 + tid;   // over TROWS*16 (8 ch each)
    int c = (gid & 15) * 8;
    h8 v = y[gid];
    float o[8];
    #pragma unroll
    for (int r = 0; r < 8; ++r)
        o[r] = (float)v[r] * sh[c + r] + sh[128 + c + r];
    f32x4 lo = { o[0], o[1], o[2], o[3] };
    f32x4 hi = { o[4], o[5], o[6], o[7] };
    ((f32x4*)dst32)[gid * 2]     = lo;
    ((f32x4*)dst32)[gid * 2 + 1] = hi;
}

// ---------------- launch ----------------
extern "C" void kernel_launch(void* const* d_in, const int* in_sizes, int n_in,
                              void* d_out, int out_size, void* d_ws, size_t ws_size,
                              hipStream_t stream)
{
    const float* s    = (const float*)d_in[0];
    const int*   dd   = (const int*)d_in[1];
    const float* e_w  = (const float*)d_in[2];
    const float* e_b  = (const float*)d_in[3];
    const float* ep_w = (const float*)d_in[4];
    const float* ep_b = (const float*)d_in[5];
    const float* Wq   = (const float*)d_in[6];
    const float* bq   = (const float*)d_in[7];
    const float* Wk   = (const float*)d_in[8];
    const float* bk   = (const float*)d_in[9];
    const float* Wv   = (const float*)d_in[10];
    const float* bv   = (const float*)d_in[11];
    const float* Wo   = (const float*)d_in[12];
    const float* bo   = (const float*)d_in[13];
    const float* Wf1  = (const float*)d_in[14];
    const float* bf1  = (const float*)d_in[15];
    const float* Wf2  = (const float*)d_in[16];
    const float* bf2  = (const float*)d_in[17];
    const float* g1   = (const float*)d_in[18];
    const float* be1  = (const float*)d_in[19];
    const float* g2   = (const float*)d_in[20];
    const float* be2  = (const float*)d_in[21];

    char* ws = (char*)d_ws;
    size_t off = 0;
    auto alloc = [&](size_t bytes) -> void* {
        void* p = ws + off;
        off += (bytes + 255) & ~(size_t)255;
        return p;
    };
    half_t* y16   = (half_t*)alloc((size_t)TROWS * 128 * 2);
    half_t* xh    = (half_t*)alloc((size_t)TROWS * 128 * 2);
    half_t* wqkv  = (half_t*)alloc((size_t)3 * 384 * 128 * 2);
    half_t* wo    = (half_t*)alloc((size_t)3 * 128 * 128 * 2);
    half_t* wf1   = (half_t*)alloc((size_t)3 * 512 * 128 * 2);
    half_t* wf2   = (half_t*)alloc((size_t)3 * 128 * 512 * 2);
    float*  bqkv  = (float*) alloc((size_t)3 * 384 * 4);
    float*  stats = (float*) alloc(6 * 256 * 4);

    dim3 blk(256);

    hipMemsetAsync(stats, 0, 6 * 256 * 4, stream);

    prep_kernel<<<dim3(768, 7), blk, 0, stream>>>(Wq, Wk, Wv, Wo, Wf1, Wf2, bq, bk, bv,
                                                  wqkv, wo, wf1, wf2, bqkv);

    embed_kernel<<<dim3(TROWS * 128 / 256), blk, 0, stream>>>(s, dd, e_w, e_b, ep_w, ep_b, xh);

    for (int l = 0; l < 3; ++l) {
        float* st1 = stats + (size_t)(l * 2) * 256;
        float* st2 = stats + (size_t)(l * 2 + 1) * 256;
        const float* st0 = (l == 0) ? nullptr : stats + (size_t)((l - 1) * 2 + 1) * 256;
        const half_t* xsrc = (l == 0) ? xh : y16;
        // [BN2 prev] + QKV + attention + O-proj + residual + BN1 stats -> y16
        layer_attn<<<dim3(BATCH), dim3(512), 0, stream>>>(xsrc, st0,
                                                          g2 + (l ? (l - 1) * 128 : 0),
                                                          be2 + (l ? (l - 1) * 128 : 0),
                                                          wqkv + (size_t)l * 49152,
                                                          bqkv + l * 384,
                                                          wo + (size_t)l * 16384,
                                                          bo + l * 128, y16, st1);
        // fused BN1-apply + FF1 + FF2 + residual + BN2 stats (in-place y16)
        ff_fused<<<dim3(404), dim3(512), 0, stream>>>(y16, st1, g1 + l * 128, be1 + l * 128,
                                                      wf1 + (size_t)l * 65536, wf2 + (size_t)l * 65536,
                                                      bf1 + l * 512, bf2 + l * 128, st2);
    }
    // final BN2 apply -> fp32 output
    bn_apply<<<dim3(TROWS * 16 / 256), blk, 0, stream>>>((const h8*)y16, stats + 5 * 256,
                                                         g2 + 2 * 128, be2 + 2 * 128,
                                                         (float*)d_out);
}

// Round 10
// 363.144 us; speedup vs baseline: 1.4176x; 1.0436x over previous
//
#include <hip/hip_runtime.h>
#include <hip/hip_fp16.h>
#include <stdint.h>

#define TROWS 51712   // 512*101
#define NCITY 101
#define BATCH 512
#define EDIM  128
#define NBH   4096    // BATCH*8 heads

using half_t = _Float16;
typedef __attribute__((ext_vector_type(8))) _Float16 h8;
typedef __attribute__((ext_vector_type(4))) _Float16 h4;
typedef __attribute__((ext_vector_type(4))) float   f32x4;

typedef __attribute__((address_space(1))) const unsigned int gu32;
typedef __attribute__((address_space(3))) unsigned int lu32;
static __device__ __forceinline__ void async16(const void* g, const void* l) {
    __builtin_amdgcn_global_load_lds((gu32*)g, (lu32*)(uint32_t)(uintptr_t)l, 16, 0, 0);
}

// Quarter-XOR image swizzle (weights only): element (row, c) stored at
// c' = (c & ~31) | ((((c>>3) ^ (row>>1)) & 3) << 3) | (c & 7).
static __device__ __forceinline__ int swz_col(int c, int row) {
    return (c & ~31) | ((((c >> 3) ^ (row >> 1)) & 3) << 3) | (c & 7);
}

// ---------------- one-shot weight prep: all transposes + bias pack ----------------
__global__ __launch_bounds__(256)
void prep_kernel(const float* __restrict__ Wq, const float* __restrict__ Wk,
                 const float* __restrict__ Wv, const float* __restrict__ Wo,
                 const float* __restrict__ Wf1, const float* __restrict__ Wf2,
                 const float* __restrict__ bq, const float* __restrict__ bk,
                 const float* __restrict__ bv,
                 half_t* __restrict__ wqkv, half_t* __restrict__ wo,
                 half_t* __restrict__ wf1, half_t* __restrict__ wf2,
                 float* __restrict__ bqkv)
{
    const int which = blockIdx.y;
    const int gid = blockIdx.x * 256 + threadIdx.x;
    if (which <= 2) {
        if (gid >= 3 * 128 * 128) return;
        const float* src = (which == 0) ? Wq : (which == 1) ? Wk : Wv;
        int l = gid >> 14, r = gid & 16383, k = r >> 7, n = r & 127;
        wqkv[(size_t)l * 49152 + which * 16384 + n * 128 + swz_col(k, n)] = (half_t)src[gid];
    } else if (which == 3) {
        if (gid >= 3 * 128 * 128) return;
        int l = gid >> 14, r = gid & 16383, k = r >> 7, n = r & 127;
        wo[(size_t)l * 16384 + n * 128 + swz_col(k, n)] = (half_t)Wo[gid];
    } else if (which == 4) {
        // wf1 image: [l][j(8)][kc(4)][n(64)][h'(32)]
        if (gid >= 3 * 65536) return;
        int l = gid >> 16, u = gid & 65535;
        int j = u >> 13, kc = (u >> 11) & 3, n = (u >> 5) & 63, hp = u & 31;
        int k = kc * 32 + ((((hp >> 3) ^ (n >> 1)) & 3) << 3) + (hp & 7);
        wf1[(size_t)l * 65536 + u] = (half_t)Wf1[(size_t)(l * 128 + k) * 512 + j * 64 + n];
    } else if (which == 5) {
        // wf2 image: [l][j(8)][kc2(2)][n(128)][h'(32)]
        if (gid >= 3 * 65536) return;
        int l = gid >> 16, u = gid & 65535;
        int j = u >> 13, kc = (u >> 12) & 1, n = (u >> 5) & 127, hp = u & 31;
        int kh = j * 64 + kc * 32 + ((((hp >> 3) ^ (n >> 1)) & 3) << 3) + (hp & 7);
        wf2[(size_t)l * 65536 + u] = (half_t)Wf2[(size_t)(l * 512 + kh) * 128 + n];
    } else {
        if (gid >= 3 * 384) return;
        int l = gid / 384, c = gid - l * 384;
        float v = (c < 128) ? bq[l * 128 + c]
                : (c < 256) ? bk[l * 128 + c - 128]
                            : bv[l * 128 + c - 256];
        bqkv[gid] = v;
    }
}

// ---------------- embedding (plain xh) ----------------
__global__ __launch_bounds__(256)
void embed_kernel(const float* __restrict__ s, const int* __restrict__ d,
                  const float* __restrict__ e_w, const float* __restrict__ e_b,
                  const float* __restrict__ ep_w, const float* __restrict__ ep_b,
                  half_t* __restrict__ xh)
{
    int gid = blockIdx.x * 256 + threadIdx.x;      // over TROWS*128
    int row = gid >> 7;
    int c   = gid & 127;
    int b = row / NCITY;
    int n = row - b * NCITY;
    const float* sp = s + ((size_t)b * NCITY + n) * 2;
    float v;
    if (n == 0) {
        v = sp[0] * ep_w[c] + sp[1] * ep_w[128 + c] + ep_b[c];
    } else {
        float dv = (float)d[b * NCITY + n];
        v = sp[0] * e_w[c] + sp[1] * e_w[128 + c] + dv * e_w[256 + c] + e_b[c];
    }
    xh[gid] = (half_t)v;
}

// ---------------- fused [BN2-prev] + QKV + attention + O-proj + residual + BN1 stats
// One block per batch element, 512 threads, 8 waves = 1 wave per head.
// 80 KB LDS -> 2 blocks/CU (all 512 blocks co-resident):
//   Region A (28,672 B): sX (phases 1-2), then sQ overlay (Q held in regs across
//                        the phase-2 barrier, then written into the dead sX).
//   Region B (53,248 B): sK|sV at 104 rows (phases 2-3; writes masked tok<104,
//                        reads clamped), then sO [112][136] overlay (ph 3b-4).
__global__ __launch_bounds__(512, 4)
void layer_attn(const half_t* __restrict__ xsrc, const float* __restrict__ stats0,
                const float* __restrict__ g0, const float* __restrict__ be0,
                const half_t* __restrict__ wqkv, const float* __restrict__ bqkv,
                const half_t* __restrict__ wo, const float* __restrict__ bo,
                half_t* __restrict__ y16, float* __restrict__ stats)
{
    __shared__ alignas(16) half_t regA[14336];   // 28,672 B
    __shared__ alignas(16) half_t regB[26624];   // 53,248 B
    half_t* sX = regA;                 // [4][112*32]
    half_t* sQ = regA;                 // [8][112*16]  (overlay, post-phase-2)
    half_t* sK = regB;                 // [8][104*16]
    half_t* sV = regB + 13312;         // [8][104*16]
    half_t* sO = regB;                 // [112*136]    (overlay, post-kf/vt)
    float* sBN2 = (float*)regB;        // 1 KB table (phase 1 only; dead before K writes)

    const int b   = blockIdx.x;
    const int tid = threadIdx.x;
    const int wave = tid >> 6, lane = tid & 63;
    const int quad = lane >> 4, l16 = lane & 15;
    const float invN = 1.0f / (float)TROWS;

    // ---- phase 1: BN2 table (if prev layer), then stage x' tile
    if (stats0) {
        if (tid < 128) {
            float mean = stats0[tid] * invN;
            float var  = stats0[128 + tid] * invN - mean * mean;
            float scl  = g0[tid] * rsqrtf(var + 1e-5f);
            sBN2[tid]       = scl;
            sBN2[128 + tid] = be0[tid] - mean * scl;
        }
        __syncthreads();
    }
    if (tid < 448) {
        int row = tid >> 2, q = tid & 3;
        int qs = ((q ^ (row >> 1)) & 3) << 3;
        h8 out[4];
        if (row < NCITY) {
            const half_t* src = xsrc + ((size_t)b * NCITY + row) * 128 + q * 8;
            #pragma unroll
            for (int kc = 0; kc < 4; ++kc) {
                h8 v = *(const h8*)(src + kc * 32);
                if (stats0) {
                    #pragma unroll
                    for (int r = 0; r < 8; ++r) {
                        int c = kc * 32 + q * 8 + r;
                        v[r] = (half_t)((float)v[r] * sBN2[c] + sBN2[128 + c]);
                    }
                }
                out[kc] = v;
            }
        } else {
            h8 z = {};
            out[0] = z; out[1] = z; out[2] = z; out[3] = z;
        }
        #pragma unroll
        for (int kc = 0; kc < 4; ++kc)
            *(h8*)(&sX[kc * 3584 + row * 32 + qs]) = out[kc];
    }
    __syncthreads();

    // ---- phase 2: per-wave QKV for head `wave`; K,V -> LDS, Q -> packed regs
    const int hn  = wave * 16 + l16;         // output column 0..127
    const int nsw = (hn >> 1) & 3;
    h8 bfr[3][4];
    float bv3[3];
    #pragma unroll
    for (int which = 0; which < 3; ++which) {
        const half_t* wrow = wqkv + which * 16384 + (size_t)hn * 128;
        #pragma unroll
        for (int kc = 0; kc < 4; ++kc)
            bfr[which][kc] = *(const h8*)(wrow + kc * 32 + (((quad ^ nsw) & 3) << 3));
        bv3[which] = bqkv[which * 128 + hn];
    }
    h4 qh[7];
    half_t* dstK = sK + wave * 1664;
    half_t* dstV = sV + wave * 1664;
    #pragma unroll
    for (int mi = 0; mi < 7; ++mi) {
        h8 af[4];
        #pragma unroll
        for (int kc = 0; kc < 4; ++kc) {
            int r = mi * 16 + l16;
            af[kc] = *(const h8*)(&sX[kc * 3584 + r * 32 + (((quad ^ (r >> 1)) & 3) << 3)]);
        }
        f32x4 aq = {}, ak = {}, av = {};
        #pragma unroll
        for (int kc = 0; kc < 4; ++kc) {
            aq = __builtin_amdgcn_mfma_f32_16x16x32_f16(af[kc], bfr[0][kc], aq, 0, 0, 0);
            ak = __builtin_amdgcn_mfma_f32_16x16x32_f16(af[kc], bfr[1][kc], ak, 0, 0, 0);
            av = __builtin_amdgcn_mfma_f32_16x16x32_f16(af[kc], bfr[2][kc], av, 0, 0, 0);
        }
        #pragma unroll
        for (int r = 0; r < 4; ++r) {
            int tok = mi * 16 + quad * 4 + r;
            int dsw = l16 ^ (((tok >> 2) & 1) << 3);
            qh[mi][r] = (half_t)(aq[r] + bv3[0]);
            if (tok < 104) {
                dstK[tok * 16 + dsw] = (half_t)(ak[r] + bv3[1]);
                dstV[tok * 16 + dsw] = (half_t)(av[r] + bv3[2]);
            }
        }
    }
    __syncthreads();   // all sX reads + K/V writes done -> sQ overlay safe, K/V visible

    // write Q into region A (old sX), and hoist kf/vt from region B
    {
        half_t* dstQ = sQ + wave * 1792;
        #pragma unroll
        for (int mi = 0; mi < 7; ++mi)
            #pragma unroll
            for (int r = 0; r < 4; ++r) {
                int tok = mi * 16 + quad * 4 + r;
                int dsw = l16 ^ (((tok >> 2) & 1) << 3);
                dstQ[tok * 16 + dsw] = qh[mi][r];
            }
    }
    const half_t* qb = sQ + wave * 1792;
    const half_t* kb = sK + wave * 1664;
    const half_t* vb = sV + wave * 1664;
    const int kflip = (l16 >> 2) & 1;

    h8 kf[7];
    #pragma unroll
    for (int jt = 0; jt < 7; ++jt) {
        kf[jt] = (h8){};
        if (quad < 2) {
            int row = jt * 16 + l16;
            row = row < 104 ? row : 103;   // clamped; rows >=101 are masked downstream
            kf[jt] = *(const h8*)(kb + row * 16 + ((quad ^ kflip) << 3));
        }
    }
    h8 vt[4];
    #pragma unroll
    for (int p = 0; p < 4; ++p)
        #pragma unroll
        for (int jj = 0; jj < 8; ++jj) {
            int tok = p * 32 + quad * 8 + jj;
            int tokc = tok < 104 ? tok : 103;   // clamped; P=0 for tok>=101
            vt[p][jj] = vb[tokc * 16 + (l16 ^ (((jj >> 2) & 1) << 3))];
        }
    __syncthreads();   // all Q writes visible + all K/V reads done -> sO overlay safe

    // ---- phase 3: attention (per-wave private)
    const int s0 = (((quad & 1) * 2)    ) * 16 + l16;
    const int s1 = (((quad & 1) * 2) + 1) * 16 + l16;
    const bool hi2 = (quad >> 1) != 0;
    const int ocol = hn;                       // this wave's output column

    for (int it = 0; it < 7; ++it) {
        h8 qf = {};
        if (quad < 2)
            qf = *(const h8*)(qb + (it * 16 + l16) * 16 + ((quad ^ kflip) << 3));

        f32x4 S[7];
        #pragma unroll
        for (int jt = 0; jt < 7; ++jt) {
            f32x4 a = {};
            a = __builtin_amdgcn_mfma_f32_16x16x32_f16(kf[jt], qf, a, 0, 0, 0);
            S[jt] = a;
        }
        float m = -1e30f;
        #pragma unroll
        for (int jt = 0; jt < 7; ++jt)
            #pragma unroll
            for (int r = 0; r < 4; ++r) {
                int jg = jt * 16 + quad * 4 + r;
                float sv = (jg < NCITY) ? S[jt][r] * 0.25f : -1e30f;
                S[jt][r] = sv;
                m = fmaxf(m, sv);
            }
        m = fmaxf(m, __shfl_xor(m, 16));
        m = fmaxf(m, __shfl_xor(m, 32));
        float sum = 0.0f;
        #pragma unroll
        for (int jt = 0; jt < 7; ++jt)
            #pragma unroll
            for (int r = 0; r < 4; ++r) {
                float e = __expf(S[jt][r] - m);
                S[jt][r] = e;
                sum += e;
            }
        sum += __shfl_xor(sum, 16);
        sum += __shfl_xor(sum, 32);
        float inv = 1.0f / sum;
        #pragma unroll
        for (int jt = 0; jt < 7; ++jt)
            #pragma unroll
            for (int r = 0; r < 4; ++r) S[jt][r] *= inv;

        f32x4 O = {};
        #pragma unroll
        for (int p = 0; p < 4; ++p) {
            float pj[8];
            #pragma unroll
            for (int r = 0; r < 4; ++r) {
                float a0 = __shfl(S[2 * p][r],     s0);
                float b0 = __shfl(S[2 * p + 1][r], s0);
                float a1 = __shfl(S[2 * p][r],     s1);
                float b1 = __shfl(S[2 * p + 1][r], s1);
                pj[r]     = hi2 ? b0 : a0;
                pj[4 + r] = hi2 ? b1 : a1;
            }
            h8 ph;
            #pragma unroll
            for (int jj = 0; jj < 8; ++jj)
                ph[jj] = (half_t)pj[jj];
            O = __builtin_amdgcn_mfma_f32_16x16x32_f16(ph, vt[p], O, 0, 0, 0);
        }
        // O -> LDS transpose tile (tail rows harmless garbage)
        #pragma unroll
        for (int r = 0; r < 4; ++r) {
            int q = it * 16 + quad * 4 + r;
            int g = (ocol >> 3) ^ ((q & 8) >> 2);
            sO[q * 136 + g * 8 + (ocol & 7)] = (half_t)O[r];
        }
    }
    __syncthreads();

    // ---- phase 4: O-proj (wave w owns cols w*16..+15), residual(+BN2), BN1 stats
    h8 bfr2[4];
    {
        const half_t* wrow = wo + (size_t)ocol * 128;
        const int nsw2 = (ocol >> 1) & 3;
        #pragma unroll
        for (int kc = 0; kc < 4; ++kc)
            bfr2[kc] = *(const h8*)(wrow + kc * 32 + (((quad ^ nsw2) & 3) << 3));
    }
    f32x4 acc[7];
    #pragma unroll
    for (int mi = 0; mi < 7; ++mi) {
        acc[mi] = (f32x4){};
        int row = mi * 16 + l16;
        int swr = (row & 8) >> 2;
        #pragma unroll
        for (int kc = 0; kc < 4; ++kc) {
            h8 af = *(const h8*)(&sO[row * 136 + (((kc * 4 + quad) ^ swr) << 3)]);
            acc[mi] = __builtin_amdgcn_mfma_f32_16x16x32_f16(af, bfr2[kc], acc[mi], 0, 0, 0);
        }
    }
    float sclo = 1.0f, shfo = 0.0f;
    if (stats0) {
        float mean = stats0[ocol] * invN;
        float var  = stats0[128 + ocol] * invN - mean * mean;
        sclo = g0[ocol] * rsqrtf(var + 1e-5f);
        shfo = be0[ocol] - mean * sclo;
    }
    float bvv = bo[ocol];
    float s = 0.0f, ss = 0.0f;
    #pragma unroll
    for (int mi = 0; mi < 7; ++mi) {
        #pragma unroll
        for (int r = 0; r < 4; ++r) {
            int q = mi * 16 + quad * 4 + r;
            if (q < NCITY) {
                size_t grow = (size_t)b * NCITY + q;
                float xv = (float)xsrc[grow * 128 + ocol] * sclo + shfo;
                float o = acc[mi][r] + bvv + xv;
                y16[grow * 128 + ocol] = (half_t)o;
                s += o; ss += o * o;
            }
        }
    }
    s  += __shfl_xor(s, 16);  s  += __shfl_xor(s, 32);
    ss += __shfl_xor(ss, 16); ss += __shfl_xor(ss, 32);
    if (quad == 0) {
        atomicAdd(&stats[ocol], s);
        atomicAdd(&stats[128 + ocol], ss);
    }
}

// ---------------- fused BN1 + FF1(ReLU) + FF2 ----------------
// 512 threads / 8 waves, 80 KB LDS -> 2 blocks/CU.
// Weights reg-staged: next round's loads issued under compute.
// Epilogue residual x' read back from sX (LDS) -- no y16 re-read.
__global__ __launch_bounds__(512, 4)
void ff_fused(half_t* __restrict__ y16, const float* __restrict__ st1,
              const float* __restrict__ g1, const float* __restrict__ be1,
              const half_t* __restrict__ w1, const half_t* __restrict__ w2,
              const float* __restrict__ bf1, const float* __restrict__ bf2,
              float* __restrict__ stats)
{
    __shared__ alignas(16) half_t sX[4][128 * 32];   // 32 KB  x' tile
    __shared__ alignas(16) half_t sW1f[8192];        // 16 KB  wf1 chunk image (flat)
    __shared__ alignas(16) half_t sW2f[8192];        // 16 KB  wf2 chunk image (flat)
    __shared__ alignas(16) half_t sH[2][128 * 32];   // 16 KB  relu chunk

    const int tid  = threadIdx.x;
    const int wave = tid >> 6, lane = tid & 63;
    const int quad = lane >> 4, l16 = lane & 15;
    const int m0 = blockIdx.x * 128;
    const int wr = wave >> 1;          // 0..3: 32-row group
    const int wc = wave & 1;           // col group

    const float invN = 1.0f / (float)TROWS;
    const int so = wave * 512 + lane * 8;    // identity global<->LDS offset

    // prologue: round-0 weight regs
    h8 rw1a = *(const h8*)(w1 + so);
    h8 rw1b = *(const h8*)(w1 + so + 4096);
    h8 rw2a = *(const h8*)(w2 + so);
    h8 rw2b = *(const h8*)(w2 + so + 4096);

    // BN1 scale/shift table (1 KB, overlaid in sW1f; dead after sX stage)
    float* sBN = (float*)&sW1f[0];
    if (tid < 128) {
        float mean = st1[tid] * invN;
        float var  = st1[128 + tid] * invN - mean * mean;
        float scl  = g1[tid] * rsqrtf(var + 1e-5f);
        sBN[tid]       = scl;
        sBN[128 + tid] = be1[tid] - mean * scl;
    }
    __syncthreads();

    // stage x' = BN1(y16) -> sX (swizzled)
    {
        const int row = tid >> 2;            // 0..127
        const int q   = tid & 3;
        const int qs  = ((q ^ (row >> 1)) & 3) << 3;
        const half_t* src = y16 + (size_t)(m0 + row) * 128 + q * 8;
        #pragma unroll
        for (int kc = 0; kc < 4; ++kc) {
            h8 v = *(const h8*)(src + kc * 32);
            h8 xv;
            #pragma unroll
            for (int r = 0; r < 8; ++r) {
                int c = kc * 32 + q * 8 + r;
                xv[r] = (half_t)((float)v[r] * sBN[c] + sBN[128 + c]);
            }
            *(h8*)(&sX[kc][row * 32 + qs]) = xv;
        }
    }

    f32x4 acc2[2][4] = {};

    for (int j = 0; j < 8; ++j) {
        // b1: FF2(j-1) done reading sW/sH; sX/sBN writes visible (j=0)
        asm volatile("s_waitcnt lgkmcnt(0)" ::: "memory");
        __builtin_amdgcn_s_barrier();
        __builtin_amdgcn_sched_barrier(0);
        // write W(j) from regs (compiler inserts the per-thread vmcnt waits)
        *(h8*)(&sW1f[so])        = rw1a;
        *(h8*)(&sW1f[so + 4096]) = rw1b;
        *(h8*)(&sW2f[so])        = rw2a;
        *(h8*)(&sW2f[so + 4096]) = rw2b;
        asm volatile("s_waitcnt lgkmcnt(0)" ::: "memory");
        __builtin_amdgcn_s_barrier();
        __builtin_amdgcn_sched_barrier(0);
        if (j < 7) {   // issue next round's loads; they fly under FF1+FF2
            const half_t* w1n = w1 + (size_t)(j + 1) * 8192;
            const half_t* w2n = w2 + (size_t)(j + 1) * 8192;
            rw1a = *(const h8*)(w1n + so);
            rw1b = *(const h8*)(w1n + so + 4096);
            rw2a = *(const h8*)(w2n + so);
            rw2b = *(const h8*)(w2n + so + 4096);
        }

        // FF1: wave tile 32x32 of 128x64 chunk
        f32x4 acc1[2][2] = {};
        #pragma unroll
        for (int kc = 0; kc < 4; ++kc) {
            h8 af[2], bf[2];
            #pragma unroll
            for (int mi = 0; mi < 2; ++mi) {
                int r = wr * 32 + mi * 16 + l16;
                af[mi] = *(const h8*)(&sX[kc][r * 32 + (((quad ^ (r >> 1)) & 3) << 3)]);
            }
            #pragma unroll
            for (int ni = 0; ni < 2; ++ni) {
                int n = wc * 32 + ni * 16 + l16;
                bf[ni] = *(const h8*)(&sW1f[kc * 2048 + n * 32 + (((quad ^ (n >> 1)) & 3) << 3)]);
            }
            #pragma unroll
            for (int mi = 0; mi < 2; ++mi)
            #pragma unroll
            for (int ni = 0; ni < 2; ++ni)
                acc1[mi][ni] = __builtin_amdgcn_mfma_f32_16x16x32_f16(af[mi], bf[ni], acc1[mi][ni], 0, 0, 0);
        }
        // bias + ReLU -> sH (swizzled scalar writes)
        #pragma unroll
        for (int ni = 0; ni < 2; ++ni) {
            int c = wc * 32 + ni * 16 + l16;       // 0..63
            float bvv = bf1[j * 64 + c];
            int kc2 = c >> 5, c5 = c & 31;
            #pragma unroll
            for (int mi = 0; mi < 2; ++mi)
            #pragma unroll
            for (int r = 0; r < 4; ++r) {
                int row = wr * 32 + mi * 16 + quad * 4 + r;
                float v = acc1[mi][ni][r] + bvv;
                v = v > 0.0f ? v : 0.0f;
                int hsw = (c5 & 7) | ((((c5 >> 3) ^ (row >> 1)) & 3) << 3);
                sH[kc2][row * 32 + hsw] = (half_t)v;
            }
        }
        asm volatile("s_waitcnt lgkmcnt(0)" ::: "memory");
        __builtin_amdgcn_s_barrier();
        __builtin_amdgcn_sched_barrier(0);

        // FF2 partial: wave tile 32x64, K-slice 64
        #pragma unroll
        for (int kc = 0; kc < 2; ++kc) {
            h8 af[2], bf[4];
            #pragma unroll
            for (int mi = 0; mi < 2; ++mi) {
                int r = wr * 32 + mi * 16 + l16;
                af[mi] = *(const h8*)(&sH[kc][r * 32 + (((quad ^ (r >> 1)) & 3) << 3)]);
            }
            #pragma unroll
            for (int ni = 0; ni < 4; ++ni) {
                int n = wc * 64 + ni * 16 + l16;
                bf[ni] = *(const h8*)(&sW2f[kc * 4096 + n * 32 + (((quad ^ (n >> 1)) & 3) << 3)]);
            }
            #pragma unroll
            for (int mi = 0; mi < 2; ++mi)
            #pragma unroll
            for (int ni = 0; ni < 4; ++ni)
                acc2[mi][ni] = __builtin_amdgcn_mfma_f32_16x16x32_f16(af[mi], bf[ni], acc2[mi][ni], 0, 0, 0);
        }
    }

    // epilogue: y2 = acc2 + bf2 + x' (x' read from sX), BN2 stats
    __syncthreads();                       // sH reads done -> reuse as reduction scratch
    float* red = (float*)&sH[0][0];        // [2][512] floats (s, ss)

    #pragma unroll
    for (int ni = 0; ni < 4; ++ni) {
        int col = wc * 64 + ni * 16 + l16;
        float bvv = bf2[col];
        int kc = col >> 5, c5 = col & 31;
        float s = 0.0f, ss = 0.0f;
        #pragma unroll
        for (int mi = 0; mi < 2; ++mi) {
            #pragma unroll
            for (int r = 0; r < 4; ++r) {
                int rowl = wr * 32 + mi * 16 + quad * 4 + r;
                int hsw = (c5 & 7) | ((((c5 >> 3) ^ (rowl >> 1)) & 3) << 3);
                float xv = (float)sX[kc][rowl * 32 + hsw];
                float o = acc2[mi][ni][r] + bvv + xv;
                y16[(size_t)(m0 + rowl) * 128 + col] = (half_t)o;
                s += o; ss += o * o;
            }
        }
        s  += __shfl_xor(s, 16);  s  += __shfl_xor(s, 32);
        ss += __shfl_xor(ss, 16); ss += __shfl_xor(ss, 32);
        if (quad == 0) {
            red[wave * 64 + ni * 16 + l16]       = s;
            red[512 + wave * 64 + ni * 16 + l16] = ss;
        }
    }
    __syncthreads();
    if (tid < 256) {
        int a   = tid >> 7;          // 0 = s, 1 = ss
        int col = tid & 127;
        int wcc = col >> 6, nii = (col >> 4) & 3, lx = col & 15;
        float t = 0.0f;
        #pragma unroll
        for (int w = 0; w < 4; ++w)
            t += red[a * 512 + (w * 2 + wcc) * 64 + nii * 16 + lx];
        atomicAdd(&stats[a * 128 + col], t);
    }
}

// ---------------- BatchNorm apply (final layer only: fp32 out) ----------------
__global__ __launch_bounds__(256)
void bn_apply(const h8* __restrict__ y, const float* __restrict__ stats,
              const float* __restrict__ g, const float* __restrict__ be,
              float* __restrict__ dst32)
{
    __shared__ float sh[256];
    const int tid = threadIdx.x;
    if (tid < 128) {
        const float invN = 1.0f / (float)TROWS;
        float mean = stats[tid] * invN;
        float var  = stats[128 + tid] * invN - mean * mean;
        float inv  = rsqrtf(var + 1e-5f);
        float scl  = g[tid] * inv;
        sh[tid]       = scl;
        sh[128 + tid] = be[tid] - mean * scl;
    }
    __syncthreads();

    int gid = blockIdx.x * 256 + tid;   // over TROWS*16 (8 ch each)
    int c = (gid & 15) * 8;
    h8 v = y[gid];
    float o[8];
    #pragma unroll
    for (int r = 0; r < 8; ++r)
        o[r] = (float)v[r] * sh[c + r] + sh[128 + c + r];
    f32x4 lo = { o[0], o[1], o[2], o[3] };
    f32x4 hi = { o[4], o[5], o[6], o[7] };
    ((f32x4*)dst32)[gid * 2]     = lo;
    ((f32x4*)dst32)[gid * 2 + 1] = hi;
}

// ---------------- launch ----------------
extern "C" void kernel_launch(void* const* d_in, const int* in_sizes, int n_in,
                              void* d_out, int out_size, void* d_ws, size_t ws_size,
                              hipStream_t stream)
{
    const float* s    = (const float*)d_in[0];
    const int*   dd   = (const int*)d_in[1];
    const float* e_w  = (const float*)d_in[2];
    const float* e_b  = (const float*)d_in[3];
    const float* ep_w = (const float*)d_in[4];
    const float* ep_b = (const float*)d_in[5];
    const float* Wq   = (const float*)d_in[6];
    const float* bq   = (const float*)d_in[7];
    const float* Wk   = (const float*)d_in[8];
    const float* bk   = (const float*)d_in[9];
    const float* Wv   = (const float*)d_in[10];
    const float* bv   = (const float*)d_in[11];
    const float* Wo   = (const float*)d_in[12];
    const float* bo   = (const float*)d_in[13];
    const float* Wf1  = (const float*)d_in[14];
    const float* bf1  = (const float*)d_in[15];
    const float* Wf2  = (const float*)d_in[16];
    const float* bf2  = (const float*)d_in[17];
    const float* g1   = (const float*)d_in[18];
    const float* be1  = (const float*)d_in[19];
    const float* g2   = (const float*)d_in[20];
    const float* be2  = (const float*)d_in[21];

    char* ws = (char*)d_ws;
    size_t off = 0;
    auto alloc = [&](size_t bytes) -> void* {
        void* p = ws + off;
        off += (bytes + 255) & ~(size_t)255;
        return p;
    };
    half_t* y16   = (half_t*)alloc((size_t)TROWS * 128 * 2);
    half_t* xh    = (half_t*)alloc((size_t)TROWS * 128 * 2);
    half_t* wqkv  = (half_t*)alloc((size_t)3 * 384 * 128 * 2);
    half_t* wo    = (half_t*)alloc((size_t)3 * 128 * 128 * 2);
    half_t* wf1   = (half_t*)alloc((size_t)3 * 512 * 128 * 2);
    half_t* wf2   = (half_t*)alloc((size_t)3 * 128 * 512 * 2);
    float*  bqkv  = (float*) alloc((size_t)3 * 384 * 4);
    float*  stats = (float*) alloc(6 * 256 * 4);

    dim3 blk(256);

    hipMemsetAsync(stats, 0, 6 * 256 * 4, stream);

    prep_kernel<<<dim3(768, 7), blk, 0, stream>>>(Wq, Wk, Wv, Wo, Wf1, Wf2, bq, bk, bv,
                                                  wqkv, wo, wf1, wf2, bqkv);

    embed_kernel<<<dim3(TROWS * 128 / 256), blk, 0, stream>>>(s, dd, e_w, e_b, ep_w, ep_b, xh);

    for (int l = 0; l < 3; ++l) {
        float* st1 = stats + (size_t)(l * 2) * 256;
        float* st2 = stats + (size_t)(l * 2 + 1) * 256;
        const float* st0 = (l == 0) ? nullptr : stats + (size_t)((l - 1) * 2 + 1) * 256;
        const half_t* xsrc = (l == 0) ? xh : y16;
        // [BN2 prev] + QKV + attention + O-proj + residual + BN1 stats -> y16
        layer_attn<<<dim3(BATCH), dim3(512), 0, stream>>>(xsrc, st0,
                                                          g2 + (l ? (l - 1) * 128 : 0),
                                                          be2 + (l ? (l - 1) * 128 : 0),
                                                          wqkv + (size_t)l * 49152,
                                                          bqkv + l * 384,
                                                          wo + (size_t)l * 16384,
                                                          bo + l * 128, y16, st1);
        // fused BN1-apply + FF1 + FF2 + residual + BN2 stats (in-place y16)
        ff_fused<<<dim3(404), dim3(512), 0, stream>>>(y16, st1, g1 + l * 128, be1 + l * 128,
                                                      wf1 + (size_t)l * 65536, wf2 + (size_t)l * 65536,
                                                      bf1 + l * 512, bf2 + l * 128, st2);
    }
    // final BN2 apply -> fp32 output
    bn_apply<<<dim3(TROWS * 16 / 256), blk, 0, stream>>>((const h8*)y16, stats + 5 * 256,
                                                         g2 + 2 * 128, be2 + 2 * 128,
                                                         (float*)d_out);
}